// Round 2
// baseline (11343.371 us; speedup 1.0000x reference)
//
#include <hip/hip_runtime.h>
#include <math.h>

#define NN 50000
#define NE 800000

// ---------------- cosine + degree count kernels -------------------------------

__global__ __launch_bounds__(256) void edge1_k(
    const float* __restrict__ nf,
    const int* __restrict__ src, const int* __restrict__ dst,
    float* __restrict__ cos1, int* __restrict__ cnt)
{
  int wid = blockIdx.x * 4 + (threadIdx.x >> 6);
  if (wid >= NE) return;
  int lane = threadIdx.x & 63;
  int s = src[wid], d = dst[wid];
  float2 hs = *(const float2*)&nf[(size_t)s * 128 + lane * 2];
  float2 hd = *(const float2*)&nf[(size_t)d * 128 + lane * 2];
  float ss = hs.x * hs.x + hs.y * hs.y;
  float dd = hd.x * hd.x + hd.y * hd.y;
  float sd = hs.x * hd.x + hs.y * hd.y;
#pragma unroll
  for (int o = 32; o >= 1; o >>= 1) {
    ss += __shfl_xor(ss, o);
    dd += __shfl_xor(dd, o);
    sd += __shfl_xor(sd, o);
  }
  if (lane == 0) {
    cos1[wid] = sd / (fmaxf(sqrtf(ss), 1e-12f) * fmaxf(sqrtf(dd), 1e-12f));
    atomicAdd(&cnt[d], 1);
  }
}

__global__ __launch_bounds__(256) void edge2_k(
    const float* __restrict__ h1,
    const int* __restrict__ src, const int* __restrict__ dst,
    float* __restrict__ cos2)
{
  int wid = blockIdx.x * 4 + (threadIdx.x >> 6);
  if (wid >= NE) return;
  int lane = threadIdx.x & 63;
  int s = src[wid], d = dst[wid];
  float4 a = *(const float4*)&h1[(size_t)s * 256 + lane * 4];
  float4 b = *(const float4*)&h1[(size_t)d * 256 + lane * 4];
  float ss = a.x * a.x + a.y * a.y + a.z * a.z + a.w * a.w;
  float dd = b.x * b.x + b.y * b.y + b.z * b.z + b.w * b.w;
  float sd = a.x * b.x + a.y * b.y + a.z * b.z + a.w * b.w;
#pragma unroll
  for (int o = 32; o >= 1; o >>= 1) {
    ss += __shfl_xor(ss, o);
    dd += __shfl_xor(dd, o);
    sd += __shfl_xor(sd, o);
  }
  if (lane == 0)
    cos2[wid] = sd / (fmaxf(sqrtf(ss), 1e-12f) * fmaxf(sqrtf(dd), 1e-12f));
}

// ---------------- fused edge-MLP layer 1 --------------------------------------
// per 64-edge tile: m = cos1*w1*h[src]; t = relu(m@Wa+ba); r = relu(t@Wb+bb);
// atomicAdd r into s1[dst].  w1 recomputed from ef (2 FMAs/elem).

__global__ __launch_bounds__(256) void edge_mlp1(
    const float* __restrict__ nf, const float* __restrict__ ef,
    const int* __restrict__ src, const int* __restrict__ dst,
    const float* __restrict__ We1, const float* __restrict__ be1,
    const float* __restrict__ Wa, const float* __restrict__ ba,
    const float* __restrict__ Wb, const float* __restrict__ bbv,
    const float* __restrict__ cosv, float* __restrict__ s1)
{
  __shared__ float As[64][132];   // padded: bank = (4*row + k) % 32
  __shared__ float Bs[16][128];
  const int t = threadIdx.x;
  const int tx = t & 15, ty = t >> 4;   // cols tx*8, rows ty*4
  const int e0 = blockIdx.x * 64;

  // prologue: As = m tile
  {
    const int k = (t & 31) * 4;
    const int rh = t >> 5;
    const float4 wa = *(const float4*)&We1[k];
    const float4 wb = *(const float4*)&We1[128 + k];
    const float4 bv = *(const float4*)&be1[k];
#pragma unroll
    for (int p = 0; p < 8; ++p) {
      const int row = p * 8 + rh;
      const int e = e0 + row;
      const int s = src[e];
      const float c = cosv[e];
      const float f0 = ef[2 * e], f1 = ef[2 * e + 1];
      const float4 h = *(const float4*)&nf[(size_t)s * 128 + k];
      float4 m;
      m.x = c * fmaf(f0, wa.x, fmaf(f1, wb.x, bv.x)) * h.x;
      m.y = c * fmaf(f0, wa.y, fmaf(f1, wb.y, bv.y)) * h.y;
      m.z = c * fmaf(f0, wa.z, fmaf(f1, wb.z, bv.z)) * h.z;
      m.w = c * fmaf(f0, wa.w, fmaf(f1, wb.w, bv.w)) * h.w;
      *(float4*)&As[row][k] = m;
    }
  }
  __syncthreads();

  float acc[4][8];
#pragma unroll
  for (int i = 0; i < 4; i++)
#pragma unroll
    for (int j = 0; j < 8; j++) acc[i][j] = 0.f;

  // stage 1: acc = m @ Wa
  for (int kt = 0; kt < 128; kt += 16) {
    *(float4*)&Bs[ty][tx * 8]     = *(const float4*)&Wa[(size_t)(kt + ty) * 128 + tx * 8];
    *(float4*)&Bs[ty][tx * 8 + 4] = *(const float4*)&Wa[(size_t)(kt + ty) * 128 + tx * 8 + 4];
    __syncthreads();
#pragma unroll
    for (int kk = 0; kk < 16; ++kk) {
      const float4 p = *(const float4*)&Bs[kk][tx * 8];
      const float4 q = *(const float4*)&Bs[kk][tx * 8 + 4];
#pragma unroll
      for (int i = 0; i < 4; ++i) {
        const float a = As[ty * 4 + i][kt + kk];
        acc[i][0] = fmaf(a, p.x, acc[i][0]);
        acc[i][1] = fmaf(a, p.y, acc[i][1]);
        acc[i][2] = fmaf(a, p.z, acc[i][2]);
        acc[i][3] = fmaf(a, p.w, acc[i][3]);
        acc[i][4] = fmaf(a, q.x, acc[i][4]);
        acc[i][5] = fmaf(a, q.y, acc[i][5]);
        acc[i][6] = fmaf(a, q.z, acc[i][6]);
        acc[i][7] = fmaf(a, q.w, acc[i][7]);
      }
    }
    __syncthreads();
  }
  // writeback t = relu(acc + ba) into As
  {
    const float4 c0 = *(const float4*)&ba[tx * 8];
    const float4 c1 = *(const float4*)&ba[tx * 8 + 4];
#pragma unroll
    for (int i = 0; i < 4; ++i) {
      const int row = ty * 4 + i;
      As[row][tx * 8 + 0] = fmaxf(acc[i][0] + c0.x, 0.f);
      As[row][tx * 8 + 1] = fmaxf(acc[i][1] + c0.y, 0.f);
      As[row][tx * 8 + 2] = fmaxf(acc[i][2] + c0.z, 0.f);
      As[row][tx * 8 + 3] = fmaxf(acc[i][3] + c0.w, 0.f);
      As[row][tx * 8 + 4] = fmaxf(acc[i][4] + c1.x, 0.f);
      As[row][tx * 8 + 5] = fmaxf(acc[i][5] + c1.y, 0.f);
      As[row][tx * 8 + 6] = fmaxf(acc[i][6] + c1.z, 0.f);
      As[row][tx * 8 + 7] = fmaxf(acc[i][7] + c1.w, 0.f);
    }
  }
  __syncthreads();

#pragma unroll
  for (int i = 0; i < 4; i++)
#pragma unroll
    for (int j = 0; j < 8; j++) acc[i][j] = 0.f;

  // stage 2: acc = t @ Wb
  for (int kt = 0; kt < 128; kt += 16) {
    *(float4*)&Bs[ty][tx * 8]     = *(const float4*)&Wb[(size_t)(kt + ty) * 128 + tx * 8];
    *(float4*)&Bs[ty][tx * 8 + 4] = *(const float4*)&Wb[(size_t)(kt + ty) * 128 + tx * 8 + 4];
    __syncthreads();
#pragma unroll
    for (int kk = 0; kk < 16; ++kk) {
      const float4 p = *(const float4*)&Bs[kk][tx * 8];
      const float4 q = *(const float4*)&Bs[kk][tx * 8 + 4];
#pragma unroll
      for (int i = 0; i < 4; ++i) {
        const float a = As[ty * 4 + i][kt + kk];
        acc[i][0] = fmaf(a, p.x, acc[i][0]);
        acc[i][1] = fmaf(a, p.y, acc[i][1]);
        acc[i][2] = fmaf(a, p.z, acc[i][2]);
        acc[i][3] = fmaf(a, p.w, acc[i][3]);
        acc[i][4] = fmaf(a, q.x, acc[i][4]);
        acc[i][5] = fmaf(a, q.y, acc[i][5]);
        acc[i][6] = fmaf(a, q.z, acc[i][6]);
        acc[i][7] = fmaf(a, q.w, acc[i][7]);
      }
    }
    __syncthreads();
  }
  // epilogue: relu + scatter-add
  {
    const float4 c0 = *(const float4*)&bbv[tx * 8];
    const float4 c1 = *(const float4*)&bbv[tx * 8 + 4];
#pragma unroll
    for (int i = 0; i < 4; ++i) {
      const int d = dst[e0 + ty * 4 + i];
      float* o = &s1[(size_t)d * 128 + tx * 8];
      atomicAdd(&o[0], fmaxf(acc[i][0] + c0.x, 0.f));
      atomicAdd(&o[1], fmaxf(acc[i][1] + c0.y, 0.f));
      atomicAdd(&o[2], fmaxf(acc[i][2] + c0.z, 0.f));
      atomicAdd(&o[3], fmaxf(acc[i][3] + c0.w, 0.f));
      atomicAdd(&o[4], fmaxf(acc[i][4] + c1.x, 0.f));
      atomicAdd(&o[5], fmaxf(acc[i][5] + c1.y, 0.f));
      atomicAdd(&o[6], fmaxf(acc[i][6] + c1.z, 0.f));
      atomicAdd(&o[7], fmaxf(acc[i][7] + c1.w, 0.f));
    }
  }
}

// ---------------- fused edge-MLP layer 2 --------------------------------------
// per 32-edge tile: w2 = relu(w1)@We2+be2; m2 = cos2*w2*h1[src];
// t2 = relu(m2@Wa+ba); r2 = relu(t2@Wb+bb); atomicAdd into s2[dst].

__global__ __launch_bounds__(256) void edge_mlp2(
    const float* __restrict__ h1, const float* __restrict__ ef,
    const int* __restrict__ src, const int* __restrict__ dst,
    const float* __restrict__ We1, const float* __restrict__ be1,
    const float* __restrict__ We2, const float* __restrict__ be2,
    const float* __restrict__ Wa, const float* __restrict__ ba,
    const float* __restrict__ Wb, const float* __restrict__ bbv,
    const float* __restrict__ cosv, float* __restrict__ s2)
{
  __shared__ float A1s[32][128];  // relu(w1) : 16 KB
  __shared__ float As[32][256];   // m2 / t2  : 32 KB
  __shared__ float Bs[16][256];   // weights  : 16 KB  (total exactly 64 KB)
  const int t = threadIdx.x;
  const int tx = t & 31, ty = t >> 5;   // cols tx*8 (0..255), rows ty*4 (0..31)
  const int e0 = blockIdx.x * 32;

  // prologue: A1s = relu(ef @ We1 + be1)
  {
    const int k = (t & 31) * 4;
    const int rh = t >> 5;
    const float4 wa = *(const float4*)&We1[k];
    const float4 wb = *(const float4*)&We1[128 + k];
    const float4 bv = *(const float4*)&be1[k];
#pragma unroll
    for (int p = 0; p < 4; ++p) {
      const int row = p * 8 + rh;
      const int e = e0 + row;
      const float f0 = ef[2 * e], f1 = ef[2 * e + 1];
      float4 m;
      m.x = fmaxf(fmaf(f0, wa.x, fmaf(f1, wb.x, bv.x)), 0.f);
      m.y = fmaxf(fmaf(f0, wa.y, fmaf(f1, wb.y, bv.y)), 0.f);
      m.z = fmaxf(fmaf(f0, wa.z, fmaf(f1, wb.z, bv.z)), 0.f);
      m.w = fmaxf(fmaf(f0, wa.w, fmaf(f1, wb.w, bv.w)), 0.f);
      *(float4*)&A1s[row][k] = m;
    }
  }
  __syncthreads();

  float acc[4][8];
#pragma unroll
  for (int i = 0; i < 4; i++)
#pragma unroll
    for (int j = 0; j < 8; j++) acc[i][j] = 0.f;

  // stage B: acc = relu(w1) @ We2   (K=128)
  for (int kt = 0; kt < 128; kt += 16) {
    {
      const int r = t >> 4, c = (t & 15) * 16;
      const float* bsrc = &We2[(size_t)(kt + r) * 256 + c];
      *(float4*)&Bs[r][c]      = *(const float4*)&bsrc[0];
      *(float4*)&Bs[r][c + 4]  = *(const float4*)&bsrc[4];
      *(float4*)&Bs[r][c + 8]  = *(const float4*)&bsrc[8];
      *(float4*)&Bs[r][c + 12] = *(const float4*)&bsrc[12];
    }
    __syncthreads();
#pragma unroll
    for (int kk = 0; kk < 16; ++kk) {
      const float4 p = *(const float4*)&Bs[kk][tx * 8];
      const float4 q = *(const float4*)&Bs[kk][tx * 8 + 4];
#pragma unroll
      for (int i = 0; i < 4; ++i) {
        const float a = A1s[ty * 4 + i][kt + kk];
        acc[i][0] = fmaf(a, p.x, acc[i][0]);
        acc[i][1] = fmaf(a, p.y, acc[i][1]);
        acc[i][2] = fmaf(a, p.z, acc[i][2]);
        acc[i][3] = fmaf(a, p.w, acc[i][3]);
        acc[i][4] = fmaf(a, q.x, acc[i][4]);
        acc[i][5] = fmaf(a, q.y, acc[i][5]);
        acc[i][6] = fmaf(a, q.z, acc[i][6]);
        acc[i][7] = fmaf(a, q.w, acc[i][7]);
      }
    }
    __syncthreads();
  }
  // m2 = (acc + be2) * cos2 * h1[src]  -> As
  {
    const float4 c0 = *(const float4*)&be2[tx * 8];
    const float4 c1 = *(const float4*)&be2[tx * 8 + 4];
#pragma unroll
    for (int i = 0; i < 4; ++i) {
      const int row = ty * 4 + i;
      const int e = e0 + row;
      const int s = src[e];
      const float cv = cosv[e];
      const float4 g0 = *(const float4*)&h1[(size_t)s * 256 + tx * 8];
      const float4 g1 = *(const float4*)&h1[(size_t)s * 256 + tx * 8 + 4];
      As[row][tx * 8 + 0] = (acc[i][0] + c0.x) * cv * g0.x;
      As[row][tx * 8 + 1] = (acc[i][1] + c0.y) * cv * g0.y;
      As[row][tx * 8 + 2] = (acc[i][2] + c0.z) * cv * g0.z;
      As[row][tx * 8 + 3] = (acc[i][3] + c0.w) * cv * g0.w;
      As[row][tx * 8 + 4] = (acc[i][4] + c1.x) * cv * g1.x;
      As[row][tx * 8 + 5] = (acc[i][5] + c1.y) * cv * g1.y;
      As[row][tx * 8 + 6] = (acc[i][6] + c1.z) * cv * g1.z;
      As[row][tx * 8 + 7] = (acc[i][7] + c1.w) * cv * g1.w;
    }
  }
  __syncthreads();

  // stage C: t2 = relu(m2 @ Wa + ba) -> As   (K=256)
#pragma unroll
  for (int i = 0; i < 4; i++)
#pragma unroll
    for (int j = 0; j < 8; j++) acc[i][j] = 0.f;
  for (int kt = 0; kt < 256; kt += 16) {
    {
      const int r = t >> 4, c = (t & 15) * 16;
      const float* bsrc = &Wa[(size_t)(kt + r) * 256 + c];
      *(float4*)&Bs[r][c]      = *(const float4*)&bsrc[0];
      *(float4*)&Bs[r][c + 4]  = *(const float4*)&bsrc[4];
      *(float4*)&Bs[r][c + 8]  = *(const float4*)&bsrc[8];
      *(float4*)&Bs[r][c + 12] = *(const float4*)&bsrc[12];
    }
    __syncthreads();
#pragma unroll
    for (int kk = 0; kk < 16; ++kk) {
      const float4 p = *(const float4*)&Bs[kk][tx * 8];
      const float4 q = *(const float4*)&Bs[kk][tx * 8 + 4];
#pragma unroll
      for (int i = 0; i < 4; ++i) {
        const float a = As[ty * 4 + i][kt + kk];
        acc[i][0] = fmaf(a, p.x, acc[i][0]);
        acc[i][1] = fmaf(a, p.y, acc[i][1]);
        acc[i][2] = fmaf(a, p.z, acc[i][2]);
        acc[i][3] = fmaf(a, p.w, acc[i][3]);
        acc[i][4] = fmaf(a, q.x, acc[i][4]);
        acc[i][5] = fmaf(a, q.y, acc[i][5]);
        acc[i][6] = fmaf(a, q.z, acc[i][6]);
        acc[i][7] = fmaf(a, q.w, acc[i][7]);
      }
    }
    __syncthreads();
  }
  {
    const float4 c0 = *(const float4*)&ba[tx * 8];
    const float4 c1 = *(const float4*)&ba[tx * 8 + 4];
#pragma unroll
    for (int i = 0; i < 4; ++i) {
      const int row = ty * 4 + i;
      As[row][tx * 8 + 0] = fmaxf(acc[i][0] + c0.x, 0.f);
      As[row][tx * 8 + 1] = fmaxf(acc[i][1] + c0.y, 0.f);
      As[row][tx * 8 + 2] = fmaxf(acc[i][2] + c0.z, 0.f);
      As[row][tx * 8 + 3] = fmaxf(acc[i][3] + c0.w, 0.f);
      As[row][tx * 8 + 4] = fmaxf(acc[i][4] + c1.x, 0.f);
      As[row][tx * 8 + 5] = fmaxf(acc[i][5] + c1.y, 0.f);
      As[row][tx * 8 + 6] = fmaxf(acc[i][6] + c1.z, 0.f);
      As[row][tx * 8 + 7] = fmaxf(acc[i][7] + c1.w, 0.f);
    }
  }
  __syncthreads();

  // stage D: r2 = relu(t2 @ Wb + bb) -> atomic scatter into s2
#pragma unroll
  for (int i = 0; i < 4; i++)
#pragma unroll
    for (int j = 0; j < 8; j++) acc[i][j] = 0.f;
  for (int kt = 0; kt < 256; kt += 16) {
    {
      const int r = t >> 4, c = (t & 15) * 16;
      const float* bsrc = &Wb[(size_t)(kt + r) * 256 + c];
      *(float4*)&Bs[r][c]      = *(const float4*)&bsrc[0];
      *(float4*)&Bs[r][c + 4]  = *(const float4*)&bsrc[4];
      *(float4*)&Bs[r][c + 8]  = *(const float4*)&bsrc[8];
      *(float4*)&Bs[r][c + 12] = *(const float4*)&bsrc[12];
    }
    __syncthreads();
#pragma unroll
    for (int kk = 0; kk < 16; ++kk) {
      const float4 p = *(const float4*)&Bs[kk][tx * 8];
      const float4 q = *(const float4*)&Bs[kk][tx * 8 + 4];
#pragma unroll
      for (int i = 0; i < 4; ++i) {
        const float a = As[ty * 4 + i][kt + kk];
        acc[i][0] = fmaf(a, p.x, acc[i][0]);
        acc[i][1] = fmaf(a, p.y, acc[i][1]);
        acc[i][2] = fmaf(a, p.z, acc[i][2]);
        acc[i][3] = fmaf(a, p.w, acc[i][3]);
        acc[i][4] = fmaf(a, q.x, acc[i][4]);
        acc[i][5] = fmaf(a, q.y, acc[i][5]);
        acc[i][6] = fmaf(a, q.z, acc[i][6]);
        acc[i][7] = fmaf(a, q.w, acc[i][7]);
      }
    }
    __syncthreads();
  }
  {
    const float4 c0 = *(const float4*)&bbv[tx * 8];
    const float4 c1 = *(const float4*)&bbv[tx * 8 + 4];
#pragma unroll
    for (int i = 0; i < 4; ++i) {
      const int d = dst[e0 + ty * 4 + i];
      float* o = &s2[(size_t)d * 256 + tx * 8];
      atomicAdd(&o[0], fmaxf(acc[i][0] + c0.x, 0.f));
      atomicAdd(&o[1], fmaxf(acc[i][1] + c0.y, 0.f));
      atomicAdd(&o[2], fmaxf(acc[i][2] + c0.z, 0.f));
      atomicAdd(&o[3], fmaxf(acc[i][3] + c0.w, 0.f));
      atomicAdd(&o[4], fmaxf(acc[i][4] + c1.x, 0.f));
      atomicAdd(&o[5], fmaxf(acc[i][5] + c1.y, 0.f));
      atomicAdd(&o[6], fmaxf(acc[i][6] + c1.z, 0.f));
      atomicAdd(&o[7], fmaxf(acc[i][7] + c1.w, 0.f));
    }
  }
}

// ---------------- node linear 1: h1 = relu(concat(nf, s1/cnt) @ Wl1 + bl1) ----

__global__ __launch_bounds__(256) void h1_k(
    const float* __restrict__ nf, const float* __restrict__ s1,
    const int* __restrict__ cnt, const float* __restrict__ Wl1,
    const float* __restrict__ bl1, float* __restrict__ h1)
{
  __shared__ float As[16][64];
  __shared__ float Bs[16][128];
  const int t = threadIdx.x;
  const int tx = t & 15, ty = t >> 4;
  const int row0 = blockIdx.x * 64, col0 = blockIdx.y * 128;
  const int am = t >> 2, ak0 = (t & 3) * 4;
  const int gra = row0 + am;
  const int r = (gra < NN) ? gra : (NN - 1);
  const float inv = 1.f / fmaxf((float)cnt[r], 1.f);

  float acc[4][8];
#pragma unroll
  for (int i = 0; i < 4; i++)
#pragma unroll
    for (int j = 0; j < 8; j++) acc[i][j] = 0.f;

  for (int kt = 0; kt < 256; kt += 16) {
    const int k = kt + ak0;
    float4 av;
    if (k < 128) {
      av = *(const float4*)&nf[(size_t)r * 128 + k];
    } else {
      av = *(const float4*)&s1[(size_t)r * 128 + (k - 128)];
      av.x *= inv; av.y *= inv; av.z *= inv; av.w *= inv;
    }
    As[ak0 + 0][am] = av.x; As[ak0 + 1][am] = av.y;
    As[ak0 + 2][am] = av.z; As[ak0 + 3][am] = av.w;
    *(float4*)&Bs[ty][tx * 8]     = *(const float4*)&Wl1[(size_t)(kt + ty) * 256 + col0 + tx * 8];
    *(float4*)&Bs[ty][tx * 8 + 4] = *(const float4*)&Wl1[(size_t)(kt + ty) * 256 + col0 + tx * 8 + 4];
    __syncthreads();
#pragma unroll
    for (int kk = 0; kk < 16; ++kk) {
      const float4 a = *(const float4*)&As[kk][ty * 4];
      const float4 p = *(const float4*)&Bs[kk][tx * 8];
      const float4 q = *(const float4*)&Bs[kk][tx * 8 + 4];
      const float aa[4] = {a.x, a.y, a.z, a.w};
#pragma unroll
      for (int i = 0; i < 4; ++i) {
        acc[i][0] = fmaf(aa[i], p.x, acc[i][0]);
        acc[i][1] = fmaf(aa[i], p.y, acc[i][1]);
        acc[i][2] = fmaf(aa[i], p.z, acc[i][2]);
        acc[i][3] = fmaf(aa[i], p.w, acc[i][3]);
        acc[i][4] = fmaf(aa[i], q.x, acc[i][4]);
        acc[i][5] = fmaf(aa[i], q.y, acc[i][5]);
        acc[i][6] = fmaf(aa[i], q.z, acc[i][6]);
        acc[i][7] = fmaf(aa[i], q.w, acc[i][7]);
      }
    }
    __syncthreads();
  }

  const float4 b0 = *(const float4*)&bl1[col0 + tx * 8];
  const float4 b1 = *(const float4*)&bl1[col0 + tx * 8 + 4];
#pragma unroll
  for (int i = 0; i < 4; ++i) {
    const int gr = row0 + ty * 4 + i;
    if (gr >= NN) continue;
    float4 v0, v1;
    v0.x = fmaxf(acc[i][0] + b0.x, 0.f);
    v0.y = fmaxf(acc[i][1] + b0.y, 0.f);
    v0.z = fmaxf(acc[i][2] + b0.z, 0.f);
    v0.w = fmaxf(acc[i][3] + b0.w, 0.f);
    v1.x = fmaxf(acc[i][4] + b1.x, 0.f);
    v1.y = fmaxf(acc[i][5] + b1.y, 0.f);
    v1.z = fmaxf(acc[i][6] + b1.z, 0.f);
    v1.w = fmaxf(acc[i][7] + b1.w, 0.f);
    *(float4*)&h1[(size_t)gr * 256 + col0 + tx * 8] = v0;
    *(float4*)&h1[(size_t)gr * 256 + col0 + tx * 8 + 4] = v1;
  }
}

// ---------------- final linear: out = concat(h1, s2/cnt) @ Wl2 + bl2 ----------

__global__ __launch_bounds__(256) void out_k(
    const float* __restrict__ h1, const float* __restrict__ s2,
    const int* __restrict__ cnt, const float* __restrict__ Wl2,
    const float* __restrict__ bl2, float* __restrict__ out)
{
  __shared__ float A8[8][512];
  const int n0 = blockIdx.x * 8;
  const int tx = threadIdx.x;       // 0..31 (col)
  const int ty = threadIdx.y;       // 0..7 (row)
  const int t = ty * 32 + tx;
  const int row = t >> 5;
  const int k0 = (t & 31) * 16;
  const int n = n0 + row;
  const float inv = 1.0f / fmaxf((float)cnt[n], 1.0f);
#pragma unroll
  for (int i = 0; i < 16; i += 4) {
    int k = k0 + i;
    float4 v;
    if (k < 256) {
      v = *(const float4*)&h1[(size_t)n * 256 + k];
    } else {
      v = *(const float4*)&s2[(size_t)n * 256 + (k - 256)];
      v.x *= inv; v.y *= inv; v.z *= inv; v.w *= inv;
    }
    *(float4*)&A8[row][k] = v;
  }
  __syncthreads();
  float acc = bl2[tx];
#pragma unroll 8
  for (int k = 0; k < 512; k++) acc = fmaf(A8[ty][k], Wl2[(size_t)k * 32 + tx], acc);
  out[(size_t)(n0 + ty) * 32 + tx] = acc;
}

// ---------------- launch ------------------------------------------------------

extern "C" void kernel_launch(void* const* d_in, const int* in_sizes, int n_in,
                              void* d_out, int out_size, void* d_ws, size_t ws_size,
                              hipStream_t stream) {
  const float* nf   = (const float*)d_in[0];
  const float* ef   = (const float*)d_in[1];
  const int*   src  = (const int*)d_in[2];
  const int*   dst  = (const int*)d_in[3];
  const float* We1  = (const float*)d_in[4];
  const float* be1  = (const float*)d_in[5];
  const float* Wr1a = (const float*)d_in[6];
  const float* br1a = (const float*)d_in[7];
  const float* Wr1b = (const float*)d_in[8];
  const float* br1b = (const float*)d_in[9];
  const float* Wl1  = (const float*)d_in[10];
  const float* bl1  = (const float*)d_in[11];
  const float* We2  = (const float*)d_in[12];
  const float* be2  = (const float*)d_in[13];
  const float* Wr2a = (const float*)d_in[14];
  const float* br2a = (const float*)d_in[15];
  const float* Wr2b = (const float*)d_in[16];
  const float* br2b = (const float*)d_in[17];
  const float* Wl2  = (const float*)d_in[18];
  const float* bl2  = (const float*)d_in[19];

  float* ws = (float*)d_ws;
  float* s1   = ws;                             // N*128
  float* s2   = s1 + (size_t)NN * 128;          // N*256
  int*   cnt  = (int*)(s2 + (size_t)NN * 256);  // N
  float* h1   = (float*)(cnt + NN);             // N*256
  float* cos1 = h1 + (size_t)NN * 256;          // E
  float* cos2 = cos1 + NE;                      // E

  size_t need = ((size_t)NN * 128 + (size_t)NN * 256 + NN +
                 (size_t)NN * 256 + 2 * (size_t)NE) * 4;
  if (ws_size < need) return;

  // zero s1, s2, cnt (contiguous)
  hipMemsetAsync(s1, 0, ((size_t)NN * 128 + (size_t)NN * 256 + NN) * 4, stream);

  edge1_k<<<NE / 4, 256, 0, stream>>>(nf, src, dst, cos1, cnt);

  edge_mlp1<<<NE / 64, 256, 0, stream>>>(nf, ef, src, dst, We1, be1,
                                         Wr1a, br1a, Wr1b, br1b, cos1, s1);

  h1_k<<<dim3(782, 2), 256, 0, stream>>>(nf, s1, cnt, Wl1, bl1, h1);

  edge2_k<<<NE / 4, 256, 0, stream>>>(h1, src, dst, cos2);

  edge_mlp2<<<NE / 32, 256, 0, stream>>>(h1, ef, src, dst, We1, be1, We2, be2,
                                         Wr2a, br2a, Wr2b, br2b, cos2, s2);

  out_k<<<NN / 8, dim3(32, 8), 0, stream>>>(h1, s2, cnt, Wl2, bl2, (float*)d_out);
}

// Round 3
// 4769.821 us; speedup vs baseline: 2.3782x; 2.3782x over previous
//
#include <hip/hip_runtime.h>
#include <math.h>

#define NN 50000
#define NE 800000

typedef short bf8 __attribute__((ext_vector_type(8)));
typedef short bf4v __attribute__((ext_vector_type(4)));
typedef float f4 __attribute__((ext_vector_type(4)));

// float -> bf16 bits, round-to-nearest-even (values are finite)
__device__ __forceinline__ short f2b(float f) {
  unsigned int u = __float_as_uint(f);
  unsigned int r = (u + 0x7FFFu + ((u >> 16) & 1u)) >> 16;
  return (short)(unsigned short)r;
}

// ---------------- weight transpose + bf16 convert -----------------------------
// in: W[K][N] fp32 row-major.  out: WT[N][K] bf16 (n-major, k contiguous).
__global__ __launch_bounds__(256) void wt_k(const float* __restrict__ in,
                                            short* __restrict__ out,
                                            int K, int N) {
  int i = blockIdx.x * 256 + threadIdx.x;
  if (i >= K * N) return;
  int n = i / K, k = i - n * K;
  out[i] = f2b(in[(size_t)k * N + n]);
}

// ---------------- cosine + degree count kernels -------------------------------

__global__ __launch_bounds__(256) void edge1_k(
    const float* __restrict__ nf,
    const int* __restrict__ src, const int* __restrict__ dst,
    float* __restrict__ cos1, int* __restrict__ cnt)
{
  int wid = blockIdx.x * 4 + (threadIdx.x >> 6);
  if (wid >= NE) return;
  int lane = threadIdx.x & 63;
  int s = src[wid], d = dst[wid];
  float2 hs = *(const float2*)&nf[(size_t)s * 128 + lane * 2];
  float2 hd = *(const float2*)&nf[(size_t)d * 128 + lane * 2];
  float ss = hs.x * hs.x + hs.y * hs.y;
  float dd = hd.x * hd.x + hd.y * hd.y;
  float sd = hs.x * hd.x + hs.y * hd.y;
#pragma unroll
  for (int o = 32; o >= 1; o >>= 1) {
    ss += __shfl_xor(ss, o);
    dd += __shfl_xor(dd, o);
    sd += __shfl_xor(sd, o);
  }
  if (lane == 0) {
    cos1[wid] = sd / (fmaxf(sqrtf(ss), 1e-12f) * fmaxf(sqrtf(dd), 1e-12f));
    atomicAdd(&cnt[d], 1);
  }
}

__global__ __launch_bounds__(256) void edge2_k(
    const float* __restrict__ h1,
    const int* __restrict__ src, const int* __restrict__ dst,
    float* __restrict__ cos2)
{
  int wid = blockIdx.x * 4 + (threadIdx.x >> 6);
  if (wid >= NE) return;
  int lane = threadIdx.x & 63;
  int s = src[wid], d = dst[wid];
  float4 a = *(const float4*)&h1[(size_t)s * 256 + lane * 4];
  float4 b = *(const float4*)&h1[(size_t)d * 256 + lane * 4];
  float ss = a.x * a.x + a.y * a.y + a.z * a.z + a.w * a.w;
  float dd = b.x * b.x + b.y * b.y + b.z * b.z + b.w * b.w;
  float sd = a.x * b.x + a.y * b.y + a.z * b.z + a.w * b.w;
#pragma unroll
  for (int o = 32; o >= 1; o >>= 1) {
    ss += __shfl_xor(ss, o);
    dd += __shfl_xor(dd, o);
    sd += __shfl_xor(sd, o);
  }
  if (lane == 0)
    cos2[wid] = sd / (fmaxf(sqrtf(ss), 1e-12f) * fmaxf(sqrtf(dd), 1e-12f));
}

// ---------------- fused edge-MLP layer 1 (bf16 MFMA) --------------------------
// 64 edges/block.  M[e][k] = cos*w1*nf[src] (bf16, LDS).
// stage1: T^T = WaT @ M^T  (relu+bias) -> Ms (in place)
// stage2: R^T = WbT @ T^T  (relu+bias) -> atomicAdd s1[dst]
// wave tile: 32 n  x 64 e  (2 n-tiles x 4 e-tiles)

__global__ __launch_bounds__(256, 4) void edge_mlp1(
    const float* __restrict__ nf, const float* __restrict__ ef,
    const int* __restrict__ src, const int* __restrict__ dst,
    const float* __restrict__ We1, const float* __restrict__ be1,
    const short* __restrict__ WaT, const float* __restrict__ ba,
    const short* __restrict__ WbT, const float* __restrict__ bbv,
    const float* __restrict__ cosv, float* __restrict__ s1)
{
  __shared__ __align__(16) short Ms[64 * 136];  // pitch 136 -> 4-bank row skew
  const int t = threadIdx.x;
  const int e0 = blockIdx.x * 64;

  // ---- build message tile M (bf16) ----
  {
    const int e = t >> 2;
    const int kb = (t & 3) * 32;
    const int ge = e0 + e;
    const int s = src[ge];
    const float c = cosv[ge];
    const float f0 = ef[2 * ge], f1 = ef[2 * ge + 1];
    const float* hrow = &nf[(size_t)s * 128];
#pragma unroll
    for (int j = 0; j < 4; ++j) {
      const int k = kb + j * 8;
      f4 h0 = *(const f4*)&hrow[k];
      f4 h1v = *(const f4*)&hrow[k + 4];
      f4 wa0 = *(const f4*)&We1[k];
      f4 wa1 = *(const f4*)&We1[k + 4];
      f4 wb0 = *(const f4*)&We1[128 + k];
      f4 wb1 = *(const f4*)&We1[128 + k + 4];
      f4 b0 = *(const f4*)&be1[k];
      f4 b1 = *(const f4*)&be1[k + 4];
      bf8 pk;
#pragma unroll
      for (int x = 0; x < 4; ++x) {
        pk[x]     = f2b(c * fmaf(f0, wa0[x], fmaf(f1, wb0[x], b0[x])) * h0[x]);
        pk[x + 4] = f2b(c * fmaf(f0, wa1[x], fmaf(f1, wb1[x], b1[x])) * h1v[x]);
      }
      *(bf8*)&Ms[e * 136 + k] = pk;
    }
  }
  __syncthreads();

  const int lane = t & 63, wv = t >> 6;
  const int lr = lane & 15;   // e-col within tile / n-row for A
  const int lq = lane >> 4;   // quad
  const int n0 = wv * 32;

  f4 acc[2][4];
#pragma unroll
  for (int a = 0; a < 2; ++a)
#pragma unroll
    for (int b = 0; b < 4; ++b) acc[a][b] = (f4)0.f;

  // ---- stage 1: K = 128 ----
#pragma unroll
  for (int kc = 0; kc < 128; kc += 32) {
    bf8 aF[2], bF[4];
#pragma unroll
    for (int a = 0; a < 2; ++a)
      aF[a] = *(const bf8*)&WaT[(size_t)(n0 + a * 16 + lr) * 128 + kc + lq * 8];
#pragma unroll
    for (int b = 0; b < 4; ++b)
      bF[b] = *(const bf8*)&Ms[(b * 16 + lr) * 136 + kc + lq * 8];
#pragma unroll
    for (int a = 0; a < 2; ++a)
#pragma unroll
      for (int b = 0; b < 4; ++b)
        acc[a][b] = __builtin_amdgcn_mfma_f32_16x16x32_bf16(aF[a], bF[b], acc[a][b], 0, 0, 0);
  }
  __syncthreads();  // all waves done reading M before overwrite

  // T[e][n] = relu(acc + ba[n]) -> Ms (row-major [e][n])
#pragma unroll
  for (int a = 0; a < 2; ++a) {
    const int n = n0 + a * 16 + lq * 4;
    f4 bb = *(const f4*)&ba[n];
#pragma unroll
    for (int b = 0; b < 4; ++b) {
      bf4v pk;
#pragma unroll
      for (int r = 0; r < 4; ++r) pk[r] = f2b(fmaxf(acc[a][b][r] + bb[r], 0.f));
      *(bf4v*)&Ms[(b * 16 + lr) * 136 + n] = pk;
    }
  }
  __syncthreads();

  // ---- stage 2: K = 128 ----
#pragma unroll
  for (int a = 0; a < 2; ++a)
#pragma unroll
    for (int b = 0; b < 4; ++b) acc[a][b] = (f4)0.f;
#pragma unroll
  for (int kc = 0; kc < 128; kc += 32) {
    bf8 aF[2], bF[4];
#pragma unroll
    for (int a = 0; a < 2; ++a)
      aF[a] = *(const bf8*)&WbT[(size_t)(n0 + a * 16 + lr) * 128 + kc + lq * 8];
#pragma unroll
    for (int b = 0; b < 4; ++b)
      bF[b] = *(const bf8*)&Ms[(b * 16 + lr) * 136 + kc + lq * 8];
#pragma unroll
    for (int a = 0; a < 2; ++a)
#pragma unroll
      for (int b = 0; b < 4; ++b)
        acc[a][b] = __builtin_amdgcn_mfma_f32_16x16x32_bf16(aF[a], bF[b], acc[a][b], 0, 0, 0);
  }

  // epilogue: relu + scatter (4 consecutive addresses per lane)
#pragma unroll
  for (int b = 0; b < 4; ++b) {
    const int d = dst[e0 + b * 16 + lr];
    float* orow = &s1[(size_t)d * 128];
#pragma unroll
    for (int a = 0; a < 2; ++a) {
      const int n = n0 + a * 16 + lq * 4;
      f4 bb = *(const f4*)&bbv[n];
      atomicAdd(&orow[n + 0], fmaxf(acc[a][b][0] + bb[0], 0.f));
      atomicAdd(&orow[n + 1], fmaxf(acc[a][b][1] + bb[1], 0.f));
      atomicAdd(&orow[n + 2], fmaxf(acc[a][b][2] + bb[2], 0.f));
      atomicAdd(&orow[n + 3], fmaxf(acc[a][b][3] + bb[3], 0.f));
    }
  }
}

// ---------------- fused edge-MLP layer 2 (bf16 MFMA) --------------------------
// 64 edges/block.  w1r = relu(ef@We1+be1) bf16 (LDS).
// stageB: w2^T = We2T @ w1r^T; m2 = (w2+be2)*cos2*h1[src] -> M2s
// stageC: t2^T = WaT @ m2^T (relu) -> M2s (in place)
// stageD: r2^T = WbT @ t2^T (relu) -> atomicAdd s2[dst]
// wave tile: 64 n x 64 e (4x4 tiles)

__global__ __launch_bounds__(256, 3) void edge_mlp2(
    const float* __restrict__ h1g, const float* __restrict__ ef,
    const int* __restrict__ src, const int* __restrict__ dst,
    const float* __restrict__ We1, const float* __restrict__ be1,
    const short* __restrict__ We2T, const float* __restrict__ be2,
    const short* __restrict__ WaT, const float* __restrict__ ba,
    const short* __restrict__ WbT, const float* __restrict__ bbv,
    const float* __restrict__ cosv, float* __restrict__ s2)
{
  __shared__ __align__(16) short Ws[64 * 136];
  __shared__ __align__(16) short M2s[64 * 264];
  const int t = threadIdx.x;
  const int e0 = blockIdx.x * 64;

  // ---- build relu(w1) tile (bf16) ----
  {
    const int e = t >> 2;
    const int kb = (t & 3) * 32;
    const int ge = e0 + e;
    const float f0 = ef[2 * ge], f1 = ef[2 * ge + 1];
#pragma unroll
    for (int j = 0; j < 4; ++j) {
      const int k = kb + j * 8;
      f4 wa0 = *(const f4*)&We1[k];
      f4 wa1 = *(const f4*)&We1[k + 4];
      f4 wb0 = *(const f4*)&We1[128 + k];
      f4 wb1 = *(const f4*)&We1[128 + k + 4];
      f4 b0 = *(const f4*)&be1[k];
      f4 b1 = *(const f4*)&be1[k + 4];
      bf8 pk;
#pragma unroll
      for (int x = 0; x < 4; ++x) {
        pk[x]     = f2b(fmaxf(fmaf(f0, wa0[x], fmaf(f1, wb0[x], b0[x])), 0.f));
        pk[x + 4] = f2b(fmaxf(fmaf(f0, wa1[x], fmaf(f1, wb1[x], b1[x])), 0.f));
      }
      *(bf8*)&Ws[e * 136 + k] = pk;
    }
  }
  __syncthreads();

  const int lane = t & 63, wv = t >> 6;
  const int lr = lane & 15;
  const int lq = lane >> 4;
  const int n0 = wv * 64;

  f4 acc[4][4];
#pragma unroll
  for (int a = 0; a < 4; ++a)
#pragma unroll
    for (int b = 0; b < 4; ++b) acc[a][b] = (f4)0.f;

  // ---- stage B: K = 128 ----
#pragma unroll
  for (int kc = 0; kc < 128; kc += 32) {
    bf8 aF[4], bF[4];
#pragma unroll
    for (int a = 0; a < 4; ++a)
      aF[a] = *(const bf8*)&We2T[(size_t)(n0 + a * 16 + lr) * 128 + kc + lq * 8];
#pragma unroll
    for (int b = 0; b < 4; ++b)
      bF[b] = *(const bf8*)&Ws[(b * 16 + lr) * 136 + kc + lq * 8];
#pragma unroll
    for (int a = 0; a < 4; ++a)
#pragma unroll
      for (int b = 0; b < 4; ++b)
        acc[a][b] = __builtin_amdgcn_mfma_f32_16x16x32_bf16(aF[a], bF[b], acc[a][b], 0, 0, 0);
  }

  // epilogue: m2[e][n] = (w2 + be2[n]) * cos2[e] * h1[src[e]][n] -> M2s
#pragma unroll
  for (int b = 0; b < 4; ++b) {
    const int ge = e0 + b * 16 + lr;
    const int s = src[ge];
    const float c = cosv[ge];
    const float* hrow = &h1g[(size_t)s * 256];
#pragma unroll
    for (int a = 0; a < 4; ++a) {
      const int n = n0 + a * 16 + lq * 4;
      f4 bb = *(const f4*)&be2[n];
      f4 hv = *(const f4*)&hrow[n];
      bf4v pk;
#pragma unroll
      for (int r = 0; r < 4; ++r)
        pk[r] = f2b((acc[a][b][r] + bb[r]) * c * hv[r]);
      *(bf4v*)&M2s[(b * 16 + lr) * 264 + n] = pk;
    }
  }
  __syncthreads();

  // ---- stage C: K = 256, relu ----
#pragma unroll
  for (int a = 0; a < 4; ++a)
#pragma unroll
    for (int b = 0; b < 4; ++b) acc[a][b] = (f4)0.f;
  for (int kc = 0; kc < 256; kc += 32) {
    bf8 aF[4], bF[4];
#pragma unroll
    for (int a = 0; a < 4; ++a)
      aF[a] = *(const bf8*)&WaT[(size_t)(n0 + a * 16 + lr) * 256 + kc + lq * 8];
#pragma unroll
    for (int b = 0; b < 4; ++b)
      bF[b] = *(const bf8*)&M2s[(b * 16 + lr) * 264 + kc + lq * 8];
#pragma unroll
    for (int a = 0; a < 4; ++a)
#pragma unroll
      for (int b = 0; b < 4; ++b)
        acc[a][b] = __builtin_amdgcn_mfma_f32_16x16x32_bf16(aF[a], bF[b], acc[a][b], 0, 0, 0);
  }
  __syncthreads();  // all waves done reading m2 before overwrite

#pragma unroll
  for (int a = 0; a < 4; ++a) {
    const int n = n0 + a * 16 + lq * 4;
    f4 bb = *(const f4*)&ba[n];
#pragma unroll
    for (int b = 0; b < 4; ++b) {
      bf4v pk;
#pragma unroll
      for (int r = 0; r < 4; ++r) pk[r] = f2b(fmaxf(acc[a][b][r] + bb[r], 0.f));
      *(bf4v*)&M2s[(b * 16 + lr) * 264 + n] = pk;
    }
  }
  __syncthreads();

  // ---- stage D: K = 256 ----
#pragma unroll
  for (int a = 0; a < 4; ++a)
#pragma unroll
    for (int b = 0; b < 4; ++b) acc[a][b] = (f4)0.f;
  for (int kc = 0; kc < 256; kc += 32) {
    bf8 aF[4], bF[4];
#pragma unroll
    for (int a = 0; a < 4; ++a)
      aF[a] = *(const bf8*)&WbT[(size_t)(n0 + a * 16 + lr) * 256 + kc + lq * 8];
#pragma unroll
    for (int b = 0; b < 4; ++b)
      bF[b] = *(const bf8*)&M2s[(b * 16 + lr) * 264 + kc + lq * 8];
#pragma unroll
    for (int a = 0; a < 4; ++a)
#pragma unroll
      for (int b = 0; b < 4; ++b)
        acc[a][b] = __builtin_amdgcn_mfma_f32_16x16x32_bf16(aF[a], bF[b], acc[a][b], 0, 0, 0);
  }

#pragma unroll
  for (int b = 0; b < 4; ++b) {
    const int d = dst[e0 + b * 16 + lr];
    float* orow = &s2[(size_t)d * 256];
#pragma unroll
    for (int a = 0; a < 4; ++a) {
      const int n = n0 + a * 16 + lq * 4;
      f4 bb = *(const f4*)&bbv[n];
      atomicAdd(&orow[n + 0], fmaxf(acc[a][b][0] + bb[0], 0.f));
      atomicAdd(&orow[n + 1], fmaxf(acc[a][b][1] + bb[1], 0.f));
      atomicAdd(&orow[n + 2], fmaxf(acc[a][b][2] + bb[2], 0.f));
      atomicAdd(&orow[n + 3], fmaxf(acc[a][b][3] + bb[3], 0.f));
    }
  }
}

// ---------------- node linear 1: h1 = relu(concat(nf, s1/cnt) @ Wl1 + bl1) ----

__global__ __launch_bounds__(256) void h1_k(
    const float* __restrict__ nf, const float* __restrict__ s1,
    const int* __restrict__ cnt, const float* __restrict__ Wl1,
    const float* __restrict__ bl1, float* __restrict__ h1)
{
  __shared__ float As[16][64];
  __shared__ float Bs[16][128];
  const int t = threadIdx.x;
  const int tx = t & 15, ty = t >> 4;
  const int row0 = blockIdx.x * 64, col0 = blockIdx.y * 128;
  const int am = t >> 2, ak0 = (t & 3) * 4;
  const int gra = row0 + am;
  const int r = (gra < NN) ? gra : (NN - 1);
  const float inv = 1.f / fmaxf((float)cnt[r], 1.f);

  float acc[4][8];
#pragma unroll
  for (int i = 0; i < 4; i++)
#pragma unroll
    for (int j = 0; j < 8; j++) acc[i][j] = 0.f;

  for (int kt = 0; kt < 256; kt += 16) {
    const int k = kt + ak0;
    float4 av;
    if (k < 128) {
      av = *(const float4*)&nf[(size_t)r * 128 + k];
    } else {
      av = *(const float4*)&s1[(size_t)r * 128 + (k - 128)];
      av.x *= inv; av.y *= inv; av.z *= inv; av.w *= inv;
    }
    As[ak0 + 0][am] = av.x; As[ak0 + 1][am] = av.y;
    As[ak0 + 2][am] = av.z; As[ak0 + 3][am] = av.w;
    *(float4*)&Bs[ty][tx * 8]     = *(const float4*)&Wl1[(size_t)(kt + ty) * 256 + col0 + tx * 8];
    *(float4*)&Bs[ty][tx * 8 + 4] = *(const float4*)&Wl1[(size_t)(kt + ty) * 256 + col0 + tx * 8 + 4];
    __syncthreads();
#pragma unroll
    for (int kk = 0; kk < 16; ++kk) {
      const float4 a = *(const float4*)&As[kk][ty * 4];
      const float4 p = *(const float4*)&Bs[kk][tx * 8];
      const float4 q = *(const float4*)&Bs[kk][tx * 8 + 4];
      const float aa[4] = {a.x, a.y, a.z, a.w};
#pragma unroll
      for (int i = 0; i < 4; ++i) {
        acc[i][0] = fmaf(aa[i], p.x, acc[i][0]);
        acc[i][1] = fmaf(aa[i], p.y, acc[i][1]);
        acc[i][2] = fmaf(aa[i], p.z, acc[i][2]);
        acc[i][3] = fmaf(aa[i], p.w, acc[i][3]);
        acc[i][4] = fmaf(aa[i], q.x, acc[i][4]);
        acc[i][5] = fmaf(aa[i], q.y, acc[i][5]);
        acc[i][6] = fmaf(aa[i], q.z, acc[i][6]);
        acc[i][7] = fmaf(aa[i], q.w, acc[i][7]);
      }
    }
    __syncthreads();
  }

  const float4 b0 = *(const float4*)&bl1[col0 + tx * 8];
  const float4 b1 = *(const float4*)&bl1[col0 + tx * 8 + 4];
#pragma unroll
  for (int i = 0; i < 4; ++i) {
    const int gr = row0 + ty * 4 + i;
    if (gr >= NN) continue;
    float4 v0, v1;
    v0.x = fmaxf(acc[i][0] + b0.x, 0.f);
    v0.y = fmaxf(acc[i][1] + b0.y, 0.f);
    v0.z = fmaxf(acc[i][2] + b0.z, 0.f);
    v0.w = fmaxf(acc[i][3] + b0.w, 0.f);
    v1.x = fmaxf(acc[i][4] + b1.x, 0.f);
    v1.y = fmaxf(acc[i][5] + b1.y, 0.f);
    v1.z = fmaxf(acc[i][6] + b1.z, 0.f);
    v1.w = fmaxf(acc[i][7] + b1.w, 0.f);
    *(float4*)&h1[(size_t)gr * 256 + col0 + tx * 8] = v0;
    *(float4*)&h1[(size_t)gr * 256 + col0 + tx * 8 + 4] = v1;
  }
}

// ---------------- final linear: out = concat(h1, s2/cnt) @ Wl2 + bl2 ----------

__global__ __launch_bounds__(256) void out_k(
    const float* __restrict__ h1, const float* __restrict__ s2,
    const int* __restrict__ cnt, const float* __restrict__ Wl2,
    const float* __restrict__ bl2, float* __restrict__ out)
{
  __shared__ float A8[8][512];
  const int n0 = blockIdx.x * 8;
  const int tx = threadIdx.x;
  const int ty = threadIdx.y;
  const int t = ty * 32 + tx;
  const int row = t >> 5;
  const int k0 = (t & 31) * 16;
  const int n = n0 + row;
  const float inv = 1.0f / fmaxf((float)cnt[n], 1.0f);
#pragma unroll
  for (int i = 0; i < 16; i += 4) {
    int k = k0 + i;
    float4 v;
    if (k < 256) {
      v = *(const float4*)&h1[(size_t)n * 256 + k];
    } else {
      v = *(const float4*)&s2[(size_t)n * 256 + (k - 256)];
      v.x *= inv; v.y *= inv; v.z *= inv; v.w *= inv;
    }
    *(float4*)&A8[row][k] = v;
  }
  __syncthreads();
  float acc = bl2[tx];
#pragma unroll 8
  for (int k = 0; k < 512; k++) acc = fmaf(A8[ty][k], Wl2[(size_t)k * 32 + tx], acc);
  out[(size_t)(n0 + ty) * 32 + tx] = acc;
}

// ---------------- launch ------------------------------------------------------

extern "C" void kernel_launch(void* const* d_in, const int* in_sizes, int n_in,
                              void* d_out, int out_size, void* d_ws, size_t ws_size,
                              hipStream_t stream) {
  const float* nf   = (const float*)d_in[0];
  const float* ef   = (const float*)d_in[1];
  const int*   src  = (const int*)d_in[2];
  const int*   dst  = (const int*)d_in[3];
  const float* We1  = (const float*)d_in[4];
  const float* be1  = (const float*)d_in[5];
  const float* Wr1a = (const float*)d_in[6];
  const float* br1a = (const float*)d_in[7];
  const float* Wr1b = (const float*)d_in[8];
  const float* br1b = (const float*)d_in[9];
  const float* Wl1  = (const float*)d_in[10];
  const float* bl1  = (const float*)d_in[11];
  const float* We2  = (const float*)d_in[12];
  const float* be2  = (const float*)d_in[13];
  const float* Wr2a = (const float*)d_in[14];
  const float* br2a = (const float*)d_in[15];
  const float* Wr2b = (const float*)d_in[16];
  const float* br2b = (const float*)d_in[17];
  const float* Wl2  = (const float*)d_in[18];
  const float* bl2  = (const float*)d_in[19];

  float* ws = (float*)d_ws;
  float* s1   = ws;                             // N*128
  float* s2   = s1 + (size_t)NN * 128;          // N*256
  int*   cnt  = (int*)(s2 + (size_t)NN * 256);  // N
  float* h1   = (float*)(cnt + NN);             // N*256
  float* cos1 = h1 + (size_t)NN * 256;          // E
  float* cos2 = cos1 + NE;                      // E
  short* WaT1 = (short*)(cos2 + NE);            // 128*128 bf16
  short* WbT1 = WaT1 + 128 * 128;               // 128*128
  short* We2T = WbT1 + 128 * 128;               // 256*128
  short* WaT2 = We2T + 256 * 128;               // 256*256
  short* WbT2 = WaT2 + 256 * 256;               // 256*256

  size_t need = ((size_t)NN * 128 + (size_t)NN * 256 + NN +
                 (size_t)NN * 256 + 2 * (size_t)NE) * 4 +
                ((size_t)128 * 128 * 2 + (size_t)256 * 128 +
                 (size_t)256 * 256 * 2) * 2;
  if (ws_size < need) return;

  // transpose+convert weights to bf16 (tiny)
  wt_k<<<(128 * 128 + 255) / 256, 256, 0, stream>>>(Wr1a, WaT1, 128, 128);
  wt_k<<<(128 * 128 + 255) / 256, 256, 0, stream>>>(Wr1b, WbT1, 128, 128);
  wt_k<<<(128 * 256 + 255) / 256, 256, 0, stream>>>(We2, We2T, 128, 256);
  wt_k<<<(256 * 256 + 255) / 256, 256, 0, stream>>>(Wr2a, WaT2, 256, 256);
  wt_k<<<(256 * 256 + 255) / 256, 256, 0, stream>>>(Wr2b, WbT2, 256, 256);

  // zero s1, s2, cnt (contiguous)
  hipMemsetAsync(s1, 0, ((size_t)NN * 128 + (size_t)NN * 256 + NN) * 4, stream);

  edge1_k<<<NE / 4, 256, 0, stream>>>(nf, src, dst, cos1, cnt);

  edge_mlp1<<<NE / 64, 256, 0, stream>>>(nf, ef, src, dst, We1, be1,
                                         WaT1, br1a, WbT1, br1b, cos1, s1);

  h1_k<<<dim3(782, 2), 256, 0, stream>>>(nf, s1, cnt, Wl1, bl1, h1);

  edge2_k<<<NE / 4, 256, 0, stream>>>(h1, src, dst, cos2);

  edge_mlp2<<<NE / 64, 256, 0, stream>>>(h1, ef, src, dst, We1, be1, We2T, be2,
                                         WaT2, br2a, WbT2, br2b, cos2, s2);

  out_k<<<NN / 8, dim3(32, 8), 0, stream>>>(h1, s2, cnt, Wl2, bl2, (float*)d_out);
}

// Round 4
// 4700.984 us; speedup vs baseline: 2.4130x; 1.0146x over previous
//
#include <hip/hip_runtime.h>
#include <math.h>

#define NN 50000
#define NE 800000

typedef short bf8 __attribute__((ext_vector_type(8)));
typedef short bf4v __attribute__((ext_vector_type(4)));
typedef float f4 __attribute__((ext_vector_type(4)));
typedef float f2v __attribute__((ext_vector_type(2)));

// float -> bf16 bits, round-to-nearest-even (values are finite)
__device__ __forceinline__ short f2b(float f) {
  unsigned int u = __float_as_uint(f);
  unsigned int r = (u + 0x7FFFu + ((u >> 16) & 1u)) >> 16;
  return (short)(unsigned short)r;
}

// packed 2xfp32 atomic add (gfx90a+ pk_add_f32). 8B granule instead of 2x16B.
__device__ __forceinline__ void atomadd2(float* p, float x, float y) {
#if __has_builtin(__builtin_amdgcn_flat_atomic_fadd_v2f32)
  f2v v = {x, y};
  __builtin_amdgcn_flat_atomic_fadd_v2f32((f2v*)p, v);
#else
  atomicAdd(p, x);
  atomicAdd(p + 1, y);
#endif
}

// ---------------- weight transpose + bf16 convert -----------------------------
// in: W[K][N] fp32 row-major.  out: WT[N][K] bf16 (n-major, k contiguous).
__global__ __launch_bounds__(256) void wt_k(const float* __restrict__ in,
                                            short* __restrict__ out,
                                            int K, int N) {
  int i = blockIdx.x * 256 + threadIdx.x;
  if (i >= K * N) return;
  int n = i / K, k = i - n * K;
  out[i] = f2b(in[(size_t)k * N + n]);
}

// ---------------- cosine + degree count kernels -------------------------------

__global__ __launch_bounds__(256) void edge1_k(
    const float* __restrict__ nf,
    const int* __restrict__ src, const int* __restrict__ dst,
    float* __restrict__ cos1, int* __restrict__ cnt)
{
  int wid = blockIdx.x * 4 + (threadIdx.x >> 6);
  if (wid >= NE) return;
  int lane = threadIdx.x & 63;
  int s = src[wid], d = dst[wid];
  float2 hs = *(const float2*)&nf[(size_t)s * 128 + lane * 2];
  float2 hd = *(const float2*)&nf[(size_t)d * 128 + lane * 2];
  float ss = hs.x * hs.x + hs.y * hs.y;
  float dd = hd.x * hd.x + hd.y * hd.y;
  float sd = hs.x * hd.x + hs.y * hd.y;
#pragma unroll
  for (int o = 32; o >= 1; o >>= 1) {
    ss += __shfl_xor(ss, o);
    dd += __shfl_xor(dd, o);
    sd += __shfl_xor(sd, o);
  }
  if (lane == 0) {
    cos1[wid] = sd / (fmaxf(sqrtf(ss), 1e-12f) * fmaxf(sqrtf(dd), 1e-12f));
    atomicAdd(&cnt[d], 1);
  }
}

__global__ __launch_bounds__(256) void edge2_k(
    const float* __restrict__ h1,
    const int* __restrict__ src, const int* __restrict__ dst,
    float* __restrict__ cos2)
{
  int wid = blockIdx.x * 4 + (threadIdx.x >> 6);
  if (wid >= NE) return;
  int lane = threadIdx.x & 63;
  int s = src[wid], d = dst[wid];
  float4 a = *(const float4*)&h1[(size_t)s * 256 + lane * 4];
  float4 b = *(const float4*)&h1[(size_t)d * 256 + lane * 4];
  float ss = a.x * a.x + a.y * a.y + a.z * a.z + a.w * a.w;
  float dd = b.x * b.x + b.y * b.y + b.z * b.z + b.w * b.w;
  float sd = a.x * b.x + a.y * b.y + a.z * b.z + a.w * b.w;
#pragma unroll
  for (int o = 32; o >= 1; o >>= 1) {
    ss += __shfl_xor(ss, o);
    dd += __shfl_xor(dd, o);
    sd += __shfl_xor(sd, o);
  }
  if (lane == 0)
    cos2[wid] = sd / (fmaxf(sqrtf(ss), 1e-12f) * fmaxf(sqrtf(dd), 1e-12f));
}

// ---------------- fused edge-MLP layer 1 (bf16 MFMA) --------------------------

__global__ __launch_bounds__(256, 4) void edge_mlp1(
    const float* __restrict__ nf, const float* __restrict__ ef,
    const int* __restrict__ src, const int* __restrict__ dst,
    const float* __restrict__ We1, const float* __restrict__ be1,
    const short* __restrict__ WaT, const float* __restrict__ ba,
    const short* __restrict__ WbT, const float* __restrict__ bbv,
    const float* __restrict__ cosv, float* __restrict__ s1)
{
  __shared__ __align__(16) short Ms[64 * 136];  // pitch 136 -> 4-bank row skew
  const int t = threadIdx.x;
  const int e0 = blockIdx.x * 64;

  // ---- build message tile M (bf16) ----
  {
    const int e = t >> 2;
    const int kb = (t & 3) * 32;
    const int ge = e0 + e;
    const int s = src[ge];
    const float c = cosv[ge];
    const float f0 = ef[2 * ge], f1 = ef[2 * ge + 1];
    const float* hrow = &nf[(size_t)s * 128];
#pragma unroll
    for (int j = 0; j < 4; ++j) {
      const int k = kb + j * 8;
      f4 h0 = *(const f4*)&hrow[k];
      f4 h1v = *(const f4*)&hrow[k + 4];
      f4 wa0 = *(const f4*)&We1[k];
      f4 wa1 = *(const f4*)&We1[k + 4];
      f4 wb0 = *(const f4*)&We1[128 + k];
      f4 wb1 = *(const f4*)&We1[128 + k + 4];
      f4 b0 = *(const f4*)&be1[k];
      f4 b1 = *(const f4*)&be1[k + 4];
      bf8 pk;
#pragma unroll
      for (int x = 0; x < 4; ++x) {
        pk[x]     = f2b(c * fmaf(f0, wa0[x], fmaf(f1, wb0[x], b0[x])) * h0[x]);
        pk[x + 4] = f2b(c * fmaf(f0, wa1[x], fmaf(f1, wb1[x], b1[x])) * h1v[x]);
      }
      *(bf8*)&Ms[e * 136 + k] = pk;
    }
  }
  __syncthreads();

  const int lane = t & 63, wv = t >> 6;
  const int lr = lane & 15;
  const int lq = lane >> 4;
  const int n0 = wv * 32;

  f4 acc[2][4];
#pragma unroll
  for (int a = 0; a < 2; ++a)
#pragma unroll
    for (int b = 0; b < 4; ++b) acc[a][b] = (f4)0.f;

  // ---- stage 1: K = 128 ----
#pragma unroll
  for (int kc = 0; kc < 128; kc += 32) {
    bf8 aF[2], bF[4];
#pragma unroll
    for (int a = 0; a < 2; ++a)
      aF[a] = *(const bf8*)&WaT[(size_t)(n0 + a * 16 + lr) * 128 + kc + lq * 8];
#pragma unroll
    for (int b = 0; b < 4; ++b)
      bF[b] = *(const bf8*)&Ms[(b * 16 + lr) * 136 + kc + lq * 8];
#pragma unroll
    for (int a = 0; a < 2; ++a)
#pragma unroll
      for (int b = 0; b < 4; ++b)
        acc[a][b] = __builtin_amdgcn_mfma_f32_16x16x32_bf16(aF[a], bF[b], acc[a][b], 0, 0, 0);
  }
  __syncthreads();

  // T[e][n] = relu(acc + ba[n]) -> Ms
#pragma unroll
  for (int a = 0; a < 2; ++a) {
    const int n = n0 + a * 16 + lq * 4;
    f4 bb = *(const f4*)&ba[n];
#pragma unroll
    for (int b = 0; b < 4; ++b) {
      bf4v pk;
#pragma unroll
      for (int r = 0; r < 4; ++r) pk[r] = f2b(fmaxf(acc[a][b][r] + bb[r], 0.f));
      *(bf4v*)&Ms[(b * 16 + lr) * 136 + n] = pk;
    }
  }
  __syncthreads();

  // ---- stage 2: K = 128 ----
#pragma unroll
  for (int a = 0; a < 2; ++a)
#pragma unroll
    for (int b = 0; b < 4; ++b) acc[a][b] = (f4)0.f;
#pragma unroll
  for (int kc = 0; kc < 128; kc += 32) {
    bf8 aF[2], bF[4];
#pragma unroll
    for (int a = 0; a < 2; ++a)
      aF[a] = *(const bf8*)&WbT[(size_t)(n0 + a * 16 + lr) * 128 + kc + lq * 8];
#pragma unroll
    for (int b = 0; b < 4; ++b)
      bF[b] = *(const bf8*)&Ms[(b * 16 + lr) * 136 + kc + lq * 8];
#pragma unroll
    for (int a = 0; a < 2; ++a)
#pragma unroll
      for (int b = 0; b < 4; ++b)
        acc[a][b] = __builtin_amdgcn_mfma_f32_16x16x32_bf16(aF[a], bF[b], acc[a][b], 0, 0, 0);
  }

  // epilogue: relu + packed scatter (2x pk_add per f4 group)
#pragma unroll
  for (int b = 0; b < 4; ++b) {
    const int d = dst[e0 + b * 16 + lr];
    float* orow = &s1[(size_t)d * 128];
#pragma unroll
    for (int a = 0; a < 2; ++a) {
      const int n = n0 + a * 16 + lq * 4;
      f4 bb = *(const f4*)&bbv[n];
      atomadd2(&orow[n],     fmaxf(acc[a][b][0] + bb[0], 0.f),
                             fmaxf(acc[a][b][1] + bb[1], 0.f));
      atomadd2(&orow[n + 2], fmaxf(acc[a][b][2] + bb[2], 0.f),
                             fmaxf(acc[a][b][3] + bb[3], 0.f));
    }
  }
}

// ---------------- fused edge-MLP layer 2 (bf16 MFMA) --------------------------

__global__ __launch_bounds__(256, 3) void edge_mlp2(
    const float* __restrict__ h1g, const float* __restrict__ ef,
    const int* __restrict__ src, const int* __restrict__ dst,
    const float* __restrict__ We1, const float* __restrict__ be1,
    const short* __restrict__ We2T, const float* __restrict__ be2,
    const short* __restrict__ WaT, const float* __restrict__ ba,
    const short* __restrict__ WbT, const float* __restrict__ bbv,
    const float* __restrict__ cosv, float* __restrict__ s2)
{
  __shared__ __align__(16) short Ws[64 * 136];
  __shared__ __align__(16) short M2s[64 * 264];
  const int t = threadIdx.x;
  const int e0 = blockIdx.x * 64;

  // ---- build relu(w1) tile (bf16) ----
  {
    const int e = t >> 2;
    const int kb = (t & 3) * 32;
    const int ge = e0 + e;
    const float f0 = ef[2 * ge], f1 = ef[2 * ge + 1];
#pragma unroll
    for (int j = 0; j < 4; ++j) {
      const int k = kb + j * 8;
      f4 wa0 = *(const f4*)&We1[k];
      f4 wa1 = *(const f4*)&We1[k + 4];
      f4 wb0 = *(const f4*)&We1[128 + k];
      f4 wb1 = *(const f4*)&We1[128 + k + 4];
      f4 b0 = *(const f4*)&be1[k];
      f4 b1 = *(const f4*)&be1[k + 4];
      bf8 pk;
#pragma unroll
      for (int x = 0; x < 4; ++x) {
        pk[x]     = f2b(fmaxf(fmaf(f0, wa0[x], fmaf(f1, wb0[x], b0[x])), 0.f));
        pk[x + 4] = f2b(fmaxf(fmaf(f0, wa1[x], fmaf(f1, wb1[x], b1[x])), 0.f));
      }
      *(bf8*)&Ws[e * 136 + k] = pk;
    }
  }
  __syncthreads();

  const int lane = t & 63, wv = t >> 6;
  const int lr = lane & 15;
  const int lq = lane >> 4;
  const int n0 = wv * 64;

  f4 acc[4][4];
#pragma unroll
  for (int a = 0; a < 4; ++a)
#pragma unroll
    for (int b = 0; b < 4; ++b) acc[a][b] = (f4)0.f;

  // ---- stage B: K = 128 ----
#pragma unroll
  for (int kc = 0; kc < 128; kc += 32) {
    bf8 aF[4], bF[4];
#pragma unroll
    for (int a = 0; a < 4; ++a)
      aF[a] = *(const bf8*)&We2T[(size_t)(n0 + a * 16 + lr) * 128 + kc + lq * 8];
#pragma unroll
    for (int b = 0; b < 4; ++b)
      bF[b] = *(const bf8*)&Ws[(b * 16 + lr) * 136 + kc + lq * 8];
#pragma unroll
    for (int a = 0; a < 4; ++a)
#pragma unroll
      for (int b = 0; b < 4; ++b)
        acc[a][b] = __builtin_amdgcn_mfma_f32_16x16x32_bf16(aF[a], bF[b], acc[a][b], 0, 0, 0);
  }

  // m2[e][n] = (w2 + be2[n]) * cos2[e] * h1[src[e]][n] -> M2s
#pragma unroll
  for (int b = 0; b < 4; ++b) {
    const int ge = e0 + b * 16 + lr;
    const int s = src[ge];
    const float c = cosv[ge];
    const float* hrow = &h1g[(size_t)s * 256];
#pragma unroll
    for (int a = 0; a < 4; ++a) {
      const int n = n0 + a * 16 + lq * 4;
      f4 bb = *(const f4*)&be2[n];
      f4 hv = *(const f4*)&hrow[n];
      bf4v pk;
#pragma unroll
      for (int r = 0; r < 4; ++r)
        pk[r] = f2b((acc[a][b][r] + bb[r]) * c * hv[r]);
      *(bf4v*)&M2s[(b * 16 + lr) * 264 + n] = pk;
    }
  }
  __syncthreads();

  // ---- stage C: K = 256, relu ----
#pragma unroll
  for (int a = 0; a < 4; ++a)
#pragma unroll
    for (int b = 0; b < 4; ++b) acc[a][b] = (f4)0.f;
  for (int kc = 0; kc < 256; kc += 32) {
    bf8 aF[4], bF[4];
#pragma unroll
    for (int a = 0; a < 4; ++a)
      aF[a] = *(const bf8*)&WaT[(size_t)(n0 + a * 16 + lr) * 256 + kc + lq * 8];
#pragma unroll
    for (int b = 0; b < 4; ++b)
      bF[b] = *(const bf8*)&M2s[(b * 16 + lr) * 264 + kc + lq * 8];
#pragma unroll
    for (int a = 0; a < 4; ++a)
#pragma unroll
      for (int b = 0; b < 4; ++b)
        acc[a][b] = __builtin_amdgcn_mfma_f32_16x16x32_bf16(aF[a], bF[b], acc[a][b], 0, 0, 0);
  }
  __syncthreads();

#pragma unroll
  for (int a = 0; a < 4; ++a) {
    const int n = n0 + a * 16 + lq * 4;
    f4 bb = *(const f4*)&ba[n];
#pragma unroll
    for (int b = 0; b < 4; ++b) {
      bf4v pk;
#pragma unroll
      for (int r = 0; r < 4; ++r) pk[r] = f2b(fmaxf(acc[a][b][r] + bb[r], 0.f));
      *(bf4v*)&M2s[(b * 16 + lr) * 264 + n] = pk;
    }
  }
  __syncthreads();

  // ---- stage D: K = 256 ----
#pragma unroll
  for (int a = 0; a < 4; ++a)
#pragma unroll
    for (int b = 0; b < 4; ++b) acc[a][b] = (f4)0.f;
  for (int kc = 0; kc < 256; kc += 32) {
    bf8 aF[4], bF[4];
#pragma unroll
    for (int a = 0; a < 4; ++a)
      aF[a] = *(const bf8*)&WbT[(size_t)(n0 + a * 16 + lr) * 256 + kc + lq * 8];
#pragma unroll
    for (int b = 0; b < 4; ++b)
      bF[b] = *(const bf8*)&M2s[(b * 16 + lr) * 264 + kc + lq * 8];
#pragma unroll
    for (int a = 0; a < 4; ++a)
#pragma unroll
      for (int b = 0; b < 4; ++b)
        acc[a][b] = __builtin_amdgcn_mfma_f32_16x16x32_bf16(aF[a], bF[b], acc[a][b], 0, 0, 0);
  }

#pragma unroll
  for (int b = 0; b < 4; ++b) {
    const int d = dst[e0 + b * 16 + lr];
    float* orow = &s2[(size_t)d * 256];
#pragma unroll
    for (int a = 0; a < 4; ++a) {
      const int n = n0 + a * 16 + lq * 4;
      f4 bb = *(const f4*)&bbv[n];
      atomadd2(&orow[n],     fmaxf(acc[a][b][0] + bb[0], 0.f),
                             fmaxf(acc[a][b][1] + bb[1], 0.f));
      atomadd2(&orow[n + 2], fmaxf(acc[a][b][2] + bb[2], 0.f),
                             fmaxf(acc[a][b][3] + bb[3], 0.f));
    }
  }
}

// ---------------- node linear 1 (bf16 MFMA) -----------------------------------
// h1 = relu(concat(nf, s1/cnt) @ Wl1 + bl1).  64 nodes/block, 4 waves x 64 out.

__global__ __launch_bounds__(256, 3) void h1m_k(
    const float* __restrict__ nf, const float* __restrict__ s1,
    const int* __restrict__ cnt, const short* __restrict__ Wl1T,
    const float* __restrict__ bl1, float* __restrict__ h1)
{
  __shared__ __align__(16) short As[64 * 264];
  const int t = threadIdx.x;
  const int v0 = blockIdx.x * 64;

  // build A tile: 64 nodes x 256 k (bf16)
  {
    const int row = t >> 2;
    const int kb = (t & 3) * 64;
    int gn = v0 + row;
    if (gn >= NN) gn = NN - 1;
    const float inv = 1.f / fmaxf((float)cnt[gn], 1.f);
#pragma unroll
    for (int j = 0; j < 64; j += 8) {
      const int k = kb + j;
      f4 x0, x1;
      if (k < 128) {
        x0 = *(const f4*)&nf[(size_t)gn * 128 + k];
        x1 = *(const f4*)&nf[(size_t)gn * 128 + k + 4];
      } else {
        x0 = *(const f4*)&s1[(size_t)gn * 128 + (k - 128)];
        x1 = *(const f4*)&s1[(size_t)gn * 128 + (k - 124)];
#pragma unroll
        for (int x = 0; x < 4; ++x) { x0[x] *= inv; x1[x] *= inv; }
      }
      bf8 pk;
#pragma unroll
      for (int x = 0; x < 4; ++x) { pk[x] = f2b(x0[x]); pk[x + 4] = f2b(x1[x]); }
      *(bf8*)&As[row * 264 + k] = pk;
    }
  }
  __syncthreads();

  const int lane = t & 63, wv = t >> 6;
  const int lr = lane & 15;
  const int lq = lane >> 4;
  const int n0 = wv * 64;

  f4 acc[4][4];
#pragma unroll
  for (int a = 0; a < 4; ++a)
#pragma unroll
    for (int b = 0; b < 4; ++b) acc[a][b] = (f4)0.f;

  for (int kc = 0; kc < 256; kc += 32) {
    bf8 aF[4], bF[4];
#pragma unroll
    for (int a = 0; a < 4; ++a)
      aF[a] = *(const bf8*)&Wl1T[(size_t)(n0 + a * 16 + lr) * 256 + kc + lq * 8];
#pragma unroll
    for (int b = 0; b < 4; ++b)
      bF[b] = *(const bf8*)&As[(b * 16 + lr) * 264 + kc + lq * 8];
#pragma unroll
    for (int a = 0; a < 4; ++a)
#pragma unroll
      for (int b = 0; b < 4; ++b)
        acc[a][b] = __builtin_amdgcn_mfma_f32_16x16x32_bf16(aF[a], bF[b], acc[a][b], 0, 0, 0);
  }

#pragma unroll
  for (int b = 0; b < 4; ++b) {
    const int gn = v0 + b * 16 + lr;
    if (gn >= NN) continue;
#pragma unroll
    for (int a = 0; a < 4; ++a) {
      const int n = n0 + a * 16 + lq * 4;
      f4 bb = *(const f4*)&bl1[n];
      float4 v;
      v.x = fmaxf(acc[a][b][0] + bb[0], 0.f);
      v.y = fmaxf(acc[a][b][1] + bb[1], 0.f);
      v.z = fmaxf(acc[a][b][2] + bb[2], 0.f);
      v.w = fmaxf(acc[a][b][3] + bb[3], 0.f);
      *(float4*)&h1[(size_t)gn * 256 + n] = v;
    }
  }
}

// ---------------- final linear: out = concat(h1, s2/cnt) @ Wl2 + bl2 ----------

__global__ __launch_bounds__(256) void out_k(
    const float* __restrict__ h1, const float* __restrict__ s2,
    const int* __restrict__ cnt, const float* __restrict__ Wl2,
    const float* __restrict__ bl2, float* __restrict__ out)
{
  __shared__ float A8[8][512];
  const int n0 = blockIdx.x * 8;
  const int tx = threadIdx.x;
  const int ty = threadIdx.y;
  const int t = ty * 32 + tx;
  const int row = t >> 5;
  const int k0 = (t & 31) * 16;
  const int n = n0 + row;
  const float inv = 1.0f / fmaxf((float)cnt[n], 1.0f);
#pragma unroll
  for (int i = 0; i < 16; i += 4) {
    int k = k0 + i;
    float4 v;
    if (k < 256) {
      v = *(const float4*)&h1[(size_t)n * 256 + k];
    } else {
      v = *(const float4*)&s2[(size_t)n * 256 + (k - 256)];
      v.x *= inv; v.y *= inv; v.z *= inv; v.w *= inv;
    }
    *(float4*)&A8[row][k] = v;
  }
  __syncthreads();
  float acc = bl2[tx];
#pragma unroll 8
  for (int k = 0; k < 512; k++) acc = fmaf(A8[ty][k], Wl2[(size_t)k * 32 + tx], acc);
  out[(size_t)(n0 + ty) * 32 + tx] = acc;
}

// ---------------- launch ------------------------------------------------------

extern "C" void kernel_launch(void* const* d_in, const int* in_sizes, int n_in,
                              void* d_out, int out_size, void* d_ws, size_t ws_size,
                              hipStream_t stream) {
  const float* nf   = (const float*)d_in[0];
  const float* ef   = (const float*)d_in[1];
  const int*   src  = (const int*)d_in[2];
  const int*   dst  = (const int*)d_in[3];
  const float* We1  = (const float*)d_in[4];
  const float* be1  = (const float*)d_in[5];
  const float* Wr1a = (const float*)d_in[6];
  const float* br1a = (const float*)d_in[7];
  const float* Wr1b = (const float*)d_in[8];
  const float* br1b = (const float*)d_in[9];
  const float* Wl1  = (const float*)d_in[10];
  const float* bl1  = (const float*)d_in[11];
  const float* We2  = (const float*)d_in[12];
  const float* be2  = (const float*)d_in[13];
  const float* Wr2a = (const float*)d_in[14];
  const float* br2a = (const float*)d_in[15];
  const float* Wr2b = (const float*)d_in[16];
  const float* br2b = (const float*)d_in[17];
  const float* Wl2  = (const float*)d_in[18];
  const float* bl2  = (const float*)d_in[19];

  float* ws = (float*)d_ws;
  float* s1   = ws;                             // N*128
  float* s2   = s1 + (size_t)NN * 128;          // N*256
  int*   cnt  = (int*)(s2 + (size_t)NN * 256);  // N
  float* h1   = (float*)(cnt + NN);             // N*256
  float* cos1 = h1 + (size_t)NN * 256;          // E
  float* cos2 = cos1 + NE;                      // E
  short* WaT1 = (short*)(cos2 + NE);            // 128*128 bf16
  short* WbT1 = WaT1 + 128 * 128;               // 128*128
  short* We2T = WbT1 + 128 * 128;               // 256*128
  short* WaT2 = We2T + 256 * 128;               // 256*256
  short* WbT2 = WaT2 + 256 * 256;               // 256*256
  short* Wl1T = WbT2 + 256 * 256;               // 256*256

  size_t need = ((size_t)NN * 128 + (size_t)NN * 256 + NN +
                 (size_t)NN * 256 + 2 * (size_t)NE) * 4 +
                ((size_t)128 * 128 * 2 + (size_t)256 * 128 +
                 (size_t)256 * 256 * 3) * 2;
  if (ws_size < need) return;

  // transpose+convert weights to bf16 (tiny)
  wt_k<<<(128 * 128 + 255) / 256, 256, 0, stream>>>(Wr1a, WaT1, 128, 128);
  wt_k<<<(128 * 128 + 255) / 256, 256, 0, stream>>>(Wr1b, WbT1, 128, 128);
  wt_k<<<(128 * 256 + 255) / 256, 256, 0, stream>>>(We2, We2T, 128, 256);
  wt_k<<<(256 * 256 + 255) / 256, 256, 0, stream>>>(Wr2a, WaT2, 256, 256);
  wt_k<<<(256 * 256 + 255) / 256, 256, 0, stream>>>(Wr2b, WbT2, 256, 256);
  wt_k<<<(256 * 256 + 255) / 256, 256, 0, stream>>>(Wl1, Wl1T, 256, 256);

  // zero s1, s2, cnt (contiguous)
  hipMemsetAsync(s1, 0, ((size_t)NN * 128 + (size_t)NN * 256 + NN) * 4, stream);

  edge1_k<<<NE / 4, 256, 0, stream>>>(nf, src, dst, cos1, cnt);

  edge_mlp1<<<NE / 64, 256, 0, stream>>>(nf, ef, src, dst, We1, be1,
                                         WaT1, br1a, WbT1, br1b, cos1, s1);

  h1m_k<<<(NN + 63) / 64, 256, 0, stream>>>(nf, s1, cnt, Wl1T, bl1, h1);

  edge2_k<<<NE / 4, 256, 0, stream>>>(h1, src, dst, cos2);

  edge_mlp2<<<NE / 64, 256, 0, stream>>>(h1, ef, src, dst, We1, be1, We2T, be2,
                                         WaT2, br2a, WbT2, br2b, cos2, s2);

  out_k<<<NN / 8, dim3(32, 8), 0, stream>>>(h1, s2, cnt, Wl2, bl2, (float*)d_out);
}

// Round 5
// 1852.385 us; speedup vs baseline: 6.1237x; 2.5378x over previous
//
#include <hip/hip_runtime.h>
#include <math.h>

#define NN 50000
#define NE 800000

typedef short bf8 __attribute__((ext_vector_type(8)));
typedef short bf4v __attribute__((ext_vector_type(4)));
typedef float f4 __attribute__((ext_vector_type(4)));

// float -> bf16 bits, round-to-nearest-even (values are finite)
__device__ __forceinline__ short f2b(float f) {
  unsigned int u = __float_as_uint(f);
  unsigned int r = (u + 0x7FFFu + ((u >> 16) & 1u)) >> 16;
  return (short)(unsigned short)r;
}

// ---------------- weight transpose + bf16 convert -----------------------------
__global__ __launch_bounds__(256) void wt_k(const float* __restrict__ in,
                                            short* __restrict__ out,
                                            int K, int N) {
  int i = blockIdx.x * 256 + threadIdx.x;
  if (i >= K * N) return;
  int n = i / K, k = i - n * K;
  out[i] = f2b(in[(size_t)k * N + n]);
}

// ---------------- cosine + degree count kernels -------------------------------

__global__ __launch_bounds__(256) void edge1_k(
    const float* __restrict__ nf,
    const int* __restrict__ src, const int* __restrict__ dst,
    float* __restrict__ cos1, int* __restrict__ cnt)
{
  int wid = blockIdx.x * 4 + (threadIdx.x >> 6);
  if (wid >= NE) return;
  int lane = threadIdx.x & 63;
  int s = src[wid], d = dst[wid];
  float2 hs = *(const float2*)&nf[(size_t)s * 128 + lane * 2];
  float2 hd = *(const float2*)&nf[(size_t)d * 128 + lane * 2];
  float ss = hs.x * hs.x + hs.y * hs.y;
  float dd = hd.x * hd.x + hd.y * hd.y;
  float sd = hs.x * hd.x + hs.y * hd.y;
#pragma unroll
  for (int o = 32; o >= 1; o >>= 1) {
    ss += __shfl_xor(ss, o);
    dd += __shfl_xor(dd, o);
    sd += __shfl_xor(sd, o);
  }
  if (lane == 0) {
    cos1[wid] = sd / (fmaxf(sqrtf(ss), 1e-12f) * fmaxf(sqrtf(dd), 1e-12f));
    atomicAdd(&cnt[d], 1);
  }
}

__global__ __launch_bounds__(256) void edge2_k(
    const float* __restrict__ h1,
    const int* __restrict__ src, const int* __restrict__ dst,
    float* __restrict__ cos2)
{
  int wid = blockIdx.x * 4 + (threadIdx.x >> 6);
  if (wid >= NE) return;
  int lane = threadIdx.x & 63;
  int s = src[wid], d = dst[wid];
  float4 a = *(const float4*)&h1[(size_t)s * 256 + lane * 4];
  float4 b = *(const float4*)&h1[(size_t)d * 256 + lane * 4];
  float ss = a.x * a.x + a.y * a.y + a.z * a.z + a.w * a.w;
  float dd = b.x * b.x + b.y * b.y + b.z * b.z + b.w * b.w;
  float sd = a.x * b.x + a.y * b.y + a.z * b.z + a.w * b.w;
#pragma unroll
  for (int o = 32; o >= 1; o >>= 1) {
    ss += __shfl_xor(ss, o);
    dd += __shfl_xor(dd, o);
    sd += __shfl_xor(sd, o);
  }
  if (lane == 0)
    cos2[wid] = sd / (fmaxf(sqrtf(ss), 1e-12f) * fmaxf(sqrtf(dd), 1e-12f));
}

// ---------------- counting-sort by dst ----------------------------------------
// scan_k: off2 = exclusive prefix sum of cnt (single block, 1024 threads)
__global__ __launch_bounds__(1024) void scan_k(const int* __restrict__ cnt,
                                               int* __restrict__ off2) {
  __shared__ int buf[1024];
  __shared__ int carry_s;
  const int t = threadIdx.x;
  if (t == 0) carry_s = 0;
  __syncthreads();
  const int nch = (NN + 1023) / 1024;
  for (int ch = 0; ch < nch; ++ch) {
    const int i = ch * 1024 + t;
    const int v = (i < NN) ? cnt[i] : 0;
    buf[t] = v;
    __syncthreads();
#pragma unroll
    for (int o = 1; o < 1024; o <<= 1) {
      int x = (t >= o) ? buf[t - o] : 0;
      __syncthreads();
      buf[t] += x;
      __syncthreads();
    }
    const int incl = buf[t];
    const int carry = carry_s;
    if (i < NN) off2[i] = carry + incl - v;
    __syncthreads();                 // all reads of carry_s done
    if (t == 1023) carry_s = carry + incl;
    __syncthreads();
  }
}

// perm_k: scatter edge ids into dst-sorted order
__global__ __launch_bounds__(256) void perm_k(const int* __restrict__ dst,
                                              int* __restrict__ off2,
                                              int* __restrict__ perm,
                                              int* __restrict__ dsts) {
  int e = blockIdx.x * 256 + threadIdx.x;
  if (e >= NE) return;
  int d = dst[e];
  int p = atomicAdd(&off2[d], 1);
  perm[p] = e;
  dsts[p] = d;
}

// ---------------- fused edge-MLP layer 1 (bf16 MFMA, sorted, seg-reduce) ------

__global__ __launch_bounds__(256, 3) void edge_mlp1(
    const float* __restrict__ nf, const float* __restrict__ ef,
    const int* __restrict__ src, const int* __restrict__ perm,
    const int* __restrict__ dsts,
    const float* __restrict__ We1, const float* __restrict__ be1,
    const short* __restrict__ WaT, const float* __restrict__ ba,
    const short* __restrict__ WbT, const float* __restrict__ bbv,
    const float* __restrict__ cosv, float* __restrict__ s1)
{
  __shared__ __align__(16) short Ms[64 * 136];   // 17408 B
  __shared__ __align__(16) float Rs[64 * 132];   // 33792 B
  __shared__ int dse[64];
  const int t = threadIdx.x;
  const int e0 = blockIdx.x * 64;

  if (t < 64) dse[t] = dsts[e0 + t];

  // ---- build message tile M (bf16), edges in sorted order ----
  {
    const int e = t >> 2;
    const int kb = (t & 3) * 32;
    const int pe = perm[e0 + e];
    const int s = src[pe];
    const float c = cosv[pe];
    const float f0 = ef[2 * pe], f1 = ef[2 * pe + 1];
    const float* hrow = &nf[(size_t)s * 128];
#pragma unroll
    for (int j = 0; j < 4; ++j) {
      const int k = kb + j * 8;
      f4 h0 = *(const f4*)&hrow[k];
      f4 h1v = *(const f4*)&hrow[k + 4];
      f4 wa0 = *(const f4*)&We1[k];
      f4 wa1 = *(const f4*)&We1[k + 4];
      f4 wb0 = *(const f4*)&We1[128 + k];
      f4 wb1 = *(const f4*)&We1[128 + k + 4];
      f4 b0 = *(const f4*)&be1[k];
      f4 b1 = *(const f4*)&be1[k + 4];
      bf8 pk;
#pragma unroll
      for (int x = 0; x < 4; ++x) {
        pk[x]     = f2b(c * fmaf(f0, wa0[x], fmaf(f1, wb0[x], b0[x])) * h0[x]);
        pk[x + 4] = f2b(c * fmaf(f0, wa1[x], fmaf(f1, wb1[x], b1[x])) * h1v[x]);
      }
      *(bf8*)&Ms[e * 136 + k] = pk;
    }
  }
  __syncthreads();

  const int lane = t & 63, wv = t >> 6;
  const int lr = lane & 15;
  const int lq = lane >> 4;
  const int n0 = wv * 32;

  f4 acc[2][4];
#pragma unroll
  for (int a = 0; a < 2; ++a)
#pragma unroll
    for (int b = 0; b < 4; ++b) acc[a][b] = (f4)0.f;

  // ---- stage 1: K = 128 ----
#pragma unroll
  for (int kc = 0; kc < 128; kc += 32) {
    bf8 aF[2], bF[4];
#pragma unroll
    for (int a = 0; a < 2; ++a)
      aF[a] = *(const bf8*)&WaT[(size_t)(n0 + a * 16 + lr) * 128 + kc + lq * 8];
#pragma unroll
    for (int b = 0; b < 4; ++b)
      bF[b] = *(const bf8*)&Ms[(b * 16 + lr) * 136 + kc + lq * 8];
#pragma unroll
    for (int a = 0; a < 2; ++a)
#pragma unroll
      for (int b = 0; b < 4; ++b)
        acc[a][b] = __builtin_amdgcn_mfma_f32_16x16x32_bf16(aF[a], bF[b], acc[a][b], 0, 0, 0);
  }
  __syncthreads();

  // T[e][n] = relu(acc + ba[n]) -> Ms
#pragma unroll
  for (int a = 0; a < 2; ++a) {
    const int n = n0 + a * 16 + lq * 4;
    f4 bb = *(const f4*)&ba[n];
#pragma unroll
    for (int b = 0; b < 4; ++b) {
      bf4v pk;
#pragma unroll
      for (int r = 0; r < 4; ++r) pk[r] = f2b(fmaxf(acc[a][b][r] + bb[r], 0.f));
      *(bf4v*)&Ms[(b * 16 + lr) * 136 + n] = pk;
    }
  }
  __syncthreads();

  // ---- stage 2: K = 128 ----
#pragma unroll
  for (int a = 0; a < 2; ++a)
#pragma unroll
    for (int b = 0; b < 4; ++b) acc[a][b] = (f4)0.f;
#pragma unroll
  for (int kc = 0; kc < 128; kc += 32) {
    bf8 aF[2], bF[4];
#pragma unroll
    for (int a = 0; a < 2; ++a)
      aF[a] = *(const bf8*)&WbT[(size_t)(n0 + a * 16 + lr) * 128 + kc + lq * 8];
#pragma unroll
    for (int b = 0; b < 4; ++b)
      bF[b] = *(const bf8*)&Ms[(b * 16 + lr) * 136 + kc + lq * 8];
#pragma unroll
    for (int a = 0; a < 2; ++a)
#pragma unroll
      for (int b = 0; b < 4; ++b)
        acc[a][b] = __builtin_amdgcn_mfma_f32_16x16x32_bf16(aF[a], bF[b], acc[a][b], 0, 0, 0);
  }

  // epilogue: relu+bias -> Rs (fp32), then segmented reduce over sorted dst
#pragma unroll
  for (int a = 0; a < 2; ++a) {
    const int n = n0 + a * 16 + lq * 4;
    f4 bb = *(const f4*)&bbv[n];
#pragma unroll
    for (int b = 0; b < 4; ++b) {
      f4 v;
#pragma unroll
      for (int r = 0; r < 4; ++r) v[r] = fmaxf(acc[a][b][r] + bb[r], 0.f);
      *(f4*)&Rs[(b * 16 + lr) * 132 + n] = v;
    }
  }
  __syncthreads();

  {
    const int f = t & 127;
    const int eb = (t >> 7) * 32;
    float run = 0.f;
    int pd = dse[eb];
#pragma unroll 4
    for (int e = eb; e < eb + 32; ++e) {
      const int d = dse[e];          // wave-uniform
      if (d != pd) {
        atomicAdd(&s1[(size_t)pd * 128 + f], run);
        run = 0.f;
        pd = d;
      }
      run += Rs[e * 132 + f];
    }
    atomicAdd(&s1[(size_t)pd * 128 + f], run);
  }
}

// ---------------- fused edge-MLP layer 2 (bf16 MFMA, sorted, seg-reduce) ------

__global__ __launch_bounds__(256, 3) void edge_mlp2(
    const float* __restrict__ h1g, const float* __restrict__ ef,
    const int* __restrict__ src, const int* __restrict__ perm,
    const int* __restrict__ dsts,
    const float* __restrict__ We1, const float* __restrict__ be1,
    const short* __restrict__ We2T, const float* __restrict__ be2,
    const short* __restrict__ WaT, const float* __restrict__ ba,
    const short* __restrict__ WbT, const float* __restrict__ bbv,
    const float* __restrict__ cosv, float* __restrict__ s2)
{
  __shared__ __align__(16) short Ws[64 * 136];   // 17408 B
  __shared__ __align__(16) short M2s[64 * 264];  // 33792 B (reused as fp32 R halves)
  __shared__ int dse[64];
  const int t = threadIdx.x;
  const int e0 = blockIdx.x * 64;

  if (t < 64) dse[t] = dsts[e0 + t];

  // ---- build relu(w1) tile (bf16) ----
  {
    const int e = t >> 2;
    const int kb = (t & 3) * 32;
    const int pe = perm[e0 + e];
    const float f0 = ef[2 * pe], f1 = ef[2 * pe + 1];
#pragma unroll
    for (int j = 0; j < 4; ++j) {
      const int k = kb + j * 8;
      f4 wa0 = *(const f4*)&We1[k];
      f4 wa1 = *(const f4*)&We1[k + 4];
      f4 wb0 = *(const f4*)&We1[128 + k];
      f4 wb1 = *(const f4*)&We1[128 + k + 4];
      f4 b0 = *(const f4*)&be1[k];
      f4 b1 = *(const f4*)&be1[k + 4];
      bf8 pk;
#pragma unroll
      for (int x = 0; x < 4; ++x) {
        pk[x]     = f2b(fmaxf(fmaf(f0, wa0[x], fmaf(f1, wb0[x], b0[x])), 0.f));
        pk[x + 4] = f2b(fmaxf(fmaf(f0, wa1[x], fmaf(f1, wb1[x], b1[x])), 0.f));
      }
      *(bf8*)&Ws[e * 136 + k] = pk;
    }
  }
  __syncthreads();

  const int lane = t & 63, wv = t >> 6;
  const int lr = lane & 15;
  const int lq = lane >> 4;
  const int n0 = wv * 64;

  f4 acc[4][4];
#pragma unroll
  for (int a = 0; a < 4; ++a)
#pragma unroll
    for (int b = 0; b < 4; ++b) acc[a][b] = (f4)0.f;

  // ---- stage B: K = 128 ----
#pragma unroll
  for (int kc = 0; kc < 128; kc += 32) {
    bf8 aF[4], bF[4];
#pragma unroll
    for (int a = 0; a < 4; ++a)
      aF[a] = *(const bf8*)&We2T[(size_t)(n0 + a * 16 + lr) * 128 + kc + lq * 8];
#pragma unroll
    for (int b = 0; b < 4; ++b)
      bF[b] = *(const bf8*)&Ws[(b * 16 + lr) * 136 + kc + lq * 8];
#pragma unroll
    for (int a = 0; a < 4; ++a)
#pragma unroll
      for (int b = 0; b < 4; ++b)
        acc[a][b] = __builtin_amdgcn_mfma_f32_16x16x32_bf16(aF[a], bF[b], acc[a][b], 0, 0, 0);
  }

  // m2[e][n] = (w2 + be2[n]) * cos2[e] * h1[src[e]][n] -> M2s
#pragma unroll
  for (int b = 0; b < 4; ++b) {
    const int pe = perm[e0 + b * 16 + lr];
    const int s = src[pe];
    const float c = cosv[pe];
    const float* hrow = &h1g[(size_t)s * 256];
#pragma unroll
    for (int a = 0; a < 4; ++a) {
      const int n = n0 + a * 16 + lq * 4;
      f4 bb = *(const f4*)&be2[n];
      f4 hv = *(const f4*)&hrow[n];
      bf4v pk;
#pragma unroll
      for (int r = 0; r < 4; ++r)
        pk[r] = f2b((acc[a][b][r] + bb[r]) * c * hv[r]);
      *(bf4v*)&M2s[(b * 16 + lr) * 264 + n] = pk;
    }
  }
  __syncthreads();

  // ---- stage C: K = 256, relu ----
#pragma unroll
  for (int a = 0; a < 4; ++a)
#pragma unroll
    for (int b = 0; b < 4; ++b) acc[a][b] = (f4)0.f;
  for (int kc = 0; kc < 256; kc += 32) {
    bf8 aF[4], bF[4];
#pragma unroll
    for (int a = 0; a < 4; ++a)
      aF[a] = *(const bf8*)&WaT[(size_t)(n0 + a * 16 + lr) * 256 + kc + lq * 8];
#pragma unroll
    for (int b = 0; b < 4; ++b)
      bF[b] = *(const bf8*)&M2s[(b * 16 + lr) * 264 + kc + lq * 8];
#pragma unroll
    for (int a = 0; a < 4; ++a)
#pragma unroll
      for (int b = 0; b < 4; ++b)
        acc[a][b] = __builtin_amdgcn_mfma_f32_16x16x32_bf16(aF[a], bF[b], acc[a][b], 0, 0, 0);
  }
  __syncthreads();

#pragma unroll
  for (int a = 0; a < 4; ++a) {
    const int n = n0 + a * 16 + lq * 4;
    f4 bb = *(const f4*)&ba[n];
#pragma unroll
    for (int b = 0; b < 4; ++b) {
      bf4v pk;
#pragma unroll
      for (int r = 0; r < 4; ++r) pk[r] = f2b(fmaxf(acc[a][b][r] + bb[r], 0.f));
      *(bf4v*)&M2s[(b * 16 + lr) * 264 + n] = pk;
    }
  }
  __syncthreads();

  // ---- stage D: K = 256 ----
#pragma unroll
  for (int a = 0; a < 4; ++a)
#pragma unroll
    for (int b = 0; b < 4; ++b) acc[a][b] = (f4)0.f;
  for (int kc = 0; kc < 256; kc += 32) {
    bf8 aF[4], bF[4];
#pragma unroll
    for (int a = 0; a < 4; ++a)
      aF[a] = *(const bf8*)&WbT[(size_t)(n0 + a * 16 + lr) * 256 + kc + lq * 8];
#pragma unroll
    for (int b = 0; b < 4; ++b)
      bF[b] = *(const bf8*)&M2s[(b * 16 + lr) * 264 + kc + lq * 8];
#pragma unroll
    for (int a = 0; a < 4; ++a)
#pragma unroll
      for (int b = 0; b < 4; ++b)
        acc[a][b] = __builtin_amdgcn_mfma_f32_16x16x32_bf16(aF[a], bF[b], acc[a][b], 0, 0, 0);
  }
  __syncthreads();  // all waves done reading M2s before fp32 reuse

  // epilogue: two n-halves; write relu+bias fp32 into RF (=M2s), seg-reduce
  float* RF = (float*)M2s;   // 64 x 132 fp32 = 33792 B
#pragma unroll
  for (int h = 0; h < 2; ++h) {
    if ((wv >> 1) == h) {
#pragma unroll
      for (int a = 0; a < 4; ++a) {
        const int n = n0 + a * 16 + lq * 4;
        f4 bb = *(const f4*)&bbv[n];
#pragma unroll
        for (int b = 0; b < 4; ++b) {
          f4 v;
#pragma unroll
          for (int r = 0; r < 4; ++r) v[r] = fmaxf(acc[a][b][r] + bb[r], 0.f);
          *(f4*)&RF[(b * 16 + lr) * 132 + (n - h * 128)] = v;
        }
      }
    }
    __syncthreads();
    {
      const int f = t & 127;
      const int eb = (t >> 7) * 32;
      float run = 0.f;
      int pd = dse[eb];
#pragma unroll 4
      for (int e = eb; e < eb + 32; ++e) {
        const int d = dse[e];        // wave-uniform
        if (d != pd) {
          atomicAdd(&s2[(size_t)pd * 256 + h * 128 + f], run);
          run = 0.f;
          pd = d;
        }
        run += RF[e * 132 + f];
      }
      atomicAdd(&s2[(size_t)pd * 256 + h * 128 + f], run);
    }
    __syncthreads();
  }
}

// ---------------- node linear 1 (bf16 MFMA) -----------------------------------

__global__ __launch_bounds__(256, 3) void h1m_k(
    const float* __restrict__ nf, const float* __restrict__ s1,
    const int* __restrict__ cnt, const short* __restrict__ Wl1T,
    const float* __restrict__ bl1, float* __restrict__ h1)
{
  __shared__ __align__(16) short As[64 * 264];
  const int t = threadIdx.x;
  const int v0 = blockIdx.x * 64;

  {
    const int row = t >> 2;
    const int kb = (t & 3) * 64;
    int gn = v0 + row;
    if (gn >= NN) gn = NN - 1;
    const float inv = 1.f / fmaxf((float)cnt[gn], 1.f);
#pragma unroll
    for (int j = 0; j < 64; j += 8) {
      const int k = kb + j;
      f4 x0, x1;
      if (k < 128) {
        x0 = *(const f4*)&nf[(size_t)gn * 128 + k];
        x1 = *(const f4*)&nf[(size_t)gn * 128 + k + 4];
      } else {
        x0 = *(const f4*)&s1[(size_t)gn * 128 + (k - 128)];
        x1 = *(const f4*)&s1[(size_t)gn * 128 + (k - 124)];
#pragma unroll
        for (int x = 0; x < 4; ++x) { x0[x] *= inv; x1[x] *= inv; }
      }
      bf8 pk;
#pragma unroll
      for (int x = 0; x < 4; ++x) { pk[x] = f2b(x0[x]); pk[x + 4] = f2b(x1[x]); }
      *(bf8*)&As[row * 264 + k] = pk;
    }
  }
  __syncthreads();

  const int lane = t & 63, wv = t >> 6;
  const int lr = lane & 15;
  const int lq = lane >> 4;
  const int n0 = wv * 64;

  f4 acc[4][4];
#pragma unroll
  for (int a = 0; a < 4; ++a)
#pragma unroll
    for (int b = 0; b < 4; ++b) acc[a][b] = (f4)0.f;

  for (int kc = 0; kc < 256; kc += 32) {
    bf8 aF[4], bF[4];
#pragma unroll
    for (int a = 0; a < 4; ++a)
      aF[a] = *(const bf8*)&Wl1T[(size_t)(n0 + a * 16 + lr) * 256 + kc + lq * 8];
#pragma unroll
    for (int b = 0; b < 4; ++b)
      bF[b] = *(const bf8*)&As[(b * 16 + lr) * 264 + kc + lq * 8];
#pragma unroll
    for (int a = 0; a < 4; ++a)
#pragma unroll
      for (int b = 0; b < 4; ++b)
        acc[a][b] = __builtin_amdgcn_mfma_f32_16x16x32_bf16(aF[a], bF[b], acc[a][b], 0, 0, 0);
  }

#pragma unroll
  for (int b = 0; b < 4; ++b) {
    const int gn = v0 + b * 16 + lr;
    if (gn >= NN) continue;
#pragma unroll
    for (int a = 0; a < 4; ++a) {
      const int n = n0 + a * 16 + lq * 4;
      f4 bb = *(const f4*)&bl1[n];
      float4 v;
      v.x = fmaxf(acc[a][b][0] + bb[0], 0.f);
      v.y = fmaxf(acc[a][b][1] + bb[1], 0.f);
      v.z = fmaxf(acc[a][b][2] + bb[2], 0.f);
      v.w = fmaxf(acc[a][b][3] + bb[3], 0.f);
      *(float4*)&h1[(size_t)gn * 256 + n] = v;
    }
  }
}

// ---------------- final linear: out = concat(h1, s2/cnt) @ Wl2 + bl2 ----------

__global__ __launch_bounds__(256) void out_k(
    const float* __restrict__ h1, const float* __restrict__ s2,
    const int* __restrict__ cnt, const float* __restrict__ Wl2,
    const float* __restrict__ bl2, float* __restrict__ out)
{
  __shared__ float A8[8][512];
  const int n0 = blockIdx.x * 8;
  const int tx = threadIdx.x;
  const int ty = threadIdx.y;
  const int t = ty * 32 + tx;
  const int row = t >> 5;
  const int k0 = (t & 31) * 16;
  const int n = n0 + row;
  const float inv = 1.0f / fmaxf((float)cnt[n], 1.0f);
#pragma unroll
  for (int i = 0; i < 16; i += 4) {
    int k = k0 + i;
    float4 v;
    if (k < 256) {
      v = *(const float4*)&h1[(size_t)n * 256 + k];
    } else {
      v = *(const float4*)&s2[(size_t)n * 256 + (k - 256)];
      v.x *= inv; v.y *= inv; v.z *= inv; v.w *= inv;
    }
    *(float4*)&A8[row][k] = v;
  }
  __syncthreads();
  float acc = bl2[tx];
#pragma unroll 8
  for (int k = 0; k < 512; k++) acc = fmaf(A8[ty][k], Wl2[(size_t)k * 32 + tx], acc);
  out[(size_t)(n0 + ty) * 32 + tx] = acc;
}

// ---------------- launch ------------------------------------------------------

extern "C" void kernel_launch(void* const* d_in, const int* in_sizes, int n_in,
                              void* d_out, int out_size, void* d_ws, size_t ws_size,
                              hipStream_t stream) {
  const float* nf   = (const float*)d_in[0];
  const float* ef   = (const float*)d_in[1];
  const int*   src  = (const int*)d_in[2];
  const int*   dst  = (const int*)d_in[3];
  const float* We1  = (const float*)d_in[4];
  const float* be1  = (const float*)d_in[5];
  const float* Wr1a = (const float*)d_in[6];
  const float* br1a = (const float*)d_in[7];
  const float* Wr1b = (const float*)d_in[8];
  const float* br1b = (const float*)d_in[9];
  const float* Wl1  = (const float*)d_in[10];
  const float* bl1  = (const float*)d_in[11];
  const float* We2  = (const float*)d_in[12];
  const float* be2  = (const float*)d_in[13];
  const float* Wr2a = (const float*)d_in[14];
  const float* br2a = (const float*)d_in[15];
  const float* Wr2b = (const float*)d_in[16];
  const float* br2b = (const float*)d_in[17];
  const float* Wl2  = (const float*)d_in[18];
  const float* bl2  = (const float*)d_in[19];

  float* ws = (float*)d_ws;
  float* s1   = ws;                             // N*128
  float* s2   = s1 + (size_t)NN * 128;          // N*256
  int*   cnt  = (int*)(s2 + (size_t)NN * 256);  // N
  float* h1   = (float*)(cnt + NN);             // N*256
  float* cos1 = h1 + (size_t)NN * 256;          // E
  float* cos2 = cos1 + NE;                      // E
  short* WaT1 = (short*)(cos2 + NE);            // 128*128 bf16
  short* WbT1 = WaT1 + 128 * 128;               // 128*128
  short* We2T = WbT1 + 128 * 128;               // 256*128
  short* WaT2 = We2T + 256 * 128;               // 256*256
  short* WbT2 = WaT2 + 256 * 256;               // 256*256
  short* Wl1T = WbT2 + 256 * 256;               // 256*256
  int*   off2 = (int*)(Wl1T + 256 * 256);       // N
  int*   perm = off2 + NN;                      // E
  int*   dsts = perm + NE;                      // E

  size_t need = ((size_t)NN * 128 + (size_t)NN * 256 + NN +
                 (size_t)NN * 256 + 2 * (size_t)NE) * 4 +
                ((size_t)128 * 128 * 2 + (size_t)256 * 128 +
                 (size_t)256 * 256 * 3) * 2 +
                ((size_t)NN + 2 * (size_t)NE) * 4;
  if (ws_size < need) return;

  // transpose+convert weights to bf16 (tiny)
  wt_k<<<(128 * 128 + 255) / 256, 256, 0, stream>>>(Wr1a, WaT1, 128, 128);
  wt_k<<<(128 * 128 + 255) / 256, 256, 0, stream>>>(Wr1b, WbT1, 128, 128);
  wt_k<<<(128 * 256 + 255) / 256, 256, 0, stream>>>(We2, We2T, 128, 256);
  wt_k<<<(256 * 256 + 255) / 256, 256, 0, stream>>>(Wr2a, WaT2, 256, 256);
  wt_k<<<(256 * 256 + 255) / 256, 256, 0, stream>>>(Wr2b, WbT2, 256, 256);
  wt_k<<<(256 * 256 + 255) / 256, 256, 0, stream>>>(Wl1, Wl1T, 256, 256);

  // zero s1, s2, cnt (contiguous)
  hipMemsetAsync(s1, 0, ((size_t)NN * 128 + (size_t)NN * 256 + NN) * 4, stream);

  edge1_k<<<NE / 4, 256, 0, stream>>>(nf, src, dst, cos1, cnt);

  // counting sort by dst
  scan_k<<<1, 1024, 0, stream>>>(cnt, off2);
  perm_k<<<NE / 256, 256, 0, stream>>>(dst, off2, perm, dsts);

  edge_mlp1<<<NE / 64, 256, 0, stream>>>(nf, ef, src, perm, dsts, We1, be1,
                                         WaT1, br1a, WbT1, br1b, cos1, s1);

  h1m_k<<<(NN + 63) / 64, 256, 0, stream>>>(nf, s1, cnt, Wl1T, bl1, h1);

  edge2_k<<<NE / 4, 256, 0, stream>>>(h1, src, dst, cos2);

  edge_mlp2<<<NE / 64, 256, 0, stream>>>(h1, ef, src, perm, dsts, We1, be1,
                                         We2T, be2, WaT2, br2a, WbT2, br2b,
                                         cos2, s2);

  out_k<<<NN / 8, dim3(32, 8), 0, stream>>>(h1, s2, cnt, Wl2, bl2, (float*)d_out);
}

// Round 6
// 1749.383 us; speedup vs baseline: 6.4842x; 1.0589x over previous
//
#include <hip/hip_runtime.h>
#include <math.h>

#define NN 50000
#define NE 800000

typedef short bf8 __attribute__((ext_vector_type(8)));
typedef short bf4v __attribute__((ext_vector_type(4)));
typedef short bf2v __attribute__((ext_vector_type(2)));
typedef float f4 __attribute__((ext_vector_type(4)));

// float -> bf16 bits, round-to-nearest-even (values are finite)
__device__ __forceinline__ short f2b(float f) {
  unsigned int u = __float_as_uint(f);
  unsigned int r = (u + 0x7FFFu + ((u >> 16) & 1u)) >> 16;
  return (short)(unsigned short)r;
}
__device__ __forceinline__ float b2f(short s) {
  return __uint_as_float(((unsigned int)(unsigned short)s) << 16);
}
__device__ __forceinline__ f4 b2f4(bf4v p) {
  f4 v;
  v[0] = b2f(p[0]); v[1] = b2f(p[1]); v[2] = b2f(p[2]); v[3] = b2f(p[3]);
  return v;
}

// ---------------- weight transpose + bf16 convert -----------------------------
__global__ __launch_bounds__(256) void wt_k(const float* __restrict__ in,
                                            short* __restrict__ out,
                                            int K, int N) {
  int i = blockIdx.x * 256 + threadIdx.x;
  if (i >= K * N) return;
  int n = i / K, k = i - n * K;
  out[i] = f2b(in[(size_t)k * N + n]);
}

// plain fp32 -> bf16 convert (4 elems/thread)
__global__ __launch_bounds__(256) void cvt_k(const float* __restrict__ in,
                                             short* __restrict__ out, int n4) {
  int i = blockIdx.x * 256 + threadIdx.x;
  if (i >= n4) return;
  f4 v = *(const f4*)&in[(size_t)i * 4];
  bf4v p;
  p[0] = f2b(v[0]); p[1] = f2b(v[1]); p[2] = f2b(v[2]); p[3] = f2b(v[3]);
  *(bf4v*)&out[(size_t)i * 4] = p;
}

// ---------------- cosine + degree count kernels -------------------------------

__global__ __launch_bounds__(256) void edge1_k(
    const short* __restrict__ nfb,
    const int* __restrict__ src, const int* __restrict__ dst,
    float* __restrict__ cos1, int* __restrict__ cnt)
{
  int wid = blockIdx.x * 4 + (threadIdx.x >> 6);
  if (wid >= NE) return;
  int lane = threadIdx.x & 63;
  int s = src[wid], d = dst[wid];
  bf2v hb = *(const bf2v*)&nfb[(size_t)s * 128 + lane * 2];
  bf2v db = *(const bf2v*)&nfb[(size_t)d * 128 + lane * 2];
  float hx = b2f(hb[0]), hy = b2f(hb[1]);
  float dx = b2f(db[0]), dy = b2f(db[1]);
  float ss = hx * hx + hy * hy;
  float dd = dx * dx + dy * dy;
  float sd = hx * dx + hy * dy;
#pragma unroll
  for (int o = 32; o >= 1; o >>= 1) {
    ss += __shfl_xor(ss, o);
    dd += __shfl_xor(dd, o);
    sd += __shfl_xor(sd, o);
  }
  if (lane == 0) {
    cos1[wid] = sd / (fmaxf(sqrtf(ss), 1e-12f) * fmaxf(sqrtf(dd), 1e-12f));
    atomicAdd(&cnt[d], 1);
  }
}

__global__ __launch_bounds__(256) void edge2_k(
    const short* __restrict__ h1b,
    const int* __restrict__ src, const int* __restrict__ dst,
    float* __restrict__ cos2)
{
  int wid = blockIdx.x * 4 + (threadIdx.x >> 6);
  if (wid >= NE) return;
  int lane = threadIdx.x & 63;
  int s = src[wid], d = dst[wid];
  f4 a = b2f4(*(const bf4v*)&h1b[(size_t)s * 256 + lane * 4]);
  f4 b = b2f4(*(const bf4v*)&h1b[(size_t)d * 256 + lane * 4]);
  float ss = a[0] * a[0] + a[1] * a[1] + a[2] * a[2] + a[3] * a[3];
  float dd = b[0] * b[0] + b[1] * b[1] + b[2] * b[2] + b[3] * b[3];
  float sd = a[0] * b[0] + a[1] * b[1] + a[2] * b[2] + a[3] * b[3];
#pragma unroll
  for (int o = 32; o >= 1; o >>= 1) {
    ss += __shfl_xor(ss, o);
    dd += __shfl_xor(dd, o);
    sd += __shfl_xor(sd, o);
  }
  if (lane == 0)
    cos2[wid] = sd / (fmaxf(sqrtf(ss), 1e-12f) * fmaxf(sqrtf(dd), 1e-12f));
}

// ---------------- counting-sort by dst ----------------------------------------
__global__ __launch_bounds__(1024) void scan_k(const int* __restrict__ cnt,
                                               int* __restrict__ off2) {
  __shared__ int buf[1024];
  __shared__ int carry_s;
  const int t = threadIdx.x;
  if (t == 0) carry_s = 0;
  __syncthreads();
  const int nch = (NN + 1023) / 1024;
  for (int ch = 0; ch < nch; ++ch) {
    const int i = ch * 1024 + t;
    const int v = (i < NN) ? cnt[i] : 0;
    buf[t] = v;
    __syncthreads();
#pragma unroll
    for (int o = 1; o < 1024; o <<= 1) {
      int x = (t >= o) ? buf[t - o] : 0;
      __syncthreads();
      buf[t] += x;
      __syncthreads();
    }
    const int incl = buf[t];
    const int carry = carry_s;
    if (i < NN) off2[i] = carry + incl - v;
    __syncthreads();
    if (t == 1023) carry_s = carry + incl;
    __syncthreads();
  }
}

__global__ __launch_bounds__(256) void perm_k(const int* __restrict__ dst,
                                              int* __restrict__ off2,
                                              int* __restrict__ perm,
                                              int* __restrict__ dsts) {
  int e = blockIdx.x * 256 + threadIdx.x;
  if (e >= NE) return;
  int d = dst[e];
  int p = atomicAdd(&off2[d], 1);
  perm[p] = e;
  dsts[p] = d;
}

// ---------------- fused edge-MLP layer 1 (bf16 MFMA, sorted, seg-reduce) ------
// LDS: single Ms buffer; result tile R is written back into Ms as bf16.

__global__ __launch_bounds__(256, 5) void edge_mlp1(
    const short* __restrict__ nfb, const float* __restrict__ ef,
    const int* __restrict__ src, const int* __restrict__ perm,
    const int* __restrict__ dsts,
    const float* __restrict__ We1, const float* __restrict__ be1,
    const short* __restrict__ WaT, const float* __restrict__ ba,
    const short* __restrict__ WbT, const float* __restrict__ bbv,
    const float* __restrict__ cosv, float* __restrict__ s1)
{
  __shared__ __align__(16) short Ms[64 * 136];   // 17408 B (M / T / R reuse)
  __shared__ int dse[64];
  const int t = threadIdx.x;
  const int e0 = blockIdx.x * 64;

  if (t < 64) dse[t] = dsts[e0 + t];

  // ---- build message tile M (bf16), edges in sorted order ----
  {
    const int e = t >> 2;
    const int kb = (t & 3) * 32;
    const int pe = perm[e0 + e];
    const int s = src[pe];
    const float c = cosv[pe];
    const float f0 = ef[2 * pe], f1 = ef[2 * pe + 1];
    const short* hrow = &nfb[(size_t)s * 128];
#pragma unroll
    for (int j = 0; j < 4; ++j) {
      const int k = kb + j * 8;
      bf8 hb = *(const bf8*)&hrow[k];
      f4 wa0 = *(const f4*)&We1[k];
      f4 wa1 = *(const f4*)&We1[k + 4];
      f4 wb0 = *(const f4*)&We1[128 + k];
      f4 wb1 = *(const f4*)&We1[128 + k + 4];
      f4 b0 = *(const f4*)&be1[k];
      f4 b1 = *(const f4*)&be1[k + 4];
      bf8 pk;
#pragma unroll
      for (int x = 0; x < 4; ++x) {
        pk[x]     = f2b(c * fmaf(f0, wa0[x], fmaf(f1, wb0[x], b0[x])) * b2f(hb[x]));
        pk[x + 4] = f2b(c * fmaf(f0, wa1[x], fmaf(f1, wb1[x], b1[x])) * b2f(hb[x + 4]));
      }
      *(bf8*)&Ms[e * 136 + k] = pk;
    }
  }
  __syncthreads();

  const int lane = t & 63, wv = t >> 6;
  const int lr = lane & 15;
  const int lq = lane >> 4;
  const int n0 = wv * 32;

  f4 acc[2][4];
#pragma unroll
  for (int a = 0; a < 2; ++a)
#pragma unroll
    for (int b = 0; b < 4; ++b) acc[a][b] = (f4)0.f;

  // ---- stage 1: K = 128 ----
#pragma unroll
  for (int kc = 0; kc < 128; kc += 32) {
    bf8 aF[2], bF[4];
#pragma unroll
    for (int a = 0; a < 2; ++a)
      aF[a] = *(const bf8*)&WaT[(size_t)(n0 + a * 16 + lr) * 128 + kc + lq * 8];
#pragma unroll
    for (int b = 0; b < 4; ++b)
      bF[b] = *(const bf8*)&Ms[(b * 16 + lr) * 136 + kc + lq * 8];
#pragma unroll
    for (int a = 0; a < 2; ++a)
#pragma unroll
      for (int b = 0; b < 4; ++b)
        acc[a][b] = __builtin_amdgcn_mfma_f32_16x16x32_bf16(aF[a], bF[b], acc[a][b], 0, 0, 0);
  }
  __syncthreads();

  // T[e][n] = relu(acc + ba[n]) -> Ms
#pragma unroll
  for (int a = 0; a < 2; ++a) {
    const int n = n0 + a * 16 + lq * 4;
    f4 bb = *(const f4*)&ba[n];
#pragma unroll
    for (int b = 0; b < 4; ++b) {
      bf4v pk;
#pragma unroll
      for (int r = 0; r < 4; ++r) pk[r] = f2b(fmaxf(acc[a][b][r] + bb[r], 0.f));
      *(bf4v*)&Ms[(b * 16 + lr) * 136 + n] = pk;
    }
  }
  __syncthreads();

  // ---- stage 2: K = 128 ----
#pragma unroll
  for (int a = 0; a < 2; ++a)
#pragma unroll
    for (int b = 0; b < 4; ++b) acc[a][b] = (f4)0.f;
#pragma unroll
  for (int kc = 0; kc < 128; kc += 32) {
    bf8 aF[2], bF[4];
#pragma unroll
    for (int a = 0; a < 2; ++a)
      aF[a] = *(const bf8*)&WbT[(size_t)(n0 + a * 16 + lr) * 128 + kc + lq * 8];
#pragma unroll
    for (int b = 0; b < 4; ++b)
      bF[b] = *(const bf8*)&Ms[(b * 16 + lr) * 136 + kc + lq * 8];
#pragma unroll
    for (int a = 0; a < 2; ++a)
#pragma unroll
      for (int b = 0; b < 4; ++b)
        acc[a][b] = __builtin_amdgcn_mfma_f32_16x16x32_bf16(aF[a], bF[b], acc[a][b], 0, 0, 0);
  }
  __syncthreads();   // all waves done reading Ms before R overwrite

  // R[e][n] = relu(acc + bb[n]) -> Ms (bf16; sums still accumulate in fp32)
#pragma unroll
  for (int a = 0; a < 2; ++a) {
    const int n = n0 + a * 16 + lq * 4;
    f4 bb = *(const f4*)&bbv[n];
#pragma unroll
    for (int b = 0; b < 4; ++b) {
      bf4v pk;
#pragma unroll
      for (int r = 0; r < 4; ++r) pk[r] = f2b(fmaxf(acc[a][b][r] + bb[r], 0.f));
      *(bf4v*)&Ms[(b * 16 + lr) * 136 + n] = pk;
    }
  }
  __syncthreads();

  // segmented reduce over sorted dst
  {
    const int f = t & 127;
    const int eb = (t >> 7) * 32;
    float run = 0.f;
    int pd = dse[eb];
#pragma unroll 4
    for (int e = eb; e < eb + 32; ++e) {
      const int d = dse[e];          // wave-uniform
      if (d != pd) {
        atomicAdd(&s1[(size_t)pd * 128 + f], run);
        run = 0.f;
        pd = d;
      }
      run += b2f(Ms[e * 136 + f]);
    }
    atomicAdd(&s1[(size_t)pd * 128 + f], run);
  }
}

// ---------------- fused edge-MLP layer 2 (bf16 MFMA, sorted, seg-reduce) ------

__global__ __launch_bounds__(256, 3) void edge_mlp2(
    const short* __restrict__ h1b, const float* __restrict__ ef,
    const int* __restrict__ src, const int* __restrict__ perm,
    const int* __restrict__ dsts,
    const float* __restrict__ We1, const float* __restrict__ be1,
    const short* __restrict__ We2T, const float* __restrict__ be2,
    const short* __restrict__ WaT, const float* __restrict__ ba,
    const short* __restrict__ WbT, const float* __restrict__ bbv,
    const float* __restrict__ cosv, float* __restrict__ s2)
{
  __shared__ __align__(16) short Ws[64 * 136];   // 17408 B
  __shared__ __align__(16) short M2s[64 * 264];  // 33792 B (reused as fp32 R halves)
  __shared__ int dse[64];
  const int t = threadIdx.x;
  const int e0 = blockIdx.x * 64;

  const int lane = t & 63, wv = t >> 6;
  const int lr = lane & 15;
  const int lq = lane >> 4;
  const int n0 = wv * 64;

  // ---- prefetch h1b[src] fragments for the m2 build (hide miss latency) ----
  int pe_b[4], s_b[4];
  float c_b[4];
#pragma unroll
  for (int b = 0; b < 4; ++b) pe_b[b] = perm[e0 + b * 16 + lr];
#pragma unroll
  for (int b = 0; b < 4; ++b) { s_b[b] = src[pe_b[b]]; c_b[b] = cosv[pe_b[b]]; }
  bf4v hpre[4][4];
#pragma unroll
  for (int b = 0; b < 4; ++b)
#pragma unroll
    for (int a = 0; a < 4; ++a)
      hpre[b][a] = *(const bf4v*)&h1b[(size_t)s_b[b] * 256 + n0 + a * 16 + lq * 4];

  if (t < 64) dse[t] = dsts[e0 + t];

  // ---- build relu(w1) tile (bf16) ----
  {
    const int e = t >> 2;
    const int kb = (t & 3) * 32;
    const int pe = perm[e0 + e];
    const float f0 = ef[2 * pe], f1 = ef[2 * pe + 1];
#pragma unroll
    for (int j = 0; j < 4; ++j) {
      const int k = kb + j * 8;
      f4 wa0 = *(const f4*)&We1[k];
      f4 wa1 = *(const f4*)&We1[k + 4];
      f4 wb0 = *(const f4*)&We1[128 + k];
      f4 wb1 = *(const f4*)&We1[128 + k + 4];
      f4 b0 = *(const f4*)&be1[k];
      f4 b1 = *(const f4*)&be1[k + 4];
      bf8 pk;
#pragma unroll
      for (int x = 0; x < 4; ++x) {
        pk[x]     = f2b(fmaxf(fmaf(f0, wa0[x], fmaf(f1, wb0[x], b0[x])), 0.f));
        pk[x + 4] = f2b(fmaxf(fmaf(f0, wa1[x], fmaf(f1, wb1[x], b1[x])), 0.f));
      }
      *(bf8*)&Ws[e * 136 + k] = pk;
    }
  }
  __syncthreads();

  f4 acc[4][4];
#pragma unroll
  for (int a = 0; a < 4; ++a)
#pragma unroll
    for (int b = 0; b < 4; ++b) acc[a][b] = (f4)0.f;

  // ---- stage B: K = 128 ----
#pragma unroll
  for (int kc = 0; kc < 128; kc += 32) {
    bf8 aF[4], bF[4];
#pragma unroll
    for (int a = 0; a < 4; ++a)
      aF[a] = *(const bf8*)&We2T[(size_t)(n0 + a * 16 + lr) * 128 + kc + lq * 8];
#pragma unroll
    for (int b = 0; b < 4; ++b)
      bF[b] = *(const bf8*)&Ws[(b * 16 + lr) * 136 + kc + lq * 8];
#pragma unroll
    for (int a = 0; a < 4; ++a)
#pragma unroll
      for (int b = 0; b < 4; ++b)
        acc[a][b] = __builtin_amdgcn_mfma_f32_16x16x32_bf16(aF[a], bF[b], acc[a][b], 0, 0, 0);
  }

  // m2[e][n] = (w2 + be2[n]) * cos2[e] * h1[src[e]][n] -> M2s  (prefetched h1)
#pragma unroll
  for (int b = 0; b < 4; ++b) {
    const float c = c_b[b];
#pragma unroll
    for (int a = 0; a < 4; ++a) {
      const int n = n0 + a * 16 + lq * 4;
      f4 bb = *(const f4*)&be2[n];
      f4 hv = b2f4(hpre[b][a]);
      bf4v pk;
#pragma unroll
      for (int r = 0; r < 4; ++r)
        pk[r] = f2b((acc[a][b][r] + bb[r]) * c * hv[r]);
      *(bf4v*)&M2s[(b * 16 + lr) * 264 + n] = pk;
    }
  }
  __syncthreads();

  // ---- stage C: K = 256, relu ----
#pragma unroll
  for (int a = 0; a < 4; ++a)
#pragma unroll
    for (int b = 0; b < 4; ++b) acc[a][b] = (f4)0.f;
  for (int kc = 0; kc < 256; kc += 32) {
    bf8 aF[4], bF[4];
#pragma unroll
    for (int a = 0; a < 4; ++a)
      aF[a] = *(const bf8*)&WaT[(size_t)(n0 + a * 16 + lr) * 256 + kc + lq * 8];
#pragma unroll
    for (int b = 0; b < 4; ++b)
      bF[b] = *(const bf8*)&M2s[(b * 16 + lr) * 264 + kc + lq * 8];
#pragma unroll
    for (int a = 0; a < 4; ++a)
#pragma unroll
      for (int b = 0; b < 4; ++b)
        acc[a][b] = __builtin_amdgcn_mfma_f32_16x16x32_bf16(aF[a], bF[b], acc[a][b], 0, 0, 0);
  }
  __syncthreads();

#pragma unroll
  for (int a = 0; a < 4; ++a) {
    const int n = n0 + a * 16 + lq * 4;
    f4 bb = *(const f4*)&ba[n];
#pragma unroll
    for (int b = 0; b < 4; ++b) {
      bf4v pk;
#pragma unroll
      for (int r = 0; r < 4; ++r) pk[r] = f2b(fmaxf(acc[a][b][r] + bb[r], 0.f));
      *(bf4v*)&M2s[(b * 16 + lr) * 264 + n] = pk;
    }
  }
  __syncthreads();

  // ---- stage D: K = 256 ----
#pragma unroll
  for (int a = 0; a < 4; ++a)
#pragma unroll
    for (int b = 0; b < 4; ++b) acc[a][b] = (f4)0.f;
  for (int kc = 0; kc < 256; kc += 32) {
    bf8 aF[4], bF[4];
#pragma unroll
    for (int a = 0; a < 4; ++a)
      aF[a] = *(const bf8*)&WbT[(size_t)(n0 + a * 16 + lr) * 256 + kc + lq * 8];
#pragma unroll
    for (int b = 0; b < 4; ++b)
      bF[b] = *(const bf8*)&M2s[(b * 16 + lr) * 264 + kc + lq * 8];
#pragma unroll
    for (int a = 0; a < 4; ++a)
#pragma unroll
      for (int b = 0; b < 4; ++b)
        acc[a][b] = __builtin_amdgcn_mfma_f32_16x16x32_bf16(aF[a], bF[b], acc[a][b], 0, 0, 0);
  }
  __syncthreads();  // all waves done reading M2s before fp32 reuse

  // epilogue: two n-halves; write relu+bias fp32 into RF (=M2s), seg-reduce
  float* RF = (float*)M2s;   // 64 x 132 fp32 = 33792 B
#pragma unroll
  for (int h = 0; h < 2; ++h) {
    if ((wv >> 1) == h) {
#pragma unroll
      for (int a = 0; a < 4; ++a) {
        const int n = n0 + a * 16 + lq * 4;
        f4 bb = *(const f4*)&bbv[n];
#pragma unroll
        for (int b = 0; b < 4; ++b) {
          f4 v;
#pragma unroll
          for (int r = 0; r < 4; ++r) v[r] = fmaxf(acc[a][b][r] + bb[r], 0.f);
          *(f4*)&RF[(b * 16 + lr) * 132 + (n - h * 128)] = v;
        }
      }
    }
    __syncthreads();
    {
      const int f = t & 127;
      const int eb = (t >> 7) * 32;
      float run = 0.f;
      int pd = dse[eb];
#pragma unroll 4
      for (int e = eb; e < eb + 32; ++e) {
        const int d = dse[e];        // wave-uniform
        if (d != pd) {
          atomicAdd(&s2[(size_t)pd * 256 + h * 128 + f], run);
          run = 0.f;
          pd = d;
        }
        run += RF[e * 132 + f];
      }
      atomicAdd(&s2[(size_t)pd * 256 + h * 128 + f], run);
    }
    __syncthreads();
  }
}

// ---------------- node linear 1 (bf16 MFMA) -> h1b (bf16) ---------------------

__global__ __launch_bounds__(256, 3) void h1m_k(
    const float* __restrict__ nf, const float* __restrict__ s1,
    const int* __restrict__ cnt, const short* __restrict__ Wl1T,
    const float* __restrict__ bl1, short* __restrict__ h1b)
{
  __shared__ __align__(16) short As[64 * 264];
  const int t = threadIdx.x;
  const int v0 = blockIdx.x * 64;

  {
    const int row = t >> 2;
    const int kb = (t & 3) * 64;
    int gn = v0 + row;
    if (gn >= NN) gn = NN - 1;
    const float inv = 1.f / fmaxf((float)cnt[gn], 1.f);
#pragma unroll
    for (int j = 0; j < 64; j += 8) {
      const int k = kb + j;
      f4 x0, x1;
      if (k < 128) {
        x0 = *(const f4*)&nf[(size_t)gn * 128 + k];
        x1 = *(const f4*)&nf[(size_t)gn * 128 + k + 4];
      } else {
        x0 = *(const f4*)&s1[(size_t)gn * 128 + (k - 128)];
        x1 = *(const f4*)&s1[(size_t)gn * 128 + (k - 124)];
#pragma unroll
        for (int x = 0; x < 4; ++x) { x0[x] *= inv; x1[x] *= inv; }
      }
      bf8 pk;
#pragma unroll
      for (int x = 0; x < 4; ++x) { pk[x] = f2b(x0[x]); pk[x + 4] = f2b(x1[x]); }
      *(bf8*)&As[row * 264 + k] = pk;
    }
  }
  __syncthreads();

  const int lane = t & 63, wv = t >> 6;
  const int lr = lane & 15;
  const int lq = lane >> 4;
  const int n0 = wv * 64;

  f4 acc[4][4];
#pragma unroll
  for (int a = 0; a < 4; ++a)
#pragma unroll
    for (int b = 0; b < 4; ++b) acc[a][b] = (f4)0.f;

  for (int kc = 0; kc < 256; kc += 32) {
    bf8 aF[4], bF[4];
#pragma unroll
    for (int a = 0; a < 4; ++a)
      aF[a] = *(const bf8*)&Wl1T[(size_t)(n0 + a * 16 + lr) * 256 + kc + lq * 8];
#pragma unroll
    for (int b = 0; b < 4; ++b)
      bF[b] = *(const bf8*)&As[(b * 16 + lr) * 264 + kc + lq * 8];
#pragma unroll
    for (int a = 0; a < 4; ++a)
#pragma unroll
      for (int b = 0; b < 4; ++b)
        acc[a][b] = __builtin_amdgcn_mfma_f32_16x16x32_bf16(aF[a], bF[b], acc[a][b], 0, 0, 0);
  }

#pragma unroll
  for (int b = 0; b < 4; ++b) {
    const int gn = v0 + b * 16 + lr;
    if (gn >= NN) continue;
#pragma unroll
    for (int a = 0; a < 4; ++a) {
      const int n = n0 + a * 16 + lq * 4;
      f4 bb = *(const f4*)&bl1[n];
      bf4v pk;
      pk[0] = f2b(fmaxf(acc[a][b][0] + bb[0], 0.f));
      pk[1] = f2b(fmaxf(acc[a][b][1] + bb[1], 0.f));
      pk[2] = f2b(fmaxf(acc[a][b][2] + bb[2], 0.f));
      pk[3] = f2b(fmaxf(acc[a][b][3] + bb[3], 0.f));
      *(bf4v*)&h1b[(size_t)gn * 256 + n] = pk;
    }
  }
}

// ---------------- final linear: out = concat(h1b, s2/cnt) @ Wl2 + bl2 ---------

__global__ __launch_bounds__(256) void out_k(
    const short* __restrict__ h1b, const float* __restrict__ s2,
    const int* __restrict__ cnt, const float* __restrict__ Wl2,
    const float* __restrict__ bl2, float* __restrict__ out)
{
  __shared__ float A8[8][512];
  const int n0 = blockIdx.x * 8;
  const int tx = threadIdx.x;
  const int ty = threadIdx.y;
  const int t = ty * 32 + tx;
  const int row = t >> 5;
  const int k0 = (t & 31) * 16;
  const int n = n0 + row;
  const float inv = 1.0f / fmaxf((float)cnt[n], 1.0f);
#pragma unroll
  for (int i = 0; i < 16; i += 4) {
    int k = k0 + i;
    f4 v;
    if (k < 256) {
      v = b2f4(*(const bf4v*)&h1b[(size_t)n * 256 + k]);
    } else {
      v = *(const f4*)&s2[(size_t)n * 256 + (k - 256)];
      v[0] *= inv; v[1] *= inv; v[2] *= inv; v[3] *= inv;
    }
    *(f4*)&A8[row][k] = v;
  }
  __syncthreads();
  float acc = bl2[tx];
#pragma unroll 8
  for (int k = 0; k < 512; k++) acc = fmaf(A8[ty][k], Wl2[(size_t)k * 32 + tx], acc);
  out[(size_t)(n0 + ty) * 32 + tx] = acc;
}

// ---------------- launch ------------------------------------------------------

extern "C" void kernel_launch(void* const* d_in, const int* in_sizes, int n_in,
                              void* d_out, int out_size, void* d_ws, size_t ws_size,
                              hipStream_t stream) {
  const float* nf   = (const float*)d_in[0];
  const float* ef   = (const float*)d_in[1];
  const int*   src  = (const int*)d_in[2];
  const int*   dst  = (const int*)d_in[3];
  const float* We1  = (const float*)d_in[4];
  const float* be1  = (const float*)d_in[5];
  const float* Wr1a = (const float*)d_in[6];
  const float* br1a = (const float*)d_in[7];
  const float* Wr1b = (const float*)d_in[8];
  const float* br1b = (const float*)d_in[9];
  const float* Wl1  = (const float*)d_in[10];
  const float* bl1  = (const float*)d_in[11];
  const float* We2  = (const float*)d_in[12];
  const float* be2  = (const float*)d_in[13];
  const float* Wr2a = (const float*)d_in[14];
  const float* br2a = (const float*)d_in[15];
  const float* Wr2b = (const float*)d_in[16];
  const float* br2b = (const float*)d_in[17];
  const float* Wl2  = (const float*)d_in[18];
  const float* bl2  = (const float*)d_in[19];

  float* ws = (float*)d_ws;
  float* s1   = ws;                             // N*128 f
  float* s2   = s1 + (size_t)NN * 128;          // N*256 f
  int*   cnt  = (int*)(s2 + (size_t)NN * 256);  // N
  float* cos1 = (float*)(cnt + NN);             // E
  float* cos2 = cos1 + NE;                      // E
  short* h1b  = (short*)(cos2 + NE);            // N*256 bf16
  short* nfb  = h1b + (size_t)NN * 256;         // N*128 bf16
  short* WaT1 = nfb + (size_t)NN * 128;         // 128*128 bf16
  short* WbT1 = WaT1 + 128 * 128;               // 128*128
  short* We2T = WbT1 + 128 * 128;               // 256*128
  short* WaT2 = We2T + 256 * 128;               // 256*256
  short* WbT2 = WaT2 + 256 * 256;               // 256*256
  short* Wl1T = WbT2 + 256 * 256;               // 256*256
  int*   off2 = (int*)(Wl1T + 256 * 256);       // N
  int*   perm = off2 + NN;                      // E
  int*   dsts = perm + NE;                      // E

  size_t need = ((size_t)NN * 128 + (size_t)NN * 256 + NN + 2 * (size_t)NE) * 4 +
                ((size_t)NN * 256 + (size_t)NN * 128 +
                 (size_t)128 * 128 * 2 + (size_t)256 * 128 +
                 (size_t)256 * 256 * 3) * 2 +
                ((size_t)NN + 2 * (size_t)NE) * 4;
  if (ws_size < need) return;

  // weight transpose+convert and nf convert (tiny)
  wt_k<<<(128 * 128 + 255) / 256, 256, 0, stream>>>(Wr1a, WaT1, 128, 128);
  wt_k<<<(128 * 128 + 255) / 256, 256, 0, stream>>>(Wr1b, WbT1, 128, 128);
  wt_k<<<(128 * 256 + 255) / 256, 256, 0, stream>>>(We2, We2T, 128, 256);
  wt_k<<<(256 * 256 + 255) / 256, 256, 0, stream>>>(Wr2a, WaT2, 256, 256);
  wt_k<<<(256 * 256 + 255) / 256, 256, 0, stream>>>(Wr2b, WbT2, 256, 256);
  wt_k<<<(256 * 256 + 255) / 256, 256, 0, stream>>>(Wl1, Wl1T, 256, 256);
  cvt_k<<<(NN * 128 / 4 + 255) / 256, 256, 0, stream>>>(nf, nfb, NN * 128 / 4);

  // zero s1, s2, cnt (contiguous)
  hipMemsetAsync(s1, 0, ((size_t)NN * 128 + (size_t)NN * 256 + NN) * 4, stream);

  edge1_k<<<NE / 4, 256, 0, stream>>>(nfb, src, dst, cos1, cnt);

  // counting sort by dst
  scan_k<<<1, 1024, 0, stream>>>(cnt, off2);
  perm_k<<<NE / 256, 256, 0, stream>>>(dst, off2, perm, dsts);

  edge_mlp1<<<NE / 64, 256, 0, stream>>>(nfb, ef, src, perm, dsts, We1, be1,
                                         WaT1, br1a, WbT1, br1b, cos1, s1);

  h1m_k<<<(NN + 63) / 64, 256, 0, stream>>>(nf, s1, cnt, Wl1T, bl1, h1b);

  edge2_k<<<NE / 4, 256, 0, stream>>>(h1b, src, dst, cos2);

  edge_mlp2<<<NE / 64, 256, 0, stream>>>(h1b, ef, src, perm, dsts, We1, be1,
                                         We2T, be2, WaT2, br2a, WbT2, br2b,
                                         cos2, s2);

  out_k<<<NN / 8, dim3(32, 8), 0, stream>>>(h1b, s2, cnt, Wl2, bl2, (float*)d_out);
}

// Round 7
// 1627.635 us; speedup vs baseline: 6.9692x; 1.0748x over previous
//
#include <hip/hip_runtime.h>
#include <math.h>

#define NN 50000
#define NE 800000

typedef short bf8 __attribute__((ext_vector_type(8)));
typedef short bf4v __attribute__((ext_vector_type(4)));
typedef float f4 __attribute__((ext_vector_type(4)));

// float -> bf16 bits, round-to-nearest-even (values are finite)
__device__ __forceinline__ short f2b(float f) {
  unsigned int u = __float_as_uint(f);
  unsigned int r = (u + 0x7FFFu + ((u >> 16) & 1u)) >> 16;
  return (short)(unsigned short)r;
}
__device__ __forceinline__ float b2f(short s) {
  return __uint_as_float(((unsigned int)(unsigned short)s) << 16);
}
__device__ __forceinline__ f4 b2f4(bf4v p) {
  f4 v;
  v[0] = b2f(p[0]); v[1] = b2f(p[1]); v[2] = b2f(p[2]); v[3] = b2f(p[3]);
  return v;
}

// ---------------- weight transpose + bf16 convert -----------------------------
__global__ __launch_bounds__(256) void wt_k(const float* __restrict__ in,
                                            short* __restrict__ out,
                                            int K, int N) {
  int i = blockIdx.x * 256 + threadIdx.x;
  if (i >= K * N) return;
  int n = i / K, k = i - n * K;
  out[i] = f2b(in[(size_t)k * N + n]);
}

// plain fp32 -> bf16 convert (4 elems/thread)
__global__ __launch_bounds__(256) void cvt_k(const float* __restrict__ in,
                                             short* __restrict__ out, int n4) {
  int i = blockIdx.x * 256 + threadIdx.x;
  if (i >= n4) return;
  f4 v = *(const f4*)&in[(size_t)i * 4];
  bf4v p;
  p[0] = f2b(v[0]); p[1] = f2b(v[1]); p[2] = f2b(v[2]); p[3] = f2b(v[3]);
  *(bf4v*)&out[(size_t)i * 4] = p;
}

// ---------------- degree count -------------------------------------------------
__global__ __launch_bounds__(256) void cnt_k(const int* __restrict__ dst,
                                             int* __restrict__ cnt) {
  int e = blockIdx.x * 256 + threadIdx.x;
  if (e >= NE) return;
  atomicAdd(&cnt[dst[e]], 1);
}

// ---------------- counting-sort by dst ----------------------------------------
__global__ __launch_bounds__(1024) void scan_k(const int* __restrict__ cnt,
                                               int* __restrict__ off2) {
  __shared__ int buf[1024];
  __shared__ int carry_s;
  const int t = threadIdx.x;
  if (t == 0) carry_s = 0;
  __syncthreads();
  const int nch = (NN + 1023) / 1024;
  for (int ch = 0; ch < nch; ++ch) {
    const int i = ch * 1024 + t;
    const int v = (i < NN) ? cnt[i] : 0;
    buf[t] = v;
    __syncthreads();
#pragma unroll
    for (int o = 1; o < 1024; o <<= 1) {
      int x = (t >= o) ? buf[t - o] : 0;
      __syncthreads();
      buf[t] += x;
      __syncthreads();
    }
    const int incl = buf[t];
    const int carry = carry_s;
    if (i < NN) off2[i] = carry + incl - v;
    __syncthreads();
    if (t == 1023) carry_s = carry + incl;
    __syncthreads();
  }
}

__global__ __launch_bounds__(256) void perm_k(const int* __restrict__ dst,
                                              int* __restrict__ off2,
                                              int* __restrict__ perm,
                                              int* __restrict__ dsts) {
  int e = blockIdx.x * 256 + threadIdx.x;
  if (e >= NE) return;
  int d = dst[e];
  int p = atomicAdd(&off2[d], 1);
  perm[p] = e;
  dsts[p] = d;
}

// ---------------- fused edge-MLP layer 1 (bf16 MFMA, fused cos1) --------------

__global__ __launch_bounds__(256, 5) void edge_mlp1(
    const short* __restrict__ nfb, const float* __restrict__ ef,
    const int* __restrict__ src, const int* __restrict__ perm,
    const int* __restrict__ dsts,
    const float* __restrict__ We1, const float* __restrict__ be1,
    const short* __restrict__ WaT, const float* __restrict__ ba,
    const short* __restrict__ WbT, const float* __restrict__ bbv,
    float* __restrict__ s1)
{
  __shared__ __align__(16) short Ms[64 * 136];   // 17408 B (M / T / R reuse)
  __shared__ int dse[64];
  const int t = threadIdx.x;
  const int e0 = blockIdx.x * 64;

  if (t < 64) dse[t] = dsts[e0 + t];

  // ---- build message tile M (bf16); cos1 computed in-place via 4-lane reduce --
  {
    const int e = t >> 2;
    const int kb = (t & 3) * 32;
    const int pe = perm[e0 + e];
    const int s = src[pe];
    const int d = dsts[e0 + e];
    const float f0 = ef[2 * pe], f1 = ef[2 * pe + 1];
    const short* hrow = &nfb[(size_t)s * 128];
    const short* drow = &nfb[(size_t)d * 128];

    // partial dot/norms over this quarter (32 comps)
    float ss = 0.f, dd = 0.f, sd = 0.f;
#pragma unroll
    for (int j = 0; j < 4; ++j) {
      const int k = kb + j * 8;
      bf8 hb = *(const bf8*)&hrow[k];
      bf8 db = *(const bf8*)&drow[k];
#pragma unroll
      for (int x = 0; x < 8; ++x) {
        float hs = b2f(hb[x]), hd = b2f(db[x]);
        ss = fmaf(hs, hs, ss);
        dd = fmaf(hd, hd, dd);
        sd = fmaf(hs, hd, sd);
      }
    }
    ss += __shfl_xor(ss, 1); ss += __shfl_xor(ss, 2);
    dd += __shfl_xor(dd, 1); dd += __shfl_xor(dd, 2);
    sd += __shfl_xor(sd, 1); sd += __shfl_xor(sd, 2);
    const float c = sd / (fmaxf(sqrtf(ss), 1e-12f) * fmaxf(sqrtf(dd), 1e-12f));

#pragma unroll
    for (int j = 0; j < 4; ++j) {
      const int k = kb + j * 8;
      bf8 hb = *(const bf8*)&hrow[k];   // L1-hot reload
      f4 wa0 = *(const f4*)&We1[k];
      f4 wa1 = *(const f4*)&We1[k + 4];
      f4 wb0 = *(const f4*)&We1[128 + k];
      f4 wb1 = *(const f4*)&We1[128 + k + 4];
      f4 b0 = *(const f4*)&be1[k];
      f4 b1 = *(const f4*)&be1[k + 4];
      bf8 pk;
#pragma unroll
      for (int x = 0; x < 4; ++x) {
        pk[x]     = f2b(c * fmaf(f0, wa0[x], fmaf(f1, wb0[x], b0[x])) * b2f(hb[x]));
        pk[x + 4] = f2b(c * fmaf(f0, wa1[x], fmaf(f1, wb1[x], b1[x])) * b2f(hb[x + 4]));
      }
      *(bf8*)&Ms[e * 136 + k] = pk;
    }
  }
  __syncthreads();

  const int lane = t & 63, wv = t >> 6;
  const int lr = lane & 15;
  const int lq = lane >> 4;
  const int n0 = wv * 32;

  f4 acc[2][4];
#pragma unroll
  for (int a = 0; a < 2; ++a)
#pragma unroll
    for (int b = 0; b < 4; ++b) acc[a][b] = (f4)0.f;

  // ---- stage 1: K = 128 ----
#pragma unroll
  for (int kc = 0; kc < 128; kc += 32) {
    bf8 aF[2], bF[4];
#pragma unroll
    for (int a = 0; a < 2; ++a)
      aF[a] = *(const bf8*)&WaT[(size_t)(n0 + a * 16 + lr) * 128 + kc + lq * 8];
#pragma unroll
    for (int b = 0; b < 4; ++b)
      bF[b] = *(const bf8*)&Ms[(b * 16 + lr) * 136 + kc + lq * 8];
#pragma unroll
    for (int a = 0; a < 2; ++a)
#pragma unroll
      for (int b = 0; b < 4; ++b)
        acc[a][b] = __builtin_amdgcn_mfma_f32_16x16x32_bf16(aF[a], bF[b], acc[a][b], 0, 0, 0);
  }
  __syncthreads();

  // T[e][n] = relu(acc + ba[n]) -> Ms
#pragma unroll
  for (int a = 0; a < 2; ++a) {
    const int n = n0 + a * 16 + lq * 4;
    f4 bb = *(const f4*)&ba[n];
#pragma unroll
    for (int b = 0; b < 4; ++b) {
      bf4v pk;
#pragma unroll
      for (int r = 0; r < 4; ++r) pk[r] = f2b(fmaxf(acc[a][b][r] + bb[r], 0.f));
      *(bf4v*)&Ms[(b * 16 + lr) * 136 + n] = pk;
    }
  }
  __syncthreads();

  // ---- stage 2: K = 128 ----
#pragma unroll
  for (int a = 0; a < 2; ++a)
#pragma unroll
    for (int b = 0; b < 4; ++b) acc[a][b] = (f4)0.f;
#pragma unroll
  for (int kc = 0; kc < 128; kc += 32) {
    bf8 aF[2], bF[4];
#pragma unroll
    for (int a = 0; a < 2; ++a)
      aF[a] = *(const bf8*)&WbT[(size_t)(n0 + a * 16 + lr) * 128 + kc + lq * 8];
#pragma unroll
    for (int b = 0; b < 4; ++b)
      bF[b] = *(const bf8*)&Ms[(b * 16 + lr) * 136 + kc + lq * 8];
#pragma unroll
    for (int a = 0; a < 2; ++a)
#pragma unroll
      for (int b = 0; b < 4; ++b)
        acc[a][b] = __builtin_amdgcn_mfma_f32_16x16x32_bf16(aF[a], bF[b], acc[a][b], 0, 0, 0);
  }
  __syncthreads();   // all waves done reading Ms before R overwrite

  // R[e][n] = relu(acc + bb[n]) -> Ms (bf16; sums still accumulate in fp32)
#pragma unroll
  for (int a = 0; a < 2; ++a) {
    const int n = n0 + a * 16 + lq * 4;
    f4 bb = *(const f4*)&bbv[n];
#pragma unroll
    for (int b = 0; b < 4; ++b) {
      bf4v pk;
#pragma unroll
      for (int r = 0; r < 4; ++r) pk[r] = f2b(fmaxf(acc[a][b][r] + bb[r], 0.f));
      *(bf4v*)&Ms[(b * 16 + lr) * 136 + n] = pk;
    }
  }
  __syncthreads();

  // segmented reduce over sorted dst
  {
    const int f = t & 127;
    const int eb = (t >> 7) * 32;
    float run = 0.f;
    int pd = dse[eb];
#pragma unroll 4
    for (int e = eb; e < eb + 32; ++e) {
      const int d = dse[e];          // wave-uniform
      if (d != pd) {
        atomicAdd(&s1[(size_t)pd * 128 + f], run);
        run = 0.f;
        pd = d;
      }
      run += b2f(Ms[e * 136 + f]);
    }
    atomicAdd(&s1[(size_t)pd * 128 + f], run);
  }
}

// ---------------- fused edge-MLP layer 2 (bf16 MFMA, fused cos2) --------------
// LDS union: Ws (17408 B) lives inside M2s (33792 B); one extra barrier after
// stage B legalizes the overlap. 34.3 KB total -> 4 blocks/CU.

__global__ __launch_bounds__(256, 4) void edge_mlp2(
    const short* __restrict__ h1b, const float* __restrict__ ef,
    const int* __restrict__ src, const int* __restrict__ perm,
    const int* __restrict__ dsts,
    const float* __restrict__ We1, const float* __restrict__ be1,
    const short* __restrict__ We2T, const float* __restrict__ be2,
    const short* __restrict__ WaT, const float* __restrict__ ba,
    const short* __restrict__ WbT, const float* __restrict__ bbv,
    float* __restrict__ s2)
{
  __shared__ __align__(16) short U[64 * 264];    // 33792 B: Ws then M2s
  __shared__ int dse[64];
  __shared__ float cos_s[64];
  short* Ws  = U;                                // 64 x 136
  short* M2s = U;                                // 64 x 264
  float* cosP = (float*)(U + 64 * 136);          // [4][64][3] = 3072 B (dead after sync2)
  const int t = threadIdx.x;
  const int e0 = blockIdx.x * 64;

  const int lane = t & 63, wv = t >> 6;
  const int lr = lane & 15;
  const int lq = lane >> 4;
  const int n0 = wv * 64;

  // ---- prefetch src/dst h1b fragments (issue loads early) ----
  int pe_b[4], s_b[4], d_b[4];
#pragma unroll
  for (int b = 0; b < 4; ++b) pe_b[b] = perm[e0 + b * 16 + lr];
#pragma unroll
  for (int b = 0; b < 4; ++b) { s_b[b] = src[pe_b[b]]; d_b[b] = dsts[e0 + b * 16 + lr]; }
  bf4v hpre[4][4], hdre[4][4];
#pragma unroll
  for (int b = 0; b < 4; ++b)
#pragma unroll
    for (int a = 0; a < 4; ++a) {
      hpre[b][a] = *(const bf4v*)&h1b[(size_t)s_b[b] * 256 + n0 + a * 16 + lq * 4];
      hdre[b][a] = *(const bf4v*)&h1b[(size_t)d_b[b] * 256 + n0 + a * 16 + lq * 4];
    }

  if (t < 64) dse[t] = dsts[e0 + t];

  // ---- build relu(w1) tile (bf16) into Ws ----
  {
    const int e = t >> 2;
    const int kb = (t & 3) * 32;
    const int pe = perm[e0 + e];
    const float f0 = ef[2 * pe], f1 = ef[2 * pe + 1];
#pragma unroll
    for (int j = 0; j < 4; ++j) {
      const int k = kb + j * 8;
      f4 wa0 = *(const f4*)&We1[k];
      f4 wa1 = *(const f4*)&We1[k + 4];
      f4 wb0 = *(const f4*)&We1[128 + k];
      f4 wb1 = *(const f4*)&We1[128 + k + 4];
      f4 b0 = *(const f4*)&be1[k];
      f4 b1 = *(const f4*)&be1[k + 4];
      bf8 pk;
#pragma unroll
      for (int x = 0; x < 4; ++x) {
        pk[x]     = f2b(fmaxf(fmaf(f0, wa0[x], fmaf(f1, wb0[x], b0[x])), 0.f));
        pk[x + 4] = f2b(fmaxf(fmaf(f0, wa1[x], fmaf(f1, wb1[x], b1[x])), 0.f));
      }
      *(bf8*)&Ws[e * 136 + k] = pk;
    }
  }

  // ---- cos2 partials: per lane over its 16 components, reduce over lq ----
  {
    float ssv[4], ddv[4], sdv[4];
#pragma unroll
    for (int b = 0; b < 4; ++b) {
      float ss = 0.f, dd = 0.f, sd = 0.f;
#pragma unroll
      for (int a = 0; a < 4; ++a) {
        f4 hs = b2f4(hpre[b][a]);
        f4 hd = b2f4(hdre[b][a]);
#pragma unroll
        for (int r = 0; r < 4; ++r) {
          ss = fmaf(hs[r], hs[r], ss);
          dd = fmaf(hd[r], hd[r], dd);
          sd = fmaf(hs[r], hd[r], sd);
        }
      }
      ssv[b] = ss; ddv[b] = dd; sdv[b] = sd;
    }
#pragma unroll
    for (int b = 0; b < 4; ++b) {
      ssv[b] += __shfl_xor(ssv[b], 16); ssv[b] += __shfl_xor(ssv[b], 32);
      ddv[b] += __shfl_xor(ddv[b], 16); ddv[b] += __shfl_xor(ddv[b], 32);
      sdv[b] += __shfl_xor(sdv[b], 16); sdv[b] += __shfl_xor(sdv[b], 32);
    }
    if (lq == 0) {
#pragma unroll
      for (int b = 0; b < 4; ++b) {
        float* p = &cosP[(wv * 64 + b * 16 + lr) * 3];
        p[0] = ssv[b]; p[1] = ddv[b]; p[2] = sdv[b];
      }
    }
  }
  __syncthreads();   // Ws + cosP ready

  // wave 0's first 64 lanes finish cos2 while everyone starts stage B
  if (t < 64) {
    float ss = 0.f, dd = 0.f, sd = 0.f;
#pragma unroll
    for (int w = 0; w < 4; ++w) {
      const float* p = &cosP[(w * 64 + t) * 3];
      ss += p[0]; dd += p[1]; sd += p[2];
    }
    cos_s[t] = sd / (fmaxf(sqrtf(ss), 1e-12f) * fmaxf(sqrtf(dd), 1e-12f));
  }

  f4 acc[4][4];
#pragma unroll
  for (int a = 0; a < 4; ++a)
#pragma unroll
    for (int b = 0; b < 4; ++b) acc[a][b] = (f4)0.f;

  // ---- stage B: K = 128 (reads Ws) ----
#pragma unroll
  for (int kc = 0; kc < 128; kc += 32) {
    bf8 aF[4], bF[4];
#pragma unroll
    for (int a = 0; a < 4; ++a)
      aF[a] = *(const bf8*)&We2T[(size_t)(n0 + a * 16 + lr) * 128 + kc + lq * 8];
#pragma unroll
    for (int b = 0; b < 4; ++b)
      bF[b] = *(const bf8*)&Ws[(b * 16 + lr) * 136 + kc + lq * 8];
#pragma unroll
    for (int a = 0; a < 4; ++a)
#pragma unroll
      for (int b = 0; b < 4; ++b)
        acc[a][b] = __builtin_amdgcn_mfma_f32_16x16x32_bf16(aF[a], bF[b], acc[a][b], 0, 0, 0);
  }
  __syncthreads();   // Ws dead; cos_s ready; M2s region may now be written

  // m2[e][n] = (w2 + be2[n]) * cos2[e] * h1[src[e]][n] -> M2s
#pragma unroll
  for (int b = 0; b < 4; ++b) {
    const float c = cos_s[b * 16 + lr];
#pragma unroll
    for (int a = 0; a < 4; ++a) {
      const int n = n0 + a * 16 + lq * 4;
      f4 bb = *(const f4*)&be2[n];
      f4 hv = b2f4(hpre[b][a]);
      bf4v pk;
#pragma unroll
      for (int r = 0; r < 4; ++r)
        pk[r] = f2b((acc[a][b][r] + bb[r]) * c * hv[r]);
      *(bf4v*)&M2s[(b * 16 + lr) * 264 + n] = pk;
    }
  }
  __syncthreads();

  // ---- stage C: K = 256, relu ----
#pragma unroll
  for (int a = 0; a < 4; ++a)
#pragma unroll
    for (int b = 0; b < 4; ++b) acc[a][b] = (f4)0.f;
  for (int kc = 0; kc < 256; kc += 32) {
    bf8 aF[4], bF[4];
#pragma unroll
    for (int a = 0; a < 4; ++a)
      aF[a] = *(const bf8*)&WaT[(size_t)(n0 + a * 16 + lr) * 256 + kc + lq * 8];
#pragma unroll
    for (int b = 0; b < 4; ++b)
      bF[b] = *(const bf8*)&M2s[(b * 16 + lr) * 264 + kc + lq * 8];
#pragma unroll
    for (int a = 0; a < 4; ++a)
#pragma unroll
      for (int b = 0; b < 4; ++b)
        acc[a][b] = __builtin_amdgcn_mfma_f32_16x16x32_bf16(aF[a], bF[b], acc[a][b], 0, 0, 0);
  }
  __syncthreads();

#pragma unroll
  for (int a = 0; a < 4; ++a) {
    const int n = n0 + a * 16 + lq * 4;
    f4 bb = *(const f4*)&ba[n];
#pragma unroll
    for (int b = 0; b < 4; ++b) {
      bf4v pk;
#pragma unroll
      for (int r = 0; r < 4; ++r) pk[r] = f2b(fmaxf(acc[a][b][r] + bb[r], 0.f));
      *(bf4v*)&M2s[(b * 16 + lr) * 264 + n] = pk;
    }
  }
  __syncthreads();

  // ---- stage D: K = 256 ----
#pragma unroll
  for (int a = 0; a < 4; ++a)
#pragma unroll
    for (int b = 0; b < 4; ++b) acc[a][b] = (f4)0.f;
  for (int kc = 0; kc < 256; kc += 32) {
    bf8 aF[4], bF[4];
#pragma unroll
    for (int a = 0; a < 4; ++a)
      aF[a] = *(const bf8*)&WbT[(size_t)(n0 + a * 16 + lr) * 256 + kc + lq * 8];
#pragma unroll
    for (int b = 0; b < 4; ++b)
      bF[b] = *(const bf8*)&M2s[(b * 16 + lr) * 264 + kc + lq * 8];
#pragma unroll
    for (int a = 0; a < 4; ++a)
#pragma unroll
      for (int b = 0; b < 4; ++b)
        acc[a][b] = __builtin_amdgcn_mfma_f32_16x16x32_bf16(aF[a], bF[b], acc[a][b], 0, 0, 0);
  }
  __syncthreads();  // all waves done reading M2s before fp32 reuse

  // epilogue: two n-halves; write relu+bias fp32 into RF (=M2s), seg-reduce
  float* RF = (float*)M2s;   // 64 x 132 fp32 = 33792 B
#pragma unroll
  for (int h = 0; h < 2; ++h) {
    if ((wv >> 1) == h) {
#pragma unroll
      for (int a = 0; a < 4; ++a) {
        const int n = n0 + a * 16 + lq * 4;
        f4 bb = *(const f4*)&bbv[n];
#pragma unroll
        for (int b = 0; b < 4; ++b) {
          f4 v;
#pragma unroll
          for (int r = 0; r < 4; ++r) v[r] = fmaxf(acc[a][b][r] + bb[r], 0.f);
          *(f4*)&RF[(b * 16 + lr) * 132 + (n - h * 128)] = v;
        }
      }
    }
    __syncthreads();
    {
      const int f = t & 127;
      const int eb = (t >> 7) * 32;
      float run = 0.f;
      int pd = dse[eb];
#pragma unroll 4
      for (int e = eb; e < eb + 32; ++e) {
        const int d = dse[e];        // wave-uniform
        if (d != pd) {
          atomicAdd(&s2[(size_t)pd * 256 + h * 128 + f], run);
          run = 0.f;
          pd = d;
        }
        run += RF[e * 132 + f];
      }
      atomicAdd(&s2[(size_t)pd * 256 + h * 128 + f], run);
    }
    __syncthreads();
  }
}

// ---------------- node linear 1 (bf16 MFMA) -> h1b (bf16) ---------------------

__global__ __launch_bounds__(256, 3) void h1m_k(
    const float* __restrict__ nf, const float* __restrict__ s1,
    const int* __restrict__ cnt, const short* __restrict__ Wl1T,
    const float* __restrict__ bl1, short* __restrict__ h1b)
{
  __shared__ __align__(16) short As[64 * 264];
  const int t = threadIdx.x;
  const int v0 = blockIdx.x * 64;

  {
    const int row = t >> 2;
    const int kb = (t & 3) * 64;
    int gn = v0 + row;
    if (gn >= NN) gn = NN - 1;
    const float inv = 1.f / fmaxf((float)cnt[gn], 1.f);
#pragma unroll
    for (int j = 0; j < 64; j += 8) {
      const int k = kb + j;
      f4 x0, x1;
      if (k < 128) {
        x0 = *(const f4*)&nf[(size_t)gn * 128 + k];
        x1 = *(const f4*)&nf[(size_t)gn * 128 + k + 4];
      } else {
        x0 = *(const f4*)&s1[(size_t)gn * 128 + (k - 128)];
        x1 = *(const f4*)&s1[(size_t)gn * 128 + (k - 124)];
#pragma unroll
        for (int x = 0; x < 4; ++x) { x0[x] *= inv; x1[x] *= inv; }
      }
      bf8 pk;
#pragma unroll
      for (int x = 0; x < 4; ++x) { pk[x] = f2b(x0[x]); pk[x + 4] = f2b(x1[x]); }
      *(bf8*)&As[row * 264 + k] = pk;
    }
  }
  __syncthreads();

  const int lane = t & 63, wv = t >> 6;
  const int lr = lane & 15;
  const int lq = lane >> 4;
  const int n0 = wv * 64;

  f4 acc[4][4];
#pragma unroll
  for (int a = 0; a < 4; ++a)
#pragma unroll
    for (int b = 0; b < 4; ++b) acc[a][b] = (f4)0.f;

  for (int kc = 0; kc < 256; kc += 32) {
    bf8 aF[4], bF[4];
#pragma unroll
    for (int a = 0; a < 4; ++a)
      aF[a] = *(const bf8*)&Wl1T[(size_t)(n0 + a * 16 + lr) * 256 + kc + lq * 8];
#pragma unroll
    for (int b = 0; b < 4; ++b)
      bF[b] = *(const bf8*)&As[(b * 16 + lr) * 264 + kc + lq * 8];
#pragma unroll
    for (int a = 0; a < 4; ++a)
#pragma unroll
      for (int b = 0; b < 4; ++b)
        acc[a][b] = __builtin_amdgcn_mfma_f32_16x16x32_bf16(aF[a], bF[b], acc[a][b], 0, 0, 0);
  }

#pragma unroll
  for (int b = 0; b < 4; ++b) {
    const int gn = v0 + b * 16 + lr;
    if (gn >= NN) continue;
#pragma unroll
    for (int a = 0; a < 4; ++a) {
      const int n = n0 + a * 16 + lq * 4;
      f4 bb = *(const f4*)&bl1[n];
      bf4v pk;
      pk[0] = f2b(fmaxf(acc[a][b][0] + bb[0], 0.f));
      pk[1] = f2b(fmaxf(acc[a][b][1] + bb[1], 0.f));
      pk[2] = f2b(fmaxf(acc[a][b][2] + bb[2], 0.f));
      pk[3] = f2b(fmaxf(acc[a][b][3] + bb[3], 0.f));
      *(bf4v*)&h1b[(size_t)gn * 256 + n] = pk;
    }
  }
}

// ---------------- final linear: out = concat(h1b, s2/cnt) @ Wl2 + bl2 ---------

__global__ __launch_bounds__(256) void out_k(
    const short* __restrict__ h1b, const float* __restrict__ s2,
    const int* __restrict__ cnt, const float* __restrict__ Wl2,
    const float* __restrict__ bl2, float* __restrict__ out)
{
  __shared__ float A8[8][512];
  const int n0 = blockIdx.x * 8;
  const int tx = threadIdx.x;
  const int ty = threadIdx.y;
  const int t = ty * 32 + tx;
  const int row = t >> 5;
  const int k0 = (t & 31) * 16;
  const int n = n0 + row;
  const float inv = 1.0f / fmaxf((float)cnt[n], 1.0f);
#pragma unroll
  for (int i = 0; i < 16; i += 4) {
    int k = k0 + i;
    f4 v;
    if (k < 256) {
      v = b2f4(*(const bf4v*)&h1b[(size_t)n * 256 + k]);
    } else {
      v = *(const f4*)&s2[(size_t)n * 256 + (k - 256)];
      v[0] *= inv; v[1] *= inv; v[2] *= inv; v[3] *= inv;
    }
    *(f4*)&A8[row][k] = v;
  }
  __syncthreads();
  float acc = bl2[tx];
#pragma unroll 8
  for (int k = 0; k < 512; k++) acc = fmaf(A8[ty][k], Wl2[(size_t)k * 32 + tx], acc);
  out[(size_t)(n0 + ty) * 32 + tx] = acc;
}

// ---------------- launch ------------------------------------------------------

extern "C" void kernel_launch(void* const* d_in, const int* in_sizes, int n_in,
                              void* d_out, int out_size, void* d_ws, size_t ws_size,
                              hipStream_t stream) {
  const float* nf   = (const float*)d_in[0];
  const float* ef   = (const float*)d_in[1];
  const int*   src  = (const int*)d_in[2];
  const int*   dst  = (const int*)d_in[3];
  const float* We1  = (const float*)d_in[4];
  const float* be1  = (const float*)d_in[5];
  const float* Wr1a = (const float*)d_in[6];
  const float* br1a = (const float*)d_in[7];
  const float* Wr1b = (const float*)d_in[8];
  const float* br1b = (const float*)d_in[9];
  const float* Wl1  = (const float*)d_in[10];
  const float* bl1  = (const float*)d_in[11];
  const float* We2  = (const float*)d_in[12];
  const float* be2  = (const float*)d_in[13];
  const float* Wr2a = (const float*)d_in[14];
  const float* br2a = (const float*)d_in[15];
  const float* Wr2b = (const float*)d_in[16];
  const float* br2b = (const float*)d_in[17];
  const float* Wl2  = (const float*)d_in[18];
  const float* bl2  = (const float*)d_in[19];

  float* ws = (float*)d_ws;
  float* s1   = ws;                             // N*128 f
  float* s2   = s1 + (size_t)NN * 128;          // N*256 f
  int*   cnt  = (int*)(s2 + (size_t)NN * 256);  // N
  short* h1b  = (short*)(cnt + NN);             // N*256 bf16
  short* nfb  = h1b + (size_t)NN * 256;         // N*128 bf16
  short* WaT1 = nfb + (size_t)NN * 128;         // 128*128 bf16
  short* WbT1 = WaT1 + 128 * 128;               // 128*128
  short* We2T = WbT1 + 128 * 128;               // 256*128
  short* WaT2 = We2T + 256 * 128;               // 256*256
  short* WbT2 = WaT2 + 256 * 256;               // 256*256
  short* Wl1T = WbT2 + 256 * 256;               // 256*256
  int*   off2 = (int*)(Wl1T + 256 * 256);       // N
  int*   perm = off2 + NN;                      // E
  int*   dsts = perm + NE;                      // E

  size_t need = ((size_t)NN * 128 + (size_t)NN * 256 + NN) * 4 +
                ((size_t)NN * 256 + (size_t)NN * 128 +
                 (size_t)128 * 128 * 2 + (size_t)256 * 128 +
                 (size_t)256 * 256 * 3) * 2 +
                ((size_t)NN + 2 * (size_t)NE) * 4;
  if (ws_size < need) return;

  // weight transpose+convert and nf convert (tiny)
  wt_k<<<(128 * 128 + 255) / 256, 256, 0, stream>>>(Wr1a, WaT1, 128, 128);
  wt_k<<<(128 * 128 + 255) / 256, 256, 0, stream>>>(Wr1b, WbT1, 128, 128);
  wt_k<<<(128 * 256 + 255) / 256, 256, 0, stream>>>(We2, We2T, 128, 256);
  wt_k<<<(256 * 256 + 255) / 256, 256, 0, stream>>>(Wr2a, WaT2, 256, 256);
  wt_k<<<(256 * 256 + 255) / 256, 256, 0, stream>>>(Wr2b, WbT2, 256, 256);
  wt_k<<<(256 * 256 + 255) / 256, 256, 0, stream>>>(Wl1, Wl1T, 256, 256);
  cvt_k<<<(NN * 128 / 4 + 255) / 256, 256, 0, stream>>>(nf, nfb, NN * 128 / 4);

  // zero s1, s2, cnt (contiguous)
  hipMemsetAsync(s1, 0, ((size_t)NN * 128 + (size_t)NN * 256 + NN) * 4, stream);

  cnt_k<<<NE / 256, 256, 0, stream>>>(dst, cnt);

  // counting sort by dst
  scan_k<<<1, 1024, 0, stream>>>(cnt, off2);
  perm_k<<<NE / 256, 256, 0, stream>>>(dst, off2, perm, dsts);

  edge_mlp1<<<NE / 64, 256, 0, stream>>>(nfb, ef, src, perm, dsts, We1, be1,
                                         WaT1, br1a, WbT1, br1b, s1);

  h1m_k<<<(NN + 63) / 64, 256, 0, stream>>>(nf, s1, cnt, Wl1T, bl1, h1b);

  edge_mlp2<<<NE / 64, 256, 0, stream>>>(h1b, ef, src, perm, dsts, We1, be1,
                                         We2T, be2, WaT2, br2a, WbT2, br2b, s2);

  out_k<<<NN / 8, dim3(32, 8), 0, stream>>>(h1b, s2, cnt, Wl2, bl2, (float*)d_out);
}

// Round 8
// 1597.301 us; speedup vs baseline: 7.1016x; 1.0190x over previous
//
#include <hip/hip_runtime.h>
#include <math.h>

#define NN 50000
#define NE 800000

typedef short bf8 __attribute__((ext_vector_type(8)));
typedef short bf4v __attribute__((ext_vector_type(4)));
typedef float f4 __attribute__((ext_vector_type(4)));

// float -> bf16 bits, round-to-nearest-even (values are finite)
__device__ __forceinline__ short f2b(float f) {
  unsigned int u = __float_as_uint(f);
  unsigned int r = (u + 0x7FFFu + ((u >> 16) & 1u)) >> 16;
  return (short)(unsigned short)r;
}
__device__ __forceinline__ float b2f(short s) {
  return __uint_as_float(((unsigned int)(unsigned short)s) << 16);
}
__device__ __forceinline__ f4 b2f4(bf4v p) {
  f4 v;
  v[0] = b2f(p[0]); v[1] = b2f(p[1]); v[2] = b2f(p[2]); v[3] = b2f(p[3]);
  return v;
}

// ---------------- weight transpose + bf16 convert -----------------------------
__global__ __launch_bounds__(256) void wt_k(const float* __restrict__ in,
                                            short* __restrict__ out,
                                            int K, int N) {
  int i = blockIdx.x * 256 + threadIdx.x;
  if (i >= K * N) return;
  int n = i / K, k = i - n * K;
  out[i] = f2b(in[(size_t)k * N + n]);
}

// plain fp32 -> bf16 convert (4 elems/thread)
__global__ __launch_bounds__(256) void cvt_k(const float* __restrict__ in,
                                             short* __restrict__ out, int n4) {
  int i = blockIdx.x * 256 + threadIdx.x;
  if (i >= n4) return;
  f4 v = *(const f4*)&in[(size_t)i * 4];
  bf4v p;
  p[0] = f2b(v[0]); p[1] = f2b(v[1]); p[2] = f2b(v[2]); p[3] = f2b(v[3]);
  *(bf4v*)&out[(size_t)i * 4] = p;
}

// ---------------- degree count -------------------------------------------------
__global__ __launch_bounds__(256) void cnt_k(const int* __restrict__ dst,
                                             int* __restrict__ cnt) {
  int e = blockIdx.x * 256 + threadIdx.x;
  if (e >= NE) return;
  atomicAdd(&cnt[dst[e]], 1);
}

// ---------------- counting-sort by dst ----------------------------------------
__global__ __launch_bounds__(1024) void scan_k(const int* __restrict__ cnt,
                                               int* __restrict__ off2) {
  __shared__ int buf[1024];
  __shared__ int carry_s;
  const int t = threadIdx.x;
  if (t == 0) carry_s = 0;
  __syncthreads();
  const int nch = (NN + 1023) / 1024;
  for (int ch = 0; ch < nch; ++ch) {
    const int i = ch * 1024 + t;
    const int v = (i < NN) ? cnt[i] : 0;
    buf[t] = v;
    __syncthreads();
#pragma unroll
    for (int o = 1; o < 1024; o <<= 1) {
      int x = (t >= o) ? buf[t - o] : 0;
      __syncthreads();
      buf[t] += x;
      __syncthreads();
    }
    const int incl = buf[t];
    const int carry = carry_s;
    if (i < NN) off2[i] = carry + incl - v;
    __syncthreads();
    if (t == 1023) carry_s = carry + incl;
    __syncthreads();
  }
}

__global__ __launch_bounds__(256) void perm_k(const int* __restrict__ dst,
                                              int* __restrict__ off2,
                                              int* __restrict__ perm,
                                              int* __restrict__ dsts) {
  int e = blockIdx.x * 256 + threadIdx.x;
  if (e >= NE) return;
  int d = dst[e];
  int p = atomicAdd(&off2[d], 1);
  perm[p] = e;
  dsts[p] = d;
}

// ---------------- fused edge-MLP layer 1 (bf16 MFMA, fused cos1) --------------

__global__ __launch_bounds__(256, 5) void edge_mlp1(
    const short* __restrict__ nfb, const float* __restrict__ ef,
    const int* __restrict__ src, const int* __restrict__ perm,
    const int* __restrict__ dsts,
    const float* __restrict__ We1, const float* __restrict__ be1,
    const short* __restrict__ WaT, const float* __restrict__ ba,
    const short* __restrict__ WbT, const float* __restrict__ bbv,
    float* __restrict__ s1)
{
  __shared__ __align__(16) short Ms[64 * 136];   // 17408 B (M / T / R reuse)
  __shared__ int dse[64];
  const int t = threadIdx.x;
  const int e0 = blockIdx.x * 64;

  if (t < 64) dse[t] = dsts[e0 + t];

  // ---- build message tile M (bf16); cos1 computed in-place via 4-lane reduce --
  {
    const int e = t >> 2;
    const int kb = (t & 3) * 32;
    const int pe = perm[e0 + e];
    const int s = src[pe];
    const int d = dsts[e0 + e];
    const float f0 = ef[2 * pe], f1 = ef[2 * pe + 1];
    const short* hrow = &nfb[(size_t)s * 128];
    const short* drow = &nfb[(size_t)d * 128];

    // partial dot/norms over this quarter (32 comps)
    float ss = 0.f, dd = 0.f, sd = 0.f;
#pragma unroll
    for (int j = 0; j < 4; ++j) {
      const int k = kb + j * 8;
      bf8 hb = *(const bf8*)&hrow[k];
      bf8 db = *(const bf8*)&drow[k];
#pragma unroll
      for (int x = 0; x < 8; ++x) {
        float hs = b2f(hb[x]), hd = b2f(db[x]);
        ss = fmaf(hs, hs, ss);
        dd = fmaf(hd, hd, dd);
        sd = fmaf(hs, hd, sd);
      }
    }
    ss += __shfl_xor(ss, 1); ss += __shfl_xor(ss, 2);
    dd += __shfl_xor(dd, 1); dd += __shfl_xor(dd, 2);
    sd += __shfl_xor(sd, 1); sd += __shfl_xor(sd, 2);
    const float c = sd / (fmaxf(sqrtf(ss), 1e-12f) * fmaxf(sqrtf(dd), 1e-12f));

#pragma unroll
    for (int j = 0; j < 4; ++j) {
      const int k = kb + j * 8;
      bf8 hb = *(const bf8*)&hrow[k];   // L1-hot reload
      f4 wa0 = *(const f4*)&We1[k];
      f4 wa1 = *(const f4*)&We1[k + 4];
      f4 wb0 = *(const f4*)&We1[128 + k];
      f4 wb1 = *(const f4*)&We1[128 + k + 4];
      f4 b0 = *(const f4*)&be1[k];
      f4 b1 = *(const f4*)&be1[k + 4];
      bf8 pk;
#pragma unroll
      for (int x = 0; x < 4; ++x) {
        pk[x]     = f2b(c * fmaf(f0, wa0[x], fmaf(f1, wb0[x], b0[x])) * b2f(hb[x]));
        pk[x + 4] = f2b(c * fmaf(f0, wa1[x], fmaf(f1, wb1[x], b1[x])) * b2f(hb[x + 4]));
      }
      *(bf8*)&Ms[e * 136 + k] = pk;
    }
  }
  __syncthreads();

  const int lane = t & 63, wv = t >> 6;
  const int lr = lane & 15;
  const int lq = lane >> 4;
  const int n0 = wv * 32;

  f4 acc[2][4];
#pragma unroll
  for (int a = 0; a < 2; ++a)
#pragma unroll
    for (int b = 0; b < 4; ++b) acc[a][b] = (f4)0.f;

  // ---- stage 1: K = 128 ----
#pragma unroll
  for (int kc = 0; kc < 128; kc += 32) {
    bf8 aF[2], bF[4];
#pragma unroll
    for (int a = 0; a < 2; ++a)
      aF[a] = *(const bf8*)&WaT[(size_t)(n0 + a * 16 + lr) * 128 + kc + lq * 8];
#pragma unroll
    for (int b = 0; b < 4; ++b)
      bF[b] = *(const bf8*)&Ms[(b * 16 + lr) * 136 + kc + lq * 8];
#pragma unroll
    for (int a = 0; a < 2; ++a)
#pragma unroll
      for (int b = 0; b < 4; ++b)
        acc[a][b] = __builtin_amdgcn_mfma_f32_16x16x32_bf16(aF[a], bF[b], acc[a][b], 0, 0, 0);
  }
  __syncthreads();

  // T[e][n] = relu(acc + ba[n]) -> Ms
#pragma unroll
  for (int a = 0; a < 2; ++a) {
    const int n = n0 + a * 16 + lq * 4;
    f4 bb = *(const f4*)&ba[n];
#pragma unroll
    for (int b = 0; b < 4; ++b) {
      bf4v pk;
#pragma unroll
      for (int r = 0; r < 4; ++r) pk[r] = f2b(fmaxf(acc[a][b][r] + bb[r], 0.f));
      *(bf4v*)&Ms[(b * 16 + lr) * 136 + n] = pk;
    }
  }
  __syncthreads();

  // ---- stage 2: K = 128 ----
#pragma unroll
  for (int a = 0; a < 2; ++a)
#pragma unroll
    for (int b = 0; b < 4; ++b) acc[a][b] = (f4)0.f;
#pragma unroll
  for (int kc = 0; kc < 128; kc += 32) {
    bf8 aF[2], bF[4];
#pragma unroll
    for (int a = 0; a < 2; ++a)
      aF[a] = *(const bf8*)&WbT[(size_t)(n0 + a * 16 + lr) * 128 + kc + lq * 8];
#pragma unroll
    for (int b = 0; b < 4; ++b)
      bF[b] = *(const bf8*)&Ms[(b * 16 + lr) * 136 + kc + lq * 8];
#pragma unroll
    for (int a = 0; a < 2; ++a)
#pragma unroll
      for (int b = 0; b < 4; ++b)
        acc[a][b] = __builtin_amdgcn_mfma_f32_16x16x32_bf16(aF[a], bF[b], acc[a][b], 0, 0, 0);
  }
  __syncthreads();   // all waves done reading Ms before R overwrite

  // R[e][n] = relu(acc + bb[n]) -> Ms (bf16; sums still accumulate in fp32)
#pragma unroll
  for (int a = 0; a < 2; ++a) {
    const int n = n0 + a * 16 + lq * 4;
    f4 bb = *(const f4*)&bbv[n];
#pragma unroll
    for (int b = 0; b < 4; ++b) {
      bf4v pk;
#pragma unroll
      for (int r = 0; r < 4; ++r) pk[r] = f2b(fmaxf(acc[a][b][r] + bb[r], 0.f));
      *(bf4v*)&Ms[(b * 16 + lr) * 136 + n] = pk;
    }
  }
  __syncthreads();

  // segmented reduce over sorted dst
  {
    const int f = t & 127;
    const int eb = (t >> 7) * 32;
    float run = 0.f;
    int pd = dse[eb];
#pragma unroll 4
    for (int e = eb; e < eb + 32; ++e) {
      const int d = dse[e];          // wave-uniform
      if (d != pd) {
        atomicAdd(&s1[(size_t)pd * 128 + f], run);
        run = 0.f;
        pd = d;
      }
      run += b2f(Ms[e * 136 + f]);
    }
    atomicAdd(&s1[(size_t)pd * 128 + f], run);
  }
}

// ---------------- fused edge-MLP layer 2 (bf16 MFMA, fused cos2) --------------
// LDS union: Ws (17408 B) lives inside M2s (33792 B). 34.3 KB -> 4 blocks/CU.
// cos2 via STREAMING loads (no persistent prefetch arrays -> no VGPR spill).

__global__ __launch_bounds__(256, 4) void edge_mlp2(
    const short* __restrict__ h1b, const float* __restrict__ ef,
    const int* __restrict__ src, const int* __restrict__ perm,
    const int* __restrict__ dsts,
    const float* __restrict__ We1, const float* __restrict__ be1,
    const short* __restrict__ We2T, const float* __restrict__ be2,
    const short* __restrict__ WaT, const float* __restrict__ ba,
    const short* __restrict__ WbT, const float* __restrict__ bbv,
    float* __restrict__ s2)
{
  __shared__ __align__(16) short U[64 * 264];    // 33792 B: Ws then M2s
  __shared__ int dse[64];
  __shared__ float cos_s[64];
  short* Ws  = U;                                // 64 x 136
  short* M2s = U;                                // 64 x 264
  float* cosP = (float*)(U + 64 * 136);          // [4][64][3] = 3072 B (dead after stage B)
  const int t = threadIdx.x;
  const int e0 = blockIdx.x * 64;

  const int lane = t & 63, wv = t >> 6;
  const int lr = lane & 15;
  const int lq = lane >> 4;
  const int n0 = wv * 64;

  int pe_b[4], s_b[4], d_b[4];
#pragma unroll
  for (int b = 0; b < 4; ++b) pe_b[b] = perm[e0 + b * 16 + lr];
#pragma unroll
  for (int b = 0; b < 4; ++b) { s_b[b] = src[pe_b[b]]; d_b[b] = dsts[e0 + b * 16 + lr]; }

  if (t < 64) dse[t] = dsts[e0 + t];

  // ---- build relu(w1) tile (bf16) into Ws ----
  {
    const int e = t >> 2;
    const int kb = (t & 3) * 32;
    const int pe = perm[e0 + e];
    const float f0 = ef[2 * pe], f1 = ef[2 * pe + 1];
#pragma unroll
    for (int j = 0; j < 4; ++j) {
      const int k = kb + j * 8;
      f4 wa0 = *(const f4*)&We1[k];
      f4 wa1 = *(const f4*)&We1[k + 4];
      f4 wb0 = *(const f4*)&We1[128 + k];
      f4 wb1 = *(const f4*)&We1[128 + k + 4];
      f4 b0 = *(const f4*)&be1[k];
      f4 b1 = *(const f4*)&be1[k + 4];
      bf8 pk;
#pragma unroll
      for (int x = 0; x < 4; ++x) {
        pk[x]     = f2b(fmaxf(fmaf(f0, wa0[x], fmaf(f1, wb0[x], b0[x])), 0.f));
        pk[x + 4] = f2b(fmaxf(fmaf(f0, wa1[x], fmaf(f1, wb1[x], b1[x])), 0.f));
      }
      *(bf8*)&Ws[e * 136 + k] = pk;
    }
  }

  // ---- cos2 partials: streaming loads, accumulate, discard ----
  {
#pragma unroll
    for (int b = 0; b < 4; ++b) {
      float ss = 0.f, dd = 0.f, sd = 0.f;
      const short* srow = &h1b[(size_t)s_b[b] * 256];
      const short* drow = &h1b[(size_t)d_b[b] * 256];
#pragma unroll
      for (int a = 0; a < 4; ++a) {
        const int n = n0 + a * 16 + lq * 4;
        f4 hs = b2f4(*(const bf4v*)&srow[n]);
        f4 hd = b2f4(*(const bf4v*)&drow[n]);
#pragma unroll
        for (int r = 0; r < 4; ++r) {
          ss = fmaf(hs[r], hs[r], ss);
          dd = fmaf(hd[r], hd[r], dd);
          sd = fmaf(hs[r], hd[r], sd);
        }
      }
      ss += __shfl_xor(ss, 16); ss += __shfl_xor(ss, 32);
      dd += __shfl_xor(dd, 16); dd += __shfl_xor(dd, 32);
      sd += __shfl_xor(sd, 16); sd += __shfl_xor(sd, 32);
      if (lq == 0) {
        float* p = &cosP[(wv * 64 + b * 16 + lr) * 3];
        p[0] = ss; p[1] = dd; p[2] = sd;
      }
    }
  }
  __syncthreads();   // Ws + cosP ready

  // first 64 threads finish cos2 while everyone starts stage B
  if (t < 64) {
    float ss = 0.f, dd = 0.f, sd = 0.f;
#pragma unroll
    for (int w = 0; w < 4; ++w) {
      const float* p = &cosP[(w * 64 + t) * 3];
      ss += p[0]; dd += p[1]; sd += p[2];
    }
    cos_s[t] = sd / (fmaxf(sqrtf(ss), 1e-12f) * fmaxf(sqrtf(dd), 1e-12f));
  }

  f4 acc[4][4];
#pragma unroll
  for (int a = 0; a < 4; ++a)
#pragma unroll
    for (int b = 0; b < 4; ++b) acc[a][b] = (f4)0.f;

  // ---- stage B: K = 128 (reads Ws) ----
#pragma unroll
  for (int kc = 0; kc < 128; kc += 32) {
    bf8 aF[4], bF[4];
#pragma unroll
    for (int a = 0; a < 4; ++a)
      aF[a] = *(const bf8*)&We2T[(size_t)(n0 + a * 16 + lr) * 128 + kc + lq * 8];
#pragma unroll
    for (int b = 0; b < 4; ++b)
      bF[b] = *(const bf8*)&Ws[(b * 16 + lr) * 136 + kc + lq * 8];
#pragma unroll
    for (int a = 0; a < 4; ++a)
#pragma unroll
      for (int b = 0; b < 4; ++b)
        acc[a][b] = __builtin_amdgcn_mfma_f32_16x16x32_bf16(aF[a], bF[b], acc[a][b], 0, 0, 0);
  }
  __syncthreads();   // Ws dead; cos_s ready; M2s region may now be written

  // m2[e][n] = (w2 + be2[n]) * cos2[e] * h1[src[e]][n] -> M2s (L2-hot reload)
#pragma unroll
  for (int b = 0; b < 4; ++b) {
    const float c = cos_s[b * 16 + lr];
    const short* srow = &h1b[(size_t)s_b[b] * 256];
#pragma unroll
    for (int a = 0; a < 4; ++a) {
      const int n = n0 + a * 16 + lq * 4;
      f4 bb = *(const f4*)&be2[n];
      f4 hv = b2f4(*(const bf4v*)&srow[n]);
      bf4v pk;
#pragma unroll
      for (int r = 0; r < 4; ++r)
        pk[r] = f2b((acc[a][b][r] + bb[r]) * c * hv[r]);
      *(bf4v*)&M2s[(b * 16 + lr) * 264 + n] = pk;
    }
  }
  __syncthreads();

  // ---- stage C: K = 256, relu ----
#pragma unroll
  for (int a = 0; a < 4; ++a)
#pragma unroll
    for (int b = 0; b < 4; ++b) acc[a][b] = (f4)0.f;
  for (int kc = 0; kc < 256; kc += 32) {
    bf8 aF[4], bF[4];
#pragma unroll
    for (int a = 0; a < 4; ++a)
      aF[a] = *(const bf8*)&WaT[(size_t)(n0 + a * 16 + lr) * 256 + kc + lq * 8];
#pragma unroll
    for (int b = 0; b < 4; ++b)
      bF[b] = *(const bf8*)&M2s[(b * 16 + lr) * 264 + kc + lq * 8];
#pragma unroll
    for (int a = 0; a < 4; ++a)
#pragma unroll
      for (int b = 0; b < 4; ++b)
        acc[a][b] = __builtin_amdgcn_mfma_f32_16x16x32_bf16(aF[a], bF[b], acc[a][b], 0, 0, 0);
  }
  __syncthreads();

#pragma unroll
  for (int a = 0; a < 4; ++a) {
    const int n = n0 + a * 16 + lq * 4;
    f4 bb = *(const f4*)&ba[n];
#pragma unroll
    for (int b = 0; b < 4; ++b) {
      bf4v pk;
#pragma unroll
      for (int r = 0; r < 4; ++r) pk[r] = f2b(fmaxf(acc[a][b][r] + bb[r], 0.f));
      *(bf4v*)&M2s[(b * 16 + lr) * 264 + n] = pk;
    }
  }
  __syncthreads();

  // ---- stage D: K = 256 ----
#pragma unroll
  for (int a = 0; a < 4; ++a)
#pragma unroll
    for (int b = 0; b < 4; ++b) acc[a][b] = (f4)0.f;
  for (int kc = 0; kc < 256; kc += 32) {
    bf8 aF[4], bF[4];
#pragma unroll
    for (int a = 0; a < 4; ++a)
      aF[a] = *(const bf8*)&WbT[(size_t)(n0 + a * 16 + lr) * 256 + kc + lq * 8];
#pragma unroll
    for (int b = 0; b < 4; ++b)
      bF[b] = *(const bf8*)&M2s[(b * 16 + lr) * 264 + kc + lq * 8];
#pragma unroll
    for (int a = 0; a < 4; ++a)
#pragma unroll
      for (int b = 0; b < 4; ++b)
        acc[a][b] = __builtin_amdgcn_mfma_f32_16x16x32_bf16(aF[a], bF[b], acc[a][b], 0, 0, 0);
  }
  __syncthreads();  // all waves done reading M2s before fp32 reuse

  // epilogue: two n-halves; write relu+bias fp32 into RF (=M2s), seg-reduce
  float* RF = (float*)M2s;   // 64 x 132 fp32 = 33792 B
#pragma unroll
  for (int h = 0; h < 2; ++h) {
    if ((wv >> 1) == h) {
#pragma unroll
      for (int a = 0; a < 4; ++a) {
        const int n = n0 + a * 16 + lq * 4;
        f4 bb = *(const f4*)&bbv[n];
#pragma unroll
        for (int b = 0; b < 4; ++b) {
          f4 v;
#pragma unroll
          for (int r = 0; r < 4; ++r) v[r] = fmaxf(acc[a][b][r] + bb[r], 0.f);
          *(f4*)&RF[(b * 16 + lr) * 132 + (n - h * 128)] = v;
        }
      }
    }
    __syncthreads();
    {
      const int f = t & 127;
      const int eb = (t >> 7) * 32;
      float run = 0.f;
      int pd = dse[eb];
#pragma unroll 4
      for (int e = eb; e < eb + 32; ++e) {
        const int d = dse[e];        // wave-uniform
        if (d != pd) {
          atomicAdd(&s2[(size_t)pd * 256 + h * 128 + f], run);
          run = 0.f;
          pd = d;
        }
        run += RF[e * 132 + f];
      }
      atomicAdd(&s2[(size_t)pd * 256 + h * 128 + f], run);
    }
    __syncthreads();
  }
}

// ---------------- node linear 1 (bf16 MFMA) -> h1b (bf16) ---------------------

__global__ __launch_bounds__(256, 3) void h1m_k(
    const float* __restrict__ nf, const float* __restrict__ s1,
    const int* __restrict__ cnt, const short* __restrict__ Wl1T,
    const float* __restrict__ bl1, short* __restrict__ h1b)
{
  __shared__ __align__(16) short As[64 * 264];
  const int t = threadIdx.x;
  const int v0 = blockIdx.x * 64;

  {
    const int row = t >> 2;
    const int kb = (t & 3) * 64;
    int gn = v0 + row;
    if (gn >= NN) gn = NN - 1;
    const float inv = 1.f / fmaxf((float)cnt[gn], 1.f);
#pragma unroll
    for (int j = 0; j < 64; j += 8) {
      const int k = kb + j;
      f4 x0, x1;
      if (k < 128) {
        x0 = *(const f4*)&nf[(size_t)gn * 128 + k];
        x1 = *(const f4*)&nf[(size_t)gn * 128 + k + 4];
      } else {
        x0 = *(const f4*)&s1[(size_t)gn * 128 + (k - 128)];
        x1 = *(const f4*)&s1[(size_t)gn * 128 + (k - 124)];
#pragma unroll
        for (int x = 0; x < 4; ++x) { x0[x] *= inv; x1[x] *= inv; }
      }
      bf8 pk;
#pragma unroll
      for (int x = 0; x < 4; ++x) { pk[x] = f2b(x0[x]); pk[x + 4] = f2b(x1[x]); }
      *(bf8*)&As[row * 264 + k] = pk;
    }
  }
  __syncthreads();

  const int lane = t & 63, wv = t >> 6;
  const int lr = lane & 15;
  const int lq = lane >> 4;
  const int n0 = wv * 64;

  f4 acc[4][4];
#pragma unroll
  for (int a = 0; a < 4; ++a)
#pragma unroll
    for (int b = 0; b < 4; ++b) acc[a][b] = (f4)0.f;

  for (int kc = 0; kc < 256; kc += 32) {
    bf8 aF[4], bF[4];
#pragma unroll
    for (int a = 0; a < 4; ++a)
      aF[a] = *(const bf8*)&Wl1T[(size_t)(n0 + a * 16 + lr) * 256 + kc + lq * 8];
#pragma unroll
    for (int b = 0; b < 4; ++b)
      bF[b] = *(const bf8*)&As[(b * 16 + lr) * 264 + kc + lq * 8];
#pragma unroll
    for (int a = 0; a < 4; ++a)
#pragma unroll
      for (int b = 0; b < 4; ++b)
        acc[a][b] = __builtin_amdgcn_mfma_f32_16x16x32_bf16(aF[a], bF[b], acc[a][b], 0, 0, 0);
  }

#pragma unroll
  for (int b = 0; b < 4; ++b) {
    const int gn = v0 + b * 16 + lr;
    if (gn >= NN) continue;
#pragma unroll
    for (int a = 0; a < 4; ++a) {
      const int n = n0 + a * 16 + lq * 4;
      f4 bb = *(const f4*)&bl1[n];
      bf4v pk;
      pk[0] = f2b(fmaxf(acc[a][b][0] + bb[0], 0.f));
      pk[1] = f2b(fmaxf(acc[a][b][1] + bb[1], 0.f));
      pk[2] = f2b(fmaxf(acc[a][b][2] + bb[2], 0.f));
      pk[3] = f2b(fmaxf(acc[a][b][3] + bb[3], 0.f));
      *(bf4v*)&h1b[(size_t)gn * 256 + n] = pk;
    }
  }
}

// ---------------- final linear: out = concat(h1b, s2/cnt) @ Wl2 + bl2 ---------

__global__ __launch_bounds__(256) void out_k(
    const short* __restrict__ h1b, const float* __restrict__ s2,
    const int* __restrict__ cnt, const float* __restrict__ Wl2,
    const float* __restrict__ bl2, float* __restrict__ out)
{
  __shared__ float A8[8][512];
  const int n0 = blockIdx.x * 8;
  const int tx = threadIdx.x;
  const int ty = threadIdx.y;
  const int t = ty * 32 + tx;
  const int row = t >> 5;
  const int k0 = (t & 31) * 16;
  const int n = n0 + row;
  const float inv = 1.0f / fmaxf((float)cnt[n], 1.0f);
#pragma unroll
  for (int i = 0; i < 16; i += 4) {
    int k = k0 + i;
    f4 v;
    if (k < 256) {
      v = b2f4(*(const bf4v*)&h1b[(size_t)n * 256 + k]);
    } else {
      v = *(const f4*)&s2[(size_t)n * 256 + (k - 256)];
      v[0] *= inv; v[1] *= inv; v[2] *= inv; v[3] *= inv;
    }
    *(f4*)&A8[row][k] = v;
  }
  __syncthreads();
  float acc = bl2[tx];
#pragma unroll 8
  for (int k = 0; k < 512; k++) acc = fmaf(A8[ty][k], Wl2[(size_t)k * 32 + tx], acc);
  out[(size_t)(n0 + ty) * 32 + tx] = acc;
}

// ---------------- launch ------------------------------------------------------

extern "C" void kernel_launch(void* const* d_in, const int* in_sizes, int n_in,
                              void* d_out, int out_size, void* d_ws, size_t ws_size,
                              hipStream_t stream) {
  const float* nf   = (const float*)d_in[0];
  const float* ef   = (const float*)d_in[1];
  const int*   src  = (const int*)d_in[2];
  const int*   dst  = (const int*)d_in[3];
  const float* We1  = (const float*)d_in[4];
  const float* be1  = (const float*)d_in[5];
  const float* Wr1a = (const float*)d_in[6];
  const float* br1a = (const float*)d_in[7];
  const float* Wr1b = (const float*)d_in[8];
  const float* br1b = (const float*)d_in[9];
  const float* Wl1  = (const float*)d_in[10];
  const float* bl1  = (const float*)d_in[11];
  const float* We2  = (const float*)d_in[12];
  const float* be2  = (const float*)d_in[13];
  const float* Wr2a = (const float*)d_in[14];
  const float* br2a = (const float*)d_in[15];
  const float* Wr2b = (const float*)d_in[16];
  const float* br2b = (const float*)d_in[17];
  const float* Wl2  = (const float*)d_in[18];
  const float* bl2  = (const float*)d_in[19];

  float* ws = (float*)d_ws;
  float* s1   = ws;                             // N*128 f
  float* s2   = s1 + (size_t)NN * 128;          // N*256 f
  int*   cnt  = (int*)(s2 + (size_t)NN * 256);  // N
  short* h1b  = (short*)(cnt + NN);             // N*256 bf16
  short* nfb  = h1b + (size_t)NN * 256;         // N*128 bf16
  short* WaT1 = nfb + (size_t)NN * 128;         // 128*128 bf16
  short* WbT1 = WaT1 + 128 * 128;               // 128*128
  short* We2T = WbT1 + 128 * 128;               // 256*128
  short* WaT2 = We2T + 256 * 128;               // 256*256
  short* WbT2 = WaT2 + 256 * 256;               // 256*256
  short* Wl1T = WbT2 + 256 * 256;               // 256*256
  int*   off2 = (int*)(Wl1T + 256 * 256);       // N
  int*   perm = off2 + NN;                      // E
  int*   dsts = perm + NE;                      // E

  size_t need = ((size_t)NN * 128 + (size_t)NN * 256 + NN) * 4 +
                ((size_t)NN * 256 + (size_t)NN * 128 +
                 (size_t)128 * 128 * 2 + (size_t)256 * 128 +
                 (size_t)256 * 256 * 3) * 2 +
                ((size_t)NN + 2 * (size_t)NE) * 4;
  if (ws_size < need) return;

  // weight transpose+convert and nf convert (tiny)
  wt_k<<<(128 * 128 + 255) / 256, 256, 0, stream>>>(Wr1a, WaT1, 128, 128);
  wt_k<<<(128 * 128 + 255) / 256, 256, 0, stream>>>(Wr1b, WbT1, 128, 128);
  wt_k<<<(128 * 256 + 255) / 256, 256, 0, stream>>>(We2, We2T, 128, 256);
  wt_k<<<(256 * 256 + 255) / 256, 256, 0, stream>>>(Wr2a, WaT2, 256, 256);
  wt_k<<<(256 * 256 + 255) / 256, 256, 0, stream>>>(Wr2b, WbT2, 256, 256);
  wt_k<<<(256 * 256 + 255) / 256, 256, 0, stream>>>(Wl1, Wl1T, 256, 256);
  cvt_k<<<(NN * 128 / 4 + 255) / 256, 256, 0, stream>>>(nf, nfb, NN * 128 / 4);

  // zero s1, s2, cnt (contiguous)
  hipMemsetAsync(s1, 0, ((size_t)NN * 128 + (size_t)NN * 256 + NN) * 4, stream);

  cnt_k<<<NE / 256, 256, 0, stream>>>(dst, cnt);

  // counting sort by dst
  scan_k<<<1, 1024, 0, stream>>>(cnt, off2);
  perm_k<<<NE / 256, 256, 0, stream>>>(dst, off2, perm, dsts);

  edge_mlp1<<<NE / 64, 256, 0, stream>>>(nfb, ef, src, perm, dsts, We1, be1,
                                         WaT1, br1a, WbT1, br1b, s1);

  h1m_k<<<(NN + 63) / 64, 256, 0, stream>>>(nf, s1, cnt, Wl1T, bl1, h1b);

  edge_mlp2<<<NE / 64, 256, 0, stream>>>(h1b, ef, src, perm, dsts, We1, be1,
                                         We2T, be2, WaT2, br2a, WbT2, br2b, s2);

  out_k<<<NN / 8, dim3(32, 8), 0, stream>>>(h1b, s2, cnt, Wl2, bl2, (float*)d_out);
}

// Round 9
// 1406.227 us; speedup vs baseline: 8.0665x; 1.1359x over previous
//
#include <hip/hip_runtime.h>
#include <math.h>

#define NN 50000
#define NE 800000

typedef short bf8 __attribute__((ext_vector_type(8)));
typedef short bf4v __attribute__((ext_vector_type(4)));
typedef short bf2v __attribute__((ext_vector_type(2)));
typedef float f4 __attribute__((ext_vector_type(4)));

// float -> bf16 bits, round-to-nearest-even (values are finite)
__device__ __forceinline__ short f2b(float f) {
  unsigned int u = __float_as_uint(f);
  unsigned int r = (u + 0x7FFFu + ((u >> 16) & 1u)) >> 16;
  return (short)(unsigned short)r;
}
__device__ __forceinline__ float b2f(short s) {
  return __uint_as_float(((unsigned int)(unsigned short)s) << 16);
}
__device__ __forceinline__ f4 b2f4(bf4v p) {
  f4 v;
  v[0] = b2f(p[0]); v[1] = b2f(p[1]); v[2] = b2f(p[2]); v[3] = b2f(p[3]);
  return v;
}

// ---------------- weight transpose + bf16 convert -----------------------------
__global__ __launch_bounds__(256) void wt_k(const float* __restrict__ in,
                                            short* __restrict__ out,
                                            int K, int N) {
  int i = blockIdx.x * 256 + threadIdx.x;
  if (i >= K * N) return;
  int n = i / K, k = i - n * K;
  out[i] = f2b(in[(size_t)k * N + n]);
}

// plain fp32 -> bf16 convert (4 elems/thread)
__global__ __launch_bounds__(256) void cvt_k(const float* __restrict__ in,
                                             short* __restrict__ out, int n4) {
  int i = blockIdx.x * 256 + threadIdx.x;
  if (i >= n4) return;
  f4 v = *(const f4*)&in[(size_t)i * 4];
  bf4v p;
  p[0] = f2b(v[0]); p[1] = f2b(v[1]); p[2] = f2b(v[2]); p[3] = f2b(v[3]);
  *(bf4v*)&out[(size_t)i * 4] = p;
}

// ---------------- degree count -------------------------------------------------
__global__ __launch_bounds__(256) void cnt_k(const int* __restrict__ dst,
                                             int* __restrict__ cnt) {
  int e = blockIdx.x * 256 + threadIdx.x;
  if (e >= NE) return;
  atomicAdd(&cnt[dst[e]], 1);
}

// ---------------- counting-sort by dst ----------------------------------------
__global__ __launch_bounds__(1024) void scan_k(const int* __restrict__ cnt,
                                               int* __restrict__ off2) {
  __shared__ int buf[1024];
  __shared__ int carry_s;
  const int t = threadIdx.x;
  if (t == 0) carry_s = 0;
  __syncthreads();
  const int nch = (NN + 1023) / 1024;
  for (int ch = 0; ch < nch; ++ch) {
    const int i = ch * 1024 + t;
    const int v = (i < NN) ? cnt[i] : 0;
    buf[t] = v;
    __syncthreads();
#pragma unroll
    for (int o = 1; o < 1024; o <<= 1) {
      int x = (t >= o) ? buf[t - o] : 0;
      __syncthreads();
      buf[t] += x;
      __syncthreads();
    }
    const int incl = buf[t];
    const int carry = carry_s;
    if (i < NN) off2[i] = carry + incl - v;
    __syncthreads();
    if (t == 1023) carry_s = carry + incl;
    __syncthreads();
  }
}

__global__ __launch_bounds__(256) void perm_k(const int* __restrict__ dst,
                                              int* __restrict__ off2,
                                              int* __restrict__ perm,
                                              int* __restrict__ dsts) {
  int e = blockIdx.x * 256 + threadIdx.x;
  if (e >= NE) return;
  int d = dst[e];
  int p = atomicAdd(&off2[d], 1);
  perm[p] = e;
  dsts[p] = d;
}

// ---------------- fused edge-MLP layer 1 (bf16 MFMA, coalesced row pass) ------

__global__ __launch_bounds__(256, 5) void edge_mlp1(
    const short* __restrict__ nfb, const float* __restrict__ ef,
    const int* __restrict__ src, const int* __restrict__ perm,
    const int* __restrict__ dsts,
    const float* __restrict__ We1, const float* __restrict__ be1,
    const short* __restrict__ WaT, const float* __restrict__ ba,
    const short* __restrict__ WbT, const float* __restrict__ bbv,
    float* __restrict__ s1)
{
  __shared__ __align__(16) short Ms[64 * 136];   // 17408 B (M / T / R reuse)
  __shared__ int dse[64];
  __shared__ int pes[64];
  __shared__ int sse[64];
  const int t = threadIdx.x;
  const int e0 = blockIdx.x * 64;
  const int lane = t & 63, wv = t >> 6;

  if (t < 64) {
    const int pe = perm[e0 + t];
    pes[t] = pe;
    dse[t] = dsts[e0 + t];
    sse[t] = src[pe];
  }
  __syncthreads();

  // ---- row pass: 16 edges/wave; coalesced row loads + wave-reduce cos1 ----
  {
    const int k2 = lane * 2;
    const float wA0 = We1[k2],       wA1 = We1[k2 + 1];
    const float wB0 = We1[128 + k2], wB1 = We1[128 + k2 + 1];
    const float bE0 = be1[k2],       bE1 = be1[k2 + 1];
#pragma unroll 2
    for (int i = 0; i < 16; ++i) {
      const int e = wv * 16 + i;
      const int s = sse[e];
      const int d = dse[e];
      bf2v hb = *(const bf2v*)&nfb[(size_t)s * 128 + k2];   // 64x4B coalesced
      bf2v db = *(const bf2v*)&nfb[(size_t)d * 128 + k2];
      const float h0 = b2f(hb[0]), h1v = b2f(hb[1]);
      const float g0 = b2f(db[0]), g1 = b2f(db[1]);
      float ss = h0 * h0 + h1v * h1v;
      float dd = g0 * g0 + g1 * g1;
      float sd = h0 * g0 + h1v * g1;
#pragma unroll
      for (int o = 32; o >= 1; o >>= 1) {
        ss += __shfl_xor(ss, o);
        dd += __shfl_xor(dd, o);
        sd += __shfl_xor(sd, o);
      }
      const float c = sd / (fmaxf(sqrtf(ss), 1e-12f) * fmaxf(sqrtf(dd), 1e-12f));
      const float2 f01 = *(const float2*)&ef[2 * pes[e]];   // uniform broadcast
      const float w0 = fmaf(f01.x, wA0, fmaf(f01.y, wB0, bE0));
      const float w1 = fmaf(f01.x, wA1, fmaf(f01.y, wB1, bE1));
      bf2v pk;
      pk[0] = f2b(c * w0 * h0);
      pk[1] = f2b(c * w1 * h1v);
      *(bf2v*)&Ms[e * 136 + k2] = pk;
    }
  }
  __syncthreads();

  const int lr = lane & 15;
  const int lq = lane >> 4;
  const int n0 = wv * 32;

  f4 acc[2][4];
#pragma unroll
  for (int a = 0; a < 2; ++a)
#pragma unroll
    for (int b = 0; b < 4; ++b) acc[a][b] = (f4)0.f;

  // ---- stage 1: K = 128 ----
#pragma unroll
  for (int kc = 0; kc < 128; kc += 32) {
    bf8 aF[2], bF[4];
#pragma unroll
    for (int a = 0; a < 2; ++a)
      aF[a] = *(const bf8*)&WaT[(size_t)(n0 + a * 16 + lr) * 128 + kc + lq * 8];
#pragma unroll
    for (int b = 0; b < 4; ++b)
      bF[b] = *(const bf8*)&Ms[(b * 16 + lr) * 136 + kc + lq * 8];
#pragma unroll
    for (int a = 0; a < 2; ++a)
#pragma unroll
      for (int b = 0; b < 4; ++b)
        acc[a][b] = __builtin_amdgcn_mfma_f32_16x16x32_bf16(aF[a], bF[b], acc[a][b], 0, 0, 0);
  }
  __syncthreads();

  // T[e][n] = relu(acc + ba[n]) -> Ms
#pragma unroll
  for (int a = 0; a < 2; ++a) {
    const int n = n0 + a * 16 + lq * 4;
    f4 bb = *(const f4*)&ba[n];
#pragma unroll
    for (int b = 0; b < 4; ++b) {
      bf4v pk;
#pragma unroll
      for (int r = 0; r < 4; ++r) pk[r] = f2b(fmaxf(acc[a][b][r] + bb[r], 0.f));
      *(bf4v*)&Ms[(b * 16 + lr) * 136 + n] = pk;
    }
  }
  __syncthreads();

  // ---- stage 2: K = 128 ----
#pragma unroll
  for (int a = 0; a < 2; ++a)
#pragma unroll
    for (int b = 0; b < 4; ++b) acc[a][b] = (f4)0.f;
#pragma unroll
  for (int kc = 0; kc < 128; kc += 32) {
    bf8 aF[2], bF[4];
#pragma unroll
    for (int a = 0; a < 2; ++a)
      aF[a] = *(const bf8*)&WbT[(size_t)(n0 + a * 16 + lr) * 128 + kc + lq * 8];
#pragma unroll
    for (int b = 0; b < 4; ++b)
      bF[b] = *(const bf8*)&Ms[(b * 16 + lr) * 136 + kc + lq * 8];
#pragma unroll
    for (int a = 0; a < 2; ++a)
#pragma unroll
      for (int b = 0; b < 4; ++b)
        acc[a][b] = __builtin_amdgcn_mfma_f32_16x16x32_bf16(aF[a], bF[b], acc[a][b], 0, 0, 0);
  }
  __syncthreads();   // all waves done reading Ms before R overwrite

  // R[e][n] = relu(acc + bb[n]) -> Ms (bf16; sums still accumulate in fp32)
#pragma unroll
  for (int a = 0; a < 2; ++a) {
    const int n = n0 + a * 16 + lq * 4;
    f4 bb = *(const f4*)&bbv[n];
#pragma unroll
    for (int b = 0; b < 4; ++b) {
      bf4v pk;
#pragma unroll
      for (int r = 0; r < 4; ++r) pk[r] = f2b(fmaxf(acc[a][b][r] + bb[r], 0.f));
      *(bf4v*)&Ms[(b * 16 + lr) * 136 + n] = pk;
    }
  }
  __syncthreads();

  // segmented reduce over sorted dst
  {
    const int f = t & 127;
    const int eb = (t >> 7) * 32;
    float run = 0.f;
    int pd = dse[eb];
#pragma unroll 4
    for (int e = eb; e < eb + 32; ++e) {
      const int d = dse[e];          // wave-uniform
      if (d != pd) {
        atomicAdd(&s1[(size_t)pd * 128 + f], run);
        run = 0.f;
        pd = d;
      }
      run += b2f(Ms[e * 136 + f]);
    }
    atomicAdd(&s1[(size_t)pd * 128 + f], run);
  }
}

// ---------------- fused edge-MLP layer 2 (bf16 MFMA, coalesced row pass) ------
// LDS union: Ws (17408 B) lives inside M2s (33792 B). ~34.5 KB -> 4 blocks/CU.

__global__ __launch_bounds__(256, 4) void edge_mlp2(
    const short* __restrict__ h1b, const float* __restrict__ ef,
    const int* __restrict__ src, const int* __restrict__ perm,
    const int* __restrict__ dsts,
    const float* __restrict__ We1, const float* __restrict__ be1,
    const short* __restrict__ We2T, const float* __restrict__ be2,
    const short* __restrict__ WaT, const float* __restrict__ ba,
    const short* __restrict__ WbT, const float* __restrict__ bbv,
    float* __restrict__ s2)
{
  __shared__ __align__(16) short U[64 * 264];    // 33792 B: Ws then M2s
  __shared__ int dse[64];
  __shared__ int pes[64];
  __shared__ int sse[64];
  short* Ws  = U;                                // 64 x 136
  short* M2s = U;                                // 64 x 264
  const int t = threadIdx.x;
  const int e0 = blockIdx.x * 64;
  const int lane = t & 63, wv = t >> 6;
  const int lr = lane & 15;
  const int lq = lane >> 4;
  const int n0 = wv * 64;

  if (t < 64) {
    const int pe = perm[e0 + t];
    pes[t] = pe;
    dse[t] = dsts[e0 + t];
    sse[t] = src[pe];
  }
  __syncthreads();

  // ---- build relu(w1) tile (bf16) into Ws ----
  {
    const int e = t >> 2;
    const int kb = (t & 3) * 32;
    const int pe = pes[e];
    const float f0 = ef[2 * pe], f1 = ef[2 * pe + 1];
#pragma unroll
    for (int j = 0; j < 4; ++j) {
      const int k = kb + j * 8;
      f4 wa0 = *(const f4*)&We1[k];
      f4 wa1 = *(const f4*)&We1[k + 4];
      f4 wb0 = *(const f4*)&We1[128 + k];
      f4 wb1 = *(const f4*)&We1[128 + k + 4];
      f4 b0 = *(const f4*)&be1[k];
      f4 b1 = *(const f4*)&be1[k + 4];
      bf8 pk;
#pragma unroll
      for (int x = 0; x < 4; ++x) {
        pk[x]     = f2b(fmaxf(fmaf(f0, wa0[x], fmaf(f1, wb0[x], b0[x])), 0.f));
        pk[x + 4] = f2b(fmaxf(fmaf(f0, wa1[x], fmaf(f1, wb1[x], b1[x])), 0.f));
      }
      *(bf8*)&Ws[e * 136 + k] = pk;
    }
  }
  __syncthreads();

  f4 acc[4][4];
#pragma unroll
  for (int a = 0; a < 4; ++a)
#pragma unroll
    for (int b = 0; b < 4; ++b) acc[a][b] = (f4)0.f;

  // ---- stage B: K = 128 (reads Ws) ----
#pragma unroll
  for (int kc = 0; kc < 128; kc += 32) {
    bf8 aF[4], bF[4];
#pragma unroll
    for (int a = 0; a < 4; ++a)
      aF[a] = *(const bf8*)&We2T[(size_t)(n0 + a * 16 + lr) * 128 + kc + lq * 8];
#pragma unroll
    for (int b = 0; b < 4; ++b)
      bF[b] = *(const bf8*)&Ws[(b * 16 + lr) * 136 + kc + lq * 8];
#pragma unroll
    for (int a = 0; a < 4; ++a)
#pragma unroll
      for (int b = 0; b < 4; ++b)
        acc[a][b] = __builtin_amdgcn_mfma_f32_16x16x32_bf16(aF[a], bF[b], acc[a][b], 0, 0, 0);
  }
  __syncthreads();   // Ws dead; M2s region may now be written

  // w2[e][n] = acc + be2[n] -> M2s (bf16, no cos/h yet)
#pragma unroll
  for (int b = 0; b < 4; ++b) {
#pragma unroll
    for (int a = 0; a < 4; ++a) {
      const int n = n0 + a * 16 + lq * 4;
      f4 bb = *(const f4*)&be2[n];
      bf4v pk;
#pragma unroll
      for (int r = 0; r < 4; ++r) pk[r] = f2b(acc[a][b][r] + bb[r]);
      *(bf4v*)&M2s[(b * 16 + lr) * 264 + n] = pk;
    }
  }
  __syncthreads();

  // ---- row pass: 16 edges/wave; coalesced src/dst rows, fused cos2 ----
  {
    const int k4 = lane * 4;
#pragma unroll 2
    for (int i = 0; i < 16; ++i) {
      const int e = wv * 16 + i;
      const int s = sse[e];
      const int d = dse[e];
      f4 hs = b2f4(*(const bf4v*)&h1b[(size_t)s * 256 + k4]);  // 64x8B coalesced
      f4 hd = b2f4(*(const bf4v*)&h1b[(size_t)d * 256 + k4]);
      float ss = 0.f, dd = 0.f, sd = 0.f;
#pragma unroll
      for (int r = 0; r < 4; ++r) {
        ss = fmaf(hs[r], hs[r], ss);
        dd = fmaf(hd[r], hd[r], dd);
        sd = fmaf(hs[r], hd[r], sd);
      }
#pragma unroll
      for (int o = 32; o >= 1; o >>= 1) {
        ss += __shfl_xor(ss, o);
        dd += __shfl_xor(dd, o);
        sd += __shfl_xor(sd, o);
      }
      const float c = sd / (fmaxf(sqrtf(ss), 1e-12f) * fmaxf(sqrtf(dd), 1e-12f));
      f4 w = b2f4(*(const bf4v*)&M2s[e * 264 + k4]);
      bf4v pk;
#pragma unroll
      for (int r = 0; r < 4; ++r) pk[r] = f2b(w[r] * c * hs[r]);
      *(bf4v*)&M2s[e * 264 + k4] = pk;
    }
  }
  __syncthreads();

  // ---- stage C: K = 256, relu ----
#pragma unroll
  for (int a = 0; a < 4; ++a)
#pragma unroll
    for (int b = 0; b < 4; ++b) acc[a][b] = (f4)0.f;
  for (int kc = 0; kc < 256; kc += 32) {
    bf8 aF[4], bF[4];
#pragma unroll
    for (int a = 0; a < 4; ++a)
      aF[a] = *(const bf8*)&WaT[(size_t)(n0 + a * 16 + lr) * 256 + kc + lq * 8];
#pragma unroll
    for (int b = 0; b < 4; ++b)
      bF[b] = *(const bf8*)&M2s[(b * 16 + lr) * 264 + kc + lq * 8];
#pragma unroll
    for (int a = 0; a < 4; ++a)
#pragma unroll
      for (int b = 0; b < 4; ++b)
        acc[a][b] = __builtin_amdgcn_mfma_f32_16x16x32_bf16(aF[a], bF[b], acc[a][b], 0, 0, 0);
  }
  __syncthreads();

#pragma unroll
  for (int a = 0; a < 4; ++a) {
    const int n = n0 + a * 16 + lq * 4;
    f4 bb = *(const f4*)&ba[n];
#pragma unroll
    for (int b = 0; b < 4; ++b) {
      bf4v pk;
#pragma unroll
      for (int r = 0; r < 4; ++r) pk[r] = f2b(fmaxf(acc[a][b][r] + bb[r], 0.f));
      *(bf4v*)&M2s[(b * 16 + lr) * 264 + n] = pk;
    }
  }
  __syncthreads();

  // ---- stage D: K = 256 ----
#pragma unroll
  for (int a = 0; a < 4; ++a)
#pragma unroll
    for (int b = 0; b < 4; ++b) acc[a][b] = (f4)0.f;
  for (int kc = 0; kc < 256; kc += 32) {
    bf8 aF[4], bF[4];
#pragma unroll
    for (int a = 0; a < 4; ++a)
      aF[a] = *(const bf8*)&WbT[(size_t)(n0 + a * 16 + lr) * 256 + kc + lq * 8];
#pragma unroll
    for (int b = 0; b < 4; ++b)
      bF[b] = *(const bf8*)&M2s[(b * 16 + lr) * 264 + kc + lq * 8];
#pragma unroll
    for (int a = 0; a < 4; ++a)
#pragma unroll
      for (int b = 0; b < 4; ++b)
        acc[a][b] = __builtin_amdgcn_mfma_f32_16x16x32_bf16(aF[a], bF[b], acc[a][b], 0, 0, 0);
  }
  __syncthreads();  // all waves done reading M2s before fp32 reuse

  // epilogue: two n-halves; write relu+bias fp32 into RF (=M2s), seg-reduce
  float* RF = (float*)M2s;   // 64 x 132 fp32 = 33792 B
#pragma unroll
  for (int h = 0; h < 2; ++h) {
    if ((wv >> 1) == h) {
#pragma unroll
      for (int a = 0; a < 4; ++a) {
        const int n = n0 + a * 16 + lq * 4;
        f4 bb = *(const f4*)&bbv[n];
#pragma unroll
        for (int b = 0; b < 4; ++b) {
          f4 v;
#pragma unroll
          for (int r = 0; r < 4; ++r) v[r] = fmaxf(acc[a][b][r] + bb[r], 0.f);
          *(f4*)&RF[(b * 16 + lr) * 132 + (n - h * 128)] = v;
        }
      }
    }
    __syncthreads();
    {
      const int f = t & 127;
      const int eb = (t >> 7) * 32;
      float run = 0.f;
      int pd = dse[eb];
#pragma unroll 4
      for (int e = eb; e < eb + 32; ++e) {
        const int d = dse[e];        // wave-uniform
        if (d != pd) {
          atomicAdd(&s2[(size_t)pd * 256 + h * 128 + f], run);
          run = 0.f;
          pd = d;
        }
        run += RF[e * 132 + f];
      }
      atomicAdd(&s2[(size_t)pd * 256 + h * 128 + f], run);
    }
    __syncthreads();
  }
}

// ---------------- node linear 1 (bf16 MFMA) -> h1b (bf16) ---------------------

__global__ __launch_bounds__(256, 3) void h1m_k(
    const float* __restrict__ nf, const float* __restrict__ s1,
    const int* __restrict__ cnt, const short* __restrict__ Wl1T,
    const float* __restrict__ bl1, short* __restrict__ h1b)
{
  __shared__ __align__(16) short As[64 * 264];
  const int t = threadIdx.x;
  const int v0 = blockIdx.x * 64;

  {
    const int row = t >> 2;
    const int kb = (t & 3) * 64;
    int gn = v0 + row;
    if (gn >= NN) gn = NN - 1;
    const float inv = 1.f / fmaxf((float)cnt[gn], 1.f);
#pragma unroll
    for (int j = 0; j < 64; j += 8) {
      const int k = kb + j;
      f4 x0, x1;
      if (k < 128) {
        x0 = *(const f4*)&nf[(size_t)gn * 128 + k];
        x1 = *(const f4*)&nf[(size_t)gn * 128 + k + 4];
      } else {
        x0 = *(const f4*)&s1[(size_t)gn * 128 + (k - 128)];
        x1 = *(const f4*)&s1[(size_t)gn * 128 + (k - 124)];
#pragma unroll
        for (int x = 0; x < 4; ++x) { x0[x] *= inv; x1[x] *= inv; }
      }
      bf8 pk;
#pragma unroll
      for (int x = 0; x < 4; ++x) { pk[x] = f2b(x0[x]); pk[x + 4] = f2b(x1[x]); }
      *(bf8*)&As[row * 264 + k] = pk;
    }
  }
  __syncthreads();

  const int lane = t & 63, wv = t >> 6;
  const int lr = lane & 15;
  const int lq = lane >> 4;
  const int n0 = wv * 64;

  f4 acc[4][4];
#pragma unroll
  for (int a = 0; a < 4; ++a)
#pragma unroll
    for (int b = 0; b < 4; ++b) acc[a][b] = (f4)0.f;

  for (int kc = 0; kc < 256; kc += 32) {
    bf8 aF[4], bF[4];
#pragma unroll
    for (int a = 0; a < 4; ++a)
      aF[a] = *(const bf8*)&Wl1T[(size_t)(n0 + a * 16 + lr) * 256 + kc + lq * 8];
#pragma unroll
    for (int b = 0; b < 4; ++b)
      bF[b] = *(const bf8*)&As[(b * 16 + lr) * 264 + kc + lq * 8];
#pragma unroll
    for (int a = 0; a < 4; ++a)
#pragma unroll
      for (int b = 0; b < 4; ++b)
        acc[a][b] = __builtin_amdgcn_mfma_f32_16x16x32_bf16(aF[a], bF[b], acc[a][b], 0, 0, 0);
  }

#pragma unroll
  for (int b = 0; b < 4; ++b) {
    const int gn = v0 + b * 16 + lr;
    if (gn >= NN) continue;
#pragma unroll
    for (int a = 0; a < 4; ++a) {
      const int n = n0 + a * 16 + lq * 4;
      f4 bb = *(const f4*)&bl1[n];
      bf4v pk;
      pk[0] = f2b(fmaxf(acc[a][b][0] + bb[0], 0.f));
      pk[1] = f2b(fmaxf(acc[a][b][1] + bb[1], 0.f));
      pk[2] = f2b(fmaxf(acc[a][b][2] + bb[2], 0.f));
      pk[3] = f2b(fmaxf(acc[a][b][3] + bb[3], 0.f));
      *(bf4v*)&h1b[(size_t)gn * 256 + n] = pk;
    }
  }
}

// ---------------- final linear: out = concat(h1b, s2/cnt) @ Wl2 + bl2 ---------

__global__ __launch_bounds__(256) void out_k(
    const short* __restrict__ h1b, const float* __restrict__ s2,
    const int* __restrict__ cnt, const float* __restrict__ Wl2,
    const float* __restrict__ bl2, float* __restrict__ out)
{
  __shared__ float A8[8][512];
  const int n0 = blockIdx.x * 8;
  const int tx = threadIdx.x;
  const int ty = threadIdx.y;
  const int t = ty * 32 + tx;
  const int row = t >> 5;
  const int k0 = (t & 31) * 16;
  const int n = n0 + row;
  const float inv = 1.0f / fmaxf((float)cnt[n], 1.0f);
#pragma unroll
  for (int i = 0; i < 16; i += 4) {
    int k = k0 + i;
    f4 v;
    if (k < 256) {
      v = b2f4(*(const bf4v*)&h1b[(size_t)n * 256 + k]);
    } else {
      v = *(const f4*)&s2[(size_t)n * 256 + (k - 256)];
      v[0] *= inv; v[1] *= inv; v[2] *= inv; v[3] *= inv;
    }
    *(f4*)&A8[row][k] = v;
  }
  __syncthreads();
  float acc = bl2[tx];
#pragma unroll 8
  for (int k = 0; k < 512; k++) acc = fmaf(A8[ty][k], Wl2[(size_t)k * 32 + tx], acc);
  out[(size_t)(n0 + ty) * 32 + tx] = acc;
}

// ---------------- launch ------------------------------------------------------

extern "C" void kernel_launch(void* const* d_in, const int* in_sizes, int n_in,
                              void* d_out, int out_size, void* d_ws, size_t ws_size,
                              hipStream_t stream) {
  const float* nf   = (const float*)d_in[0];
  const float* ef   = (const float*)d_in[1];
  const int*   src  = (const int*)d_in[2];
  const int*   dst  = (const int*)d_in[3];
  const float* We1  = (const float*)d_in[4];
  const float* be1  = (const float*)d_in[5];
  const float* Wr1a = (const float*)d_in[6];
  const float* br1a = (const float*)d_in[7];
  const float* Wr1b = (const float*)d_in[8];
  const float* br1b = (const float*)d_in[9];
  const float* Wl1  = (const float*)d_in[10];
  const float* bl1  = (const float*)d_in[11];
  const float* We2  = (const float*)d_in[12];
  const float* be2  = (const float*)d_in[13];
  const float* Wr2a = (const float*)d_in[14];
  const float* br2a = (const float*)d_in[15];
  const float* Wr2b = (const float*)d_in[16];
  const float* br2b = (const float*)d_in[17];
  const float* Wl2  = (const float*)d_in[18];
  const float* bl2  = (const float*)d_in[19];

  float* ws = (float*)d_ws;
  float* s1   = ws;                             // N*128 f
  float* s2   = s1 + (size_t)NN * 128;          // N*256 f
  int*   cnt  = (int*)(s2 + (size_t)NN * 256);  // N
  short* h1b  = (short*)(cnt + NN);             // N*256 bf16
  short* nfb  = h1b + (size_t)NN * 256;         // N*128 bf16
  short* WaT1 = nfb + (size_t)NN * 128;         // 128*128 bf16
  short* WbT1 = WaT1 + 128 * 128;               // 128*128
  short* We2T = WbT1 + 128 * 128;               // 256*128
  short* WaT2 = We2T + 256 * 128;               // 256*256
  short* WbT2 = WaT2 + 256 * 256;               // 256*256
  short* Wl1T = WbT2 + 256 * 256;               // 256*256
  int*   off2 = (int*)(Wl1T + 256 * 256);       // N
  int*   perm = off2 + NN;                      // E
  int*   dsts = perm + NE;                      // E

  size_t need = ((size_t)NN * 128 + (size_t)NN * 256 + NN) * 4 +
                ((size_t)NN * 256 + (size_t)NN * 128 +
                 (size_t)128 * 128 * 2 + (size_t)256 * 128 +
                 (size_t)256 * 256 * 3) * 2 +
                ((size_t)NN + 2 * (size_t)NE) * 4;
  if (ws_size < need) return;

  // weight transpose+convert and nf convert (tiny)
  wt_k<<<(128 * 128 + 255) / 256, 256, 0, stream>>>(Wr1a, WaT1, 128, 128);
  wt_k<<<(128 * 128 + 255) / 256, 256, 0, stream>>>(Wr1b, WbT1, 128, 128);
  wt_k<<<(128 * 256 + 255) / 256, 256, 0, stream>>>(We2, We2T, 128, 256);
  wt_k<<<(256 * 256 + 255) / 256, 256, 0, stream>>>(Wr2a, WaT2, 256, 256);
  wt_k<<<(256 * 256 + 255) / 256, 256, 0, stream>>>(Wr2b, WbT2, 256, 256);
  wt_k<<<(256 * 256 + 255) / 256, 256, 0, stream>>>(Wl1, Wl1T, 256, 256);
  cvt_k<<<(NN * 128 / 4 + 255) / 256, 256, 0, stream>>>(nf, nfb, NN * 128 / 4);

  // zero s1, s2, cnt (contiguous)
  hipMemsetAsync(s1, 0, ((size_t)NN * 128 + (size_t)NN * 256 + NN) * 4, stream);

  cnt_k<<<NE / 256, 256, 0, stream>>>(dst, cnt);

  // counting sort by dst
  scan_k<<<1, 1024, 0, stream>>>(cnt, off2);
  perm_k<<<NE / 256, 256, 0, stream>>>(dst, off2, perm, dsts);

  edge_mlp1<<<NE / 64, 256, 0, stream>>>(nfb, ef, src, perm, dsts, We1, be1,
                                         WaT1, br1a, WbT1, br1b, s1);

  h1m_k<<<(NN + 63) / 64, 256, 0, stream>>>(nf, s1, cnt, Wl1T, bl1, h1b);

  edge_mlp2<<<NE / 64, 256, 0, stream>>>(h1b, ef, src, perm, dsts, We1, be1,
                                         We2T, be2, WaT2, br2a, WbT2, br2b, s2);

  out_k<<<NN / 8, dim3(32, 8), 0, stream>>>(h1b, s2, cnt, Wl2, bl2, (float*)d_out);
}

// Round 10
// 1323.081 us; speedup vs baseline: 8.5735x; 1.0628x over previous
//
#include <hip/hip_runtime.h>
#include <math.h>

#define NN 50000
#define NE 800000

typedef short bf8 __attribute__((ext_vector_type(8)));
typedef short bf4v __attribute__((ext_vector_type(4)));
typedef short bf2v __attribute__((ext_vector_type(2)));
typedef float f4 __attribute__((ext_vector_type(4)));

// float -> bf16 bits, round-to-nearest-even (values are finite)
__device__ __forceinline__ short f2b(float f) {
  unsigned int u = __float_as_uint(f);
  unsigned int r = (u + 0x7FFFu + ((u >> 16) & 1u)) >> 16;
  return (short)(unsigned short)r;
}
__device__ __forceinline__ float b2f(short s) {
  return __uint_as_float(((unsigned int)(unsigned short)s) << 16);
}
__device__ __forceinline__ f4 b2f4(bf4v p) {
  f4 v;
  v[0] = b2f(p[0]); v[1] = b2f(p[1]); v[2] = b2f(p[2]); v[3] = b2f(p[3]);
  return v;
}

// ---------------- weight transpose + bf16 convert -----------------------------
__global__ __launch_bounds__(256) void wt_k(const float* __restrict__ in,
                                            short* __restrict__ out,
                                            int K, int N) {
  int i = blockIdx.x * 256 + threadIdx.x;
  if (i >= K * N) return;
  int n = i / K, k = i - n * K;
  out[i] = f2b(in[(size_t)k * N + n]);
}

// plain fp32 -> bf16 convert (4 elems/thread)
__global__ __launch_bounds__(256) void cvt_k(const float* __restrict__ in,
                                             short* __restrict__ out, int n4) {
  int i = blockIdx.x * 256 + threadIdx.x;
  if (i >= n4) return;
  f4 v = *(const f4*)&in[(size_t)i * 4];
  bf4v p;
  p[0] = f2b(v[0]); p[1] = f2b(v[1]); p[2] = f2b(v[2]); p[3] = f2b(v[3]);
  *(bf4v*)&out[(size_t)i * 4] = p;
}

// ---------------- per-node inverse norms --------------------------------------
__global__ __launch_bounds__(256) void norm1_k(const short* __restrict__ nfb,
                                               float* __restrict__ invn) {
  const int node = blockIdx.x * 4 + (threadIdx.x >> 6);
  if (node >= NN) return;
  const int lane = threadIdx.x & 63;
  bf2v hb = *(const bf2v*)&nfb[(size_t)node * 128 + lane * 2];
  float h0 = b2f(hb[0]), h1v = b2f(hb[1]);
  float ss = fmaf(h0, h0, h1v * h1v);
#pragma unroll
  for (int o = 32; o >= 1; o >>= 1) ss += __shfl_xor(ss, o);
  if (lane == 0) invn[node] = 1.f / fmaxf(sqrtf(ss), 1e-12f);
}

__global__ __launch_bounds__(256) void norm2_k(const short* __restrict__ h1b,
                                               float* __restrict__ invn) {
  const int node = blockIdx.x * 4 + (threadIdx.x >> 6);
  if (node >= NN) return;
  const int lane = threadIdx.x & 63;
  f4 h = b2f4(*(const bf4v*)&h1b[(size_t)node * 256 + lane * 4]);
  float ss = 0.f;
#pragma unroll
  for (int r = 0; r < 4; ++r) ss = fmaf(h[r], h[r], ss);
#pragma unroll
  for (int o = 32; o >= 1; o >>= 1) ss += __shfl_xor(ss, o);
  if (lane == 0) invn[node] = 1.f / fmaxf(sqrtf(ss), 1e-12f);
}

// ---------------- degree count -------------------------------------------------
__global__ __launch_bounds__(256) void cnt_k(const int* __restrict__ dst,
                                             int* __restrict__ cnt) {
  int e = blockIdx.x * 256 + threadIdx.x;
  if (e >= NE) return;
  atomicAdd(&cnt[dst[e]], 1);
}

// ---------------- counting-sort by dst ----------------------------------------
__global__ __launch_bounds__(1024) void scan_k(const int* __restrict__ cnt,
                                               int* __restrict__ off2) {
  __shared__ int buf[1024];
  __shared__ int carry_s;
  const int t = threadIdx.x;
  if (t == 0) carry_s = 0;
  __syncthreads();
  const int nch = (NN + 1023) / 1024;
  for (int ch = 0; ch < nch; ++ch) {
    const int i = ch * 1024 + t;
    const int v = (i < NN) ? cnt[i] : 0;
    buf[t] = v;
    __syncthreads();
#pragma unroll
    for (int o = 1; o < 1024; o <<= 1) {
      int x = (t >= o) ? buf[t - o] : 0;
      __syncthreads();
      buf[t] += x;
      __syncthreads();
    }
    const int incl = buf[t];
    const int carry = carry_s;
    if (i < NN) off2[i] = carry + incl - v;
    __syncthreads();
    if (t == 1023) carry_s = carry + incl;
    __syncthreads();
  }
}

__global__ __launch_bounds__(256) void perm_k(const int* __restrict__ dst,
                                              int* __restrict__ off2,
                                              int* __restrict__ perm,
                                              int* __restrict__ dsts) {
  int e = blockIdx.x * 256 + threadIdx.x;
  if (e >= NE) return;
  int d = dst[e];
  int p = atomicAdd(&off2[d], 1);
  perm[p] = e;
  dsts[p] = d;
}

// ---------------- fused edge-MLP layer 1 (bf16 MFMA, sd-only row pass) --------

__global__ __launch_bounds__(256, 5) void edge_mlp1(
    const short* __restrict__ nfb, const float* __restrict__ ef,
    const int* __restrict__ src, const int* __restrict__ perm,
    const int* __restrict__ dsts, const float* __restrict__ invn1,
    const float* __restrict__ We1, const float* __restrict__ be1,
    const short* __restrict__ WaT, const float* __restrict__ ba,
    const short* __restrict__ WbT, const float* __restrict__ bbv,
    float* __restrict__ s1)
{
  __shared__ __align__(16) short Ms[64 * 136];   // 17408 B (M / T / R reuse)
  __shared__ int dse[64];
  __shared__ int pes[64];
  __shared__ int sse[64];
  const int t = threadIdx.x;
  const int e0 = blockIdx.x * 64;
  const int lane = t & 63, wv = t >> 6;

  if (t < 64) {
    const int pe = perm[e0 + t];
    pes[t] = pe;
    dse[t] = dsts[e0 + t];
    sse[t] = src[pe];
  }
  __syncthreads();

  // ---- row pass: 16 edges/wave; coalesced rows, sd-only wave-reduce ----
  {
    const int k2 = lane * 2;
    const float wA0 = We1[k2],       wA1 = We1[k2 + 1];
    const float wB0 = We1[128 + k2], wB1 = We1[128 + k2 + 1];
    const float bE0 = be1[k2],       bE1 = be1[k2 + 1];
#pragma unroll 4
    for (int i = 0; i < 16; ++i) {
      const int e = wv * 16 + i;
      const int s = sse[e];
      const int d = dse[e];
      bf2v hb = *(const bf2v*)&nfb[(size_t)s * 128 + k2];   // 64x4B coalesced
      bf2v db = *(const bf2v*)&nfb[(size_t)d * 128 + k2];
      const float h0 = b2f(hb[0]), h1v = b2f(hb[1]);
      const float g0 = b2f(db[0]), g1 = b2f(db[1]);
      float sd = fmaf(h0, g0, h1v * g1);
#pragma unroll
      for (int o = 32; o >= 1; o >>= 1) sd += __shfl_xor(sd, o);
      const float c = sd * invn1[s] * invn1[d];
      const float2 f01 = *(const float2*)&ef[2 * pes[e]];   // uniform broadcast
      const float w0 = fmaf(f01.x, wA0, fmaf(f01.y, wB0, bE0));
      const float w1 = fmaf(f01.x, wA1, fmaf(f01.y, wB1, bE1));
      bf2v pk;
      pk[0] = f2b(c * w0 * h0);
      pk[1] = f2b(c * w1 * h1v);
      *(bf2v*)&Ms[e * 136 + k2] = pk;
    }
  }
  __syncthreads();

  const int lr = lane & 15;
  const int lq = lane >> 4;
  const int n0 = wv * 32;

  f4 acc[2][4];
#pragma unroll
  for (int a = 0; a < 2; ++a)
#pragma unroll
    for (int b = 0; b < 4; ++b) acc[a][b] = (f4)0.f;

  // ---- stage 1: K = 128 ----
#pragma unroll
  for (int kc = 0; kc < 128; kc += 32) {
    bf8 aF[2], bF[4];
#pragma unroll
    for (int a = 0; a < 2; ++a)
      aF[a] = *(const bf8*)&WaT[(size_t)(n0 + a * 16 + lr) * 128 + kc + lq * 8];
#pragma unroll
    for (int b = 0; b < 4; ++b)
      bF[b] = *(const bf8*)&Ms[(b * 16 + lr) * 136 + kc + lq * 8];
#pragma unroll
    for (int a = 0; a < 2; ++a)
#pragma unroll
      for (int b = 0; b < 4; ++b)
        acc[a][b] = __builtin_amdgcn_mfma_f32_16x16x32_bf16(aF[a], bF[b], acc[a][b], 0, 0, 0);
  }
  __syncthreads();

  // T[e][n] = relu(acc + ba[n]) -> Ms
#pragma unroll
  for (int a = 0; a < 2; ++a) {
    const int n = n0 + a * 16 + lq * 4;
    f4 bb = *(const f4*)&ba[n];
#pragma unroll
    for (int b = 0; b < 4; ++b) {
      bf4v pk;
#pragma unroll
      for (int r = 0; r < 4; ++r) pk[r] = f2b(fmaxf(acc[a][b][r] + bb[r], 0.f));
      *(bf4v*)&Ms[(b * 16 + lr) * 136 + n] = pk;
    }
  }
  __syncthreads();

  // ---- stage 2: K = 128 ----
#pragma unroll
  for (int a = 0; a < 2; ++a)
#pragma unroll
    for (int b = 0; b < 4; ++b) acc[a][b] = (f4)0.f;
#pragma unroll
  for (int kc = 0; kc < 128; kc += 32) {
    bf8 aF[2], bF[4];
#pragma unroll
    for (int a = 0; a < 2; ++a)
      aF[a] = *(const bf8*)&WbT[(size_t)(n0 + a * 16 + lr) * 128 + kc + lq * 8];
#pragma unroll
    for (int b = 0; b < 4; ++b)
      bF[b] = *(const bf8*)&Ms[(b * 16 + lr) * 136 + kc + lq * 8];
#pragma unroll
    for (int a = 0; a < 2; ++a)
#pragma unroll
      for (int b = 0; b < 4; ++b)
        acc[a][b] = __builtin_amdgcn_mfma_f32_16x16x32_bf16(aF[a], bF[b], acc[a][b], 0, 0, 0);
  }
  __syncthreads();   // all waves done reading Ms before R overwrite

  // R[e][n] = relu(acc + bb[n]) -> Ms (bf16; sums still accumulate in fp32)
#pragma unroll
  for (int a = 0; a < 2; ++a) {
    const int n = n0 + a * 16 + lq * 4;
    f4 bb = *(const f4*)&bbv[n];
#pragma unroll
    for (int b = 0; b < 4; ++b) {
      bf4v pk;
#pragma unroll
      for (int r = 0; r < 4; ++r) pk[r] = f2b(fmaxf(acc[a][b][r] + bb[r], 0.f));
      *(bf4v*)&Ms[(b * 16 + lr) * 136 + n] = pk;
    }
  }
  __syncthreads();

  // segmented reduce over sorted dst
  {
    const int f = t & 127;
    const int eb = (t >> 7) * 32;
    float run = 0.f;
    int pd = dse[eb];
#pragma unroll 4
    for (int e = eb; e < eb + 32; ++e) {
      const int d = dse[e];          // wave-uniform
      if (d != pd) {
        atomicAdd(&s1[(size_t)pd * 128 + f], run);
        run = 0.f;
        pd = d;
      }
      run += b2f(Ms[e * 136 + f]);
    }
    atomicAdd(&s1[(size_t)pd * 128 + f], run);
  }
}

// ---------------- fused edge-MLP layer 2 (bf16 MFMA, sd-only row pass) --------
// LDS union: Ws (17408 B) lives inside M2s (33792 B). ~34.5 KB -> 4 blocks/CU.

__global__ __launch_bounds__(256, 4) void edge_mlp2(
    const short* __restrict__ h1b, const float* __restrict__ ef,
    const int* __restrict__ src, const int* __restrict__ perm,
    const int* __restrict__ dsts, const float* __restrict__ invn2,
    const float* __restrict__ We1, const float* __restrict__ be1,
    const short* __restrict__ We2T, const float* __restrict__ be2,
    const short* __restrict__ WaT, const float* __restrict__ ba,
    const short* __restrict__ WbT, const float* __restrict__ bbv,
    float* __restrict__ s2)
{
  __shared__ __align__(16) short U[64 * 264];    // 33792 B: Ws then M2s
  __shared__ int dse[64];
  __shared__ int pes[64];
  __shared__ int sse[64];
  short* Ws  = U;                                // 64 x 136
  short* M2s = U;                                // 64 x 264
  const int t = threadIdx.x;
  const int e0 = blockIdx.x * 64;
  const int lane = t & 63, wv = t >> 6;
  const int lr = lane & 15;
  const int lq = lane >> 4;
  const int n0 = wv * 64;

  if (t < 64) {
    const int pe = perm[e0 + t];
    pes[t] = pe;
    dse[t] = dsts[e0 + t];
    sse[t] = src[pe];
  }
  __syncthreads();

  // ---- build relu(w1) tile (bf16) into Ws ----
  {
    const int e = t >> 2;
    const int kb = (t & 3) * 32;
    const int pe = pes[e];
    const float f0 = ef[2 * pe], f1 = ef[2 * pe + 1];
#pragma unroll
    for (int j = 0; j < 4; ++j) {
      const int k = kb + j * 8;
      f4 wa0 = *(const f4*)&We1[k];
      f4 wa1 = *(const f4*)&We1[k + 4];
      f4 wb0 = *(const f4*)&We1[128 + k];
      f4 wb1 = *(const f4*)&We1[128 + k + 4];
      f4 b0 = *(const f4*)&be1[k];
      f4 b1 = *(const f4*)&be1[k + 4];
      bf8 pk;
#pragma unroll
      for (int x = 0; x < 4; ++x) {
        pk[x]     = f2b(fmaxf(fmaf(f0, wa0[x], fmaf(f1, wb0[x], b0[x])), 0.f));
        pk[x + 4] = f2b(fmaxf(fmaf(f0, wa1[x], fmaf(f1, wb1[x], b1[x])), 0.f));
      }
      *(bf8*)&Ws[e * 136 + k] = pk;
    }
  }
  __syncthreads();

  f4 acc[4][4];
#pragma unroll
  for (int a = 0; a < 4; ++a)
#pragma unroll
    for (int b = 0; b < 4; ++b) acc[a][b] = (f4)0.f;

  // ---- stage B: K = 128 (reads Ws) ----
#pragma unroll
  for (int kc = 0; kc < 128; kc += 32) {
    bf8 aF[4], bF[4];
#pragma unroll
    for (int a = 0; a < 4; ++a)
      aF[a] = *(const bf8*)&We2T[(size_t)(n0 + a * 16 + lr) * 128 + kc + lq * 8];
#pragma unroll
    for (int b = 0; b < 4; ++b)
      bF[b] = *(const bf8*)&Ws[(b * 16 + lr) * 136 + kc + lq * 8];
#pragma unroll
    for (int a = 0; a < 4; ++a)
#pragma unroll
      for (int b = 0; b < 4; ++b)
        acc[a][b] = __builtin_amdgcn_mfma_f32_16x16x32_bf16(aF[a], bF[b], acc[a][b], 0, 0, 0);
  }
  __syncthreads();   // Ws dead; M2s region may now be written

  // w2[e][n] = acc + be2[n] -> M2s (bf16, no cos/h yet)
#pragma unroll
  for (int b = 0; b < 4; ++b) {
#pragma unroll
    for (int a = 0; a < 4; ++a) {
      const int n = n0 + a * 16 + lq * 4;
      f4 bb = *(const f4*)&be2[n];
      bf4v pk;
#pragma unroll
      for (int r = 0; r < 4; ++r) pk[r] = f2b(acc[a][b][r] + bb[r]);
      *(bf4v*)&M2s[(b * 16 + lr) * 264 + n] = pk;
    }
  }
  __syncthreads();

  // ---- row pass: 16 edges/wave; coalesced rows, sd-only wave-reduce ----
  {
    const int k4 = lane * 4;
#pragma unroll 4
    for (int i = 0; i < 16; ++i) {
      const int e = wv * 16 + i;
      const int s = sse[e];
      const int d = dse[e];
      f4 hs = b2f4(*(const bf4v*)&h1b[(size_t)s * 256 + k4]);  // 64x8B coalesced
      f4 hd = b2f4(*(const bf4v*)&h1b[(size_t)d * 256 + k4]);
      float sd = 0.f;
#pragma unroll
      for (int r = 0; r < 4; ++r) sd = fmaf(hs[r], hd[r], sd);
#pragma unroll
      for (int o = 32; o >= 1; o >>= 1) sd += __shfl_xor(sd, o);
      const float c = sd * invn2[s] * invn2[d];
      f4 w = b2f4(*(const bf4v*)&M2s[e * 264 + k4]);
      bf4v pk;
#pragma unroll
      for (int r = 0; r < 4; ++r) pk[r] = f2b(w[r] * c * hs[r]);
      *(bf4v*)&M2s[e * 264 + k4] = pk;
    }
  }
  __syncthreads();

  // ---- stage C: K = 256, relu ----
#pragma unroll
  for (int a = 0; a < 4; ++a)
#pragma unroll
    for (int b = 0; b < 4; ++b) acc[a][b] = (f4)0.f;
  for (int kc = 0; kc < 256; kc += 32) {
    bf8 aF[4], bF[4];
#pragma unroll
    for (int a = 0; a < 4; ++a)
      aF[a] = *(const bf8*)&WaT[(size_t)(n0 + a * 16 + lr) * 256 + kc + lq * 8];
#pragma unroll
    for (int b = 0; b < 4; ++b)
      bF[b] = *(const bf8*)&M2s[(b * 16 + lr) * 264 + kc + lq * 8];
#pragma unroll
    for (int a = 0; a < 4; ++a)
#pragma unroll
      for (int b = 0; b < 4; ++b)
        acc[a][b] = __builtin_amdgcn_mfma_f32_16x16x32_bf16(aF[a], bF[b], acc[a][b], 0, 0, 0);
  }
  __syncthreads();

#pragma unroll
  for (int a = 0; a < 4; ++a) {
    const int n = n0 + a * 16 + lq * 4;
    f4 bb = *(const f4*)&ba[n];
#pragma unroll
    for (int b = 0; b < 4; ++b) {
      bf4v pk;
#pragma unroll
      for (int r = 0; r < 4; ++r) pk[r] = f2b(fmaxf(acc[a][b][r] + bb[r], 0.f));
      *(bf4v*)&M2s[(b * 16 + lr) * 264 + n] = pk;
    }
  }
  __syncthreads();

  // ---- stage D: K = 256 ----
#pragma unroll
  for (int a = 0; a < 4; ++a)
#pragma unroll
    for (int b = 0; b < 4; ++b) acc[a][b] = (f4)0.f;
  for (int kc = 0; kc < 256; kc += 32) {
    bf8 aF[4], bF[4];
#pragma unroll
    for (int a = 0; a < 4; ++a)
      aF[a] = *(const bf8*)&WbT[(size_t)(n0 + a * 16 + lr) * 256 + kc + lq * 8];
#pragma unroll
    for (int b = 0; b < 4; ++b)
      bF[b] = *(const bf8*)&M2s[(b * 16 + lr) * 264 + kc + lq * 8];
#pragma unroll
    for (int a = 0; a < 4; ++a)
#pragma unroll
      for (int b = 0; b < 4; ++b)
        acc[a][b] = __builtin_amdgcn_mfma_f32_16x16x32_bf16(aF[a], bF[b], acc[a][b], 0, 0, 0);
  }
  __syncthreads();  // all waves done reading M2s before fp32 reuse

  // epilogue: two n-halves; write relu+bias fp32 into RF (=M2s), seg-reduce
  float* RF = (float*)M2s;   // 64 x 132 fp32 = 33792 B
#pragma unroll
  for (int h = 0; h < 2; ++h) {
    if ((wv >> 1) == h) {
#pragma unroll
      for (int a = 0; a < 4; ++a) {
        const int n = n0 + a * 16 + lq * 4;
        f4 bb = *(const f4*)&bbv[n];
#pragma unroll
        for (int b = 0; b < 4; ++b) {
          f4 v;
#pragma unroll
          for (int r = 0; r < 4; ++r) v[r] = fmaxf(acc[a][b][r] + bb[r], 0.f);
          *(f4*)&RF[(b * 16 + lr) * 132 + (n - h * 128)] = v;
        }
      }
    }
    __syncthreads();
    {
      const int f = t & 127;
      const int eb = (t >> 7) * 32;
      float run = 0.f;
      int pd = dse[eb];
#pragma unroll 4
      for (int e = eb; e < eb + 32; ++e) {
        const int d = dse[e];        // wave-uniform
        if (d != pd) {
          atomicAdd(&s2[(size_t)pd * 256 + h * 128 + f], run);
          run = 0.f;
          pd = d;
        }
        run += RF[e * 132 + f];
      }
      atomicAdd(&s2[(size_t)pd * 256 + h * 128 + f], run);
    }
    __syncthreads();
  }
}

// ---------------- node linear 1 (bf16 MFMA) -> h1b (bf16) ---------------------

__global__ __launch_bounds__(256, 3) void h1m_k(
    const float* __restrict__ nf, const float* __restrict__ s1,
    const int* __restrict__ cnt, const short* __restrict__ Wl1T,
    const float* __restrict__ bl1, short* __restrict__ h1b)
{
  __shared__ __align__(16) short As[64 * 264];
  const int t = threadIdx.x;
  const int v0 = blockIdx.x * 64;

  {
    const int row = t >> 2;
    const int kb = (t & 3) * 64;
    int gn = v0 + row;
    if (gn >= NN) gn = NN - 1;
    const float inv = 1.f / fmaxf((float)cnt[gn], 1.f);
#pragma unroll
    for (int j = 0; j < 64; j += 8) {
      const int k = kb + j;
      f4 x0, x1;
      if (k < 128) {
        x0 = *(const f4*)&nf[(size_t)gn * 128 + k];
        x1 = *(const f4*)&nf[(size_t)gn * 128 + k + 4];
      } else {
        x0 = *(const f4*)&s1[(size_t)gn * 128 + (k - 128)];
        x1 = *(const f4*)&s1[(size_t)gn * 128 + (k - 124)];
#pragma unroll
        for (int x = 0; x < 4; ++x) { x0[x] *= inv; x1[x] *= inv; }
      }
      bf8 pk;
#pragma unroll
      for (int x = 0; x < 4; ++x) { pk[x] = f2b(x0[x]); pk[x + 4] = f2b(x1[x]); }
      *(bf8*)&As[row * 264 + k] = pk;
    }
  }
  __syncthreads();

  const int lane = t & 63, wv = t >> 6;
  const int lr = lane & 15;
  const int lq = lane >> 4;
  const int n0 = wv * 64;

  f4 acc[4][4];
#pragma unroll
  for (int a = 0; a < 4; ++a)
#pragma unroll
    for (int b = 0; b < 4; ++b) acc[a][b] = (f4)0.f;

  for (int kc = 0; kc < 256; kc += 32) {
    bf8 aF[4], bF[4];
#pragma unroll
    for (int a = 0; a < 4; ++a)
      aF[a] = *(const bf8*)&Wl1T[(size_t)(n0 + a * 16 + lr) * 256 + kc + lq * 8];
#pragma unroll
    for (int b = 0; b < 4; ++b)
      bF[b] = *(const bf8*)&As[(b * 16 + lr) * 264 + kc + lq * 8];
#pragma unroll
    for (int a = 0; a < 4; ++a)
#pragma unroll
      for (int b = 0; b < 4; ++b)
        acc[a][b] = __builtin_amdgcn_mfma_f32_16x16x32_bf16(aF[a], bF[b], acc[a][b], 0, 0, 0);
  }

#pragma unroll
  for (int b = 0; b < 4; ++b) {
    const int gn = v0 + b * 16 + lr;
    if (gn >= NN) continue;
#pragma unroll
    for (int a = 0; a < 4; ++a) {
      const int n = n0 + a * 16 + lq * 4;
      f4 bb = *(const f4*)&bl1[n];
      bf4v pk;
      pk[0] = f2b(fmaxf(acc[a][b][0] + bb[0], 0.f));
      pk[1] = f2b(fmaxf(acc[a][b][1] + bb[1], 0.f));
      pk[2] = f2b(fmaxf(acc[a][b][2] + bb[2], 0.f));
      pk[3] = f2b(fmaxf(acc[a][b][3] + bb[3], 0.f));
      *(bf4v*)&h1b[(size_t)gn * 256 + n] = pk;
    }
  }
}

// ---------------- final linear: out = concat(h1b, s2/cnt) @ Wl2 + bl2 ---------

__global__ __launch_bounds__(256) void out_k(
    const short* __restrict__ h1b, const float* __restrict__ s2,
    const int* __restrict__ cnt, const float* __restrict__ Wl2,
    const float* __restrict__ bl2, float* __restrict__ out)
{
  __shared__ float A8[8][512];
  const int n0 = blockIdx.x * 8;
  const int tx = threadIdx.x;
  const int ty = threadIdx.y;
  const int t = ty * 32 + tx;
  const int row = t >> 5;
  const int k0 = (t & 31) * 16;
  const int n = n0 + row;
  const float inv = 1.0f / fmaxf((float)cnt[n], 1.0f);
#pragma unroll
  for (int i = 0; i < 16; i += 4) {
    int k = k0 + i;
    f4 v;
    if (k < 256) {
      v = b2f4(*(const bf4v*)&h1b[(size_t)n * 256 + k]);
    } else {
      v = *(const f4*)&s2[(size_t)n * 256 + (k - 256)];
      v[0] *= inv; v[1] *= inv; v[2] *= inv; v[3] *= inv;
    }
    *(f4*)&A8[row][k] = v;
  }
  __syncthreads();
  float acc = bl2[tx];
#pragma unroll 8
  for (int k = 0; k < 512; k++) acc = fmaf(A8[ty][k], Wl2[(size_t)k * 32 + tx], acc);
  out[(size_t)(n0 + ty) * 32 + tx] = acc;
}

// ---------------- launch ------------------------------------------------------

extern "C" void kernel_launch(void* const* d_in, const int* in_sizes, int n_in,
                              void* d_out, int out_size, void* d_ws, size_t ws_size,
                              hipStream_t stream) {
  const float* nf   = (const float*)d_in[0];
  const float* ef   = (const float*)d_in[1];
  const int*   src  = (const int*)d_in[2];
  const int*   dst  = (const int*)d_in[3];
  const float* We1  = (const float*)d_in[4];
  const float* be1  = (const float*)d_in[5];
  const float* Wr1a = (const float*)d_in[6];
  const float* br1a = (const float*)d_in[7];
  const float* Wr1b = (const float*)d_in[8];
  const float* br1b = (const float*)d_in[9];
  const float* Wl1  = (const float*)d_in[10];
  const float* bl1  = (const float*)d_in[11];
  const float* We2  = (const float*)d_in[12];
  const float* be2  = (const float*)d_in[13];
  const float* Wr2a = (const float*)d_in[14];
  const float* br2a = (const float*)d_in[15];
  const float* Wr2b = (const float*)d_in[16];
  const float* br2b = (const float*)d_in[17];
  const float* Wl2  = (const float*)d_in[18];
  const float* bl2  = (const float*)d_in[19];

  float* ws = (float*)d_ws;
  float* s1   = ws;                             // N*128 f
  float* s2   = s1 + (size_t)NN * 128;          // N*256 f
  int*   cnt  = (int*)(s2 + (size_t)NN * 256);  // N
  short* h1b  = (short*)(cnt + NN);             // N*256 bf16
  short* nfb  = h1b + (size_t)NN * 256;         // N*128 bf16
  short* WaT1 = nfb + (size_t)NN * 128;         // 128*128 bf16
  short* WbT1 = WaT1 + 128 * 128;               // 128*128
  short* We2T = WbT1 + 128 * 128;               // 256*128
  short* WaT2 = We2T + 256 * 128;               // 256*256
  short* WbT2 = WaT2 + 256 * 256;               // 256*256
  short* Wl1T = WbT2 + 256 * 256;               // 256*256
  int*   off2 = (int*)(Wl1T + 256 * 256);       // N
  int*   perm = off2 + NN;                      // E
  int*   dsts = perm + NE;                      // E
  float* invn1 = (float*)(dsts + NE);           // N
  float* invn2 = invn1 + NN;                    // N

  size_t need = ((size_t)NN * 128 + (size_t)NN * 256 + NN) * 4 +
                ((size_t)NN * 256 + (size_t)NN * 128 +
                 (size_t)128 * 128 * 2 + (size_t)256 * 128 +
                 (size_t)256 * 256 * 3) * 2 +
                ((size_t)NN + 2 * (size_t)NE + 2 * (size_t)NN) * 4;
  if (ws_size < need) return;

  // weight transpose+convert and nf convert (tiny)
  wt_k<<<(128 * 128 + 255) / 256, 256, 0, stream>>>(Wr1a, WaT1, 128, 128);
  wt_k<<<(128 * 128 + 255) / 256, 256, 0, stream>>>(Wr1b, WbT1, 128, 128);
  wt_k<<<(128 * 256 + 255) / 256, 256, 0, stream>>>(We2, We2T, 128, 256);
  wt_k<<<(256 * 256 + 255) / 256, 256, 0, stream>>>(Wr2a, WaT2, 256, 256);
  wt_k<<<(256 * 256 + 255) / 256, 256, 0, stream>>>(Wr2b, WbT2, 256, 256);
  wt_k<<<(256 * 256 + 255) / 256, 256, 0, stream>>>(Wl1, Wl1T, 256, 256);
  cvt_k<<<(NN * 128 / 4 + 255) / 256, 256, 0, stream>>>(nf, nfb, NN * 128 / 4);
  norm1_k<<<(NN + 3) / 4, 256, 0, stream>>>(nfb, invn1);

  // zero s1, s2, cnt (contiguous)
  hipMemsetAsync(s1, 0, ((size_t)NN * 128 + (size_t)NN * 256 + NN) * 4, stream);

  cnt_k<<<NE / 256, 256, 0, stream>>>(dst, cnt);

  // counting sort by dst
  scan_k<<<1, 1024, 0, stream>>>(cnt, off2);
  perm_k<<<NE / 256, 256, 0, stream>>>(dst, off2, perm, dsts);

  edge_mlp1<<<NE / 64, 256, 0, stream>>>(nfb, ef, src, perm, dsts, invn1,
                                         We1, be1, WaT1, br1a, WbT1, br1b, s1);

  h1m_k<<<(NN + 63) / 64, 256, 0, stream>>>(nf, s1, cnt, Wl1T, bl1, h1b);
  norm2_k<<<(NN + 3) / 4, 256, 0, stream>>>(h1b, invn2);

  edge_mlp2<<<NE / 64, 256, 0, stream>>>(h1b, ef, src, perm, dsts, invn2,
                                         We1, be1, We2T, be2, WaT2, br2a,
                                         WbT2, br2b, s2);

  out_k<<<NN / 8, dim3(32, 8), 0, stream>>>(h1b, s2, cnt, Wl2, bl2, (float*)d_out);
}